// Round 1
// baseline (1158.072 us; speedup 1.0000x reference)
//
#include <hip/hip_runtime.h>
#include <hip/hip_bf16.h>
#include <stdint.h>

#define TOK 4096
#define SEQ 2048
#define DM 2048
#define NH 16
#define NKV 4
#define HDIM 128
#define HID 8192
#define WIN 1024
#define SINKN 4

typedef float f32x4 __attribute__((ext_vector_type(4)));
typedef __bf16 bf16x8 __attribute__((ext_vector_type(8)));
typedef unsigned short u16;
typedef unsigned int u32;

__device__ __forceinline__ u16 f2bf(float f) {
  union { float f; u32 u; } v; v.f = f;
  return (u16)((v.u + 0x7fffu + ((v.u >> 16) & 1u)) >> 16);
}
__device__ __forceinline__ float bf2f(u16 h) {
  union { u32 u; float f; } v; v.u = ((u32)h) << 16;
  return v.f;
}
__device__ __forceinline__ f32x4 mfma16(bf16x8 a, bf16x8 b, f32x4 c) {
  return __builtin_amdgcn_mfma_f32_16x16x32_bf16(a, b, c, 0, 0, 0);
}
__device__ __forceinline__ void gld16(const u16* g, u16* l) {
  __builtin_amdgcn_global_load_lds(
      (const __attribute__((address_space(1))) u32*)g,
      (__attribute__((address_space(3))) u32*)l, 16, 0, 0);
}
// Inverse swizzle for 64B-row tiles ([rows][32] u16), byte ^= ((row&7)<<4).
// chunk c (16B units) -> (row, k8chunk) it must source so that linear dest +
// swizzled read are consistent (rule #21).
__device__ __forceinline__ void swz_rc(int c, int& row, int& k8) {
  row = 2 * (c >> 3) + (((c >> 2) & 1) ^ ((c >> 4) & 1));
  k8 = (c & 3) ^ (row & 3);
}

// ---------------- weight transpose fp32[K][N] -> bf16[N][K] ----------------
__global__ __launch_bounds__(256)
void wtrans(const float* __restrict__ in, u16* __restrict__ out, int K, int N)
{
  __shared__ float t[32][33];
  int tx = threadIdx.x & 31, ty = threadIdx.x >> 5;
  int bx = blockIdx.x, by = blockIdx.y;
  #pragma unroll
  for (int i = 0; i < 4; i++) {
    int r = ty + i * 8;
    t[r][tx] = in[(size_t)(by * 32 + r) * N + bx * 32 + tx];
  }
  __syncthreads();
  #pragma unroll
  for (int i = 0; i < 4; i++) {
    int r = ty + i * 8;
    out[(size_t)(bx * 32 + r) * K + by * 32 + tx] = f2bf(t[tx][r]);
  }
}

// ------------- V transpose: bf16 [4096][512] -> [(b*4+hk)*128+d][2048] ------
__global__ __launch_bounds__(256)
void vtrans(const u16* __restrict__ in, u16* __restrict__ out)
{
  __shared__ u16 t[32][33];
  int tx = threadIdx.x & 31, ty = threadIdx.x >> 5;
  int bx = blockIdx.x;   // 512/32 = 16
  int by = blockIdx.y;   // 4096/32 = 128
  #pragma unroll
  for (int i = 0; i < 4; i++) {
    int r = ty + i * 8;
    t[r][tx] = in[(size_t)(by * 32 + r) * (NKV * HDIM) + bx * 32 + tx];
  }
  __syncthreads();
  int b = (by * 32) >> 11;
  int s0 = (by * 32) & (SEQ - 1);
  #pragma unroll
  for (int i = 0; i < 4; i++) {
    int c = bx * 32 + ty + i * 8;
    out[(size_t)(b * (NKV * HDIM) + c) * SEQ + s0 + tx] = t[tx][ty + i * 8];
  }
}

// ---------------------------- RoPE table -----------------------------------
__global__ __launch_bounds__(256)
void rope_table_k(float* __restrict__ ct, float* __restrict__ st)
{
  int idx = blockIdx.x * 256 + threadIdx.x;   // 2048*64
  int pos = idx >> 6, d = idx & 63;
  float inv = powf(10000.0f, -(float)d / 64.0f);
  float a = (float)pos * inv;
  ct[idx] = cosf(a);
  st[idx] = sinf(a);
}

// ----------------------- RoPE apply (in place, bf16) ------------------------
__global__ void rope_apply_k(u16* __restrict__ q, const float* __restrict__ ct,
                             const float* __restrict__ st, float scale)
{
  int t = blockIdx.x;                 // token
  int hh = threadIdx.x >> 6;          // head
  int d = threadIdx.x & 63;
  int pos = t & (SEQ - 1);
  int nh = blockDim.x >> 6;
  size_t base = (size_t)t * (nh * HDIM) + hh * HDIM + d;
  float x1 = bf2f(q[base]), x2 = bf2f(q[base + 64]);
  float c = ct[pos * 64 + d], s = st[pos * 64 + d];
  q[base]      = f2bf((x1 * c - x2 * s) * scale);
  q[base + 64] = f2bf((x2 * c + x1 * s) * scale);
}

// ------------------------------ RMSNorm ------------------------------------
__global__ __launch_bounds__(256)
void rmsnorm_k(const float* __restrict__ x, const float* __restrict__ g,
               u16* __restrict__ o)
{
  int row = blockIdx.x;
  int tid = threadIdx.x;
  const float* xr = x + (size_t)row * DM;
  float4 v0 = *(const float4*)(xr + tid * 8);
  float4 v1 = *(const float4*)(xr + tid * 8 + 4);
  float ss = v0.x*v0.x + v0.y*v0.y + v0.z*v0.z + v0.w*v0.w
           + v1.x*v1.x + v1.y*v1.y + v1.z*v1.z + v1.w*v1.w;
  #pragma unroll
  for (int d = 1; d < 64; d <<= 1) ss += __shfl_xor(ss, d);
  __shared__ float red[4];
  if ((tid & 63) == 0) red[tid >> 6] = ss;
  __syncthreads();
  float inv = rsqrtf((red[0] + red[1] + red[2] + red[3]) * (1.0f / DM) + 1e-6f);
  float4 g0 = *(const float4*)(g + tid * 8);
  float4 g1 = *(const float4*)(g + tid * 8 + 4);
  ushort4 o0, o1;
  o0.x = f2bf(v0.x * inv * g0.x); o0.y = f2bf(v0.y * inv * g0.y);
  o0.z = f2bf(v0.z * inv * g0.z); o0.w = f2bf(v0.w * inv * g0.w);
  o1.x = f2bf(v1.x * inv * g1.x); o1.y = f2bf(v1.y * inv * g1.y);
  o1.z = f2bf(v1.z * inv * g1.z); o1.w = f2bf(v1.w * inv * g1.w);
  *(ushort4*)(o + (size_t)row * DM + tid * 8) = o0;
  *(ushort4*)(o + (size_t)row * DM + tid * 8 + 4) = o1;
}

// --------------------- 128x128 bf16 GEMM, C = A @ Bt^T ----------------------
// A [M][K] bf16, Bt [N][K] bf16. EPI: 0 store bf16; 1 Cf = X + acc;
// 2 Cb = silu(Cb)*acc; 3 Cf += acc.
template<int EPI>
__global__ __launch_bounds__(256)
void gemm128(const u16* __restrict__ A, const u16* __restrict__ Bt,
             u16* __restrict__ Cb, float* __restrict__ Cf,
             const float* __restrict__ X, int M, int N, int K)
{
  __shared__ u16 As[128 * 32];
  __shared__ u16 Bs[128 * 32];
  int nbx = gridDim.x;
  int wg = blockIdx.y * nbx + blockIdx.x;
  int nwg = nbx * gridDim.y;
  int cpx = nwg >> 3;
  int swz = (wg & 7) * cpx + (wg >> 3);   // grids are multiples of 8
  int bx = swz % nbx, by = swz / nbx;
  int m0 = by * 128, n0 = bx * 128;
  int tid = threadIdx.x;
  int l = tid & 63, w = tid >> 6;
  int l16 = l & 15, lg = l >> 4;
  int wr = w >> 1, wc = w & 1;

  int r0, c0, r1, c1;
  swz_rc(tid, r0, c0);
  swz_rc(tid + 256, r1, c1);
  const u16* ga0 = A + (size_t)(m0 + r0) * K + c0 * 8;
  const u16* ga1 = A + (size_t)(m0 + r1) * K + c1 * 8;
  const u16* gb0 = Bt + (size_t)(n0 + r0) * K + c0 * 8;
  const u16* gb1 = Bt + (size_t)(n0 + r1) * K + c1 * 8;
  u16* lA0 = As + tid * 8;
  u16* lA1 = As + (tid + 256) * 8;
  u16* lB0 = Bs + tid * 8;
  u16* lB1 = Bs + (tid + 256) * 8;

  f32x4 acc[4][4];
  f32x4 zero = {0.f, 0.f, 0.f, 0.f};
  #pragma unroll
  for (int m = 0; m < 4; m++)
    #pragma unroll
    for (int n = 0; n < 4; n++) acc[m][n] = zero;

  int aoff[4], boff[4];
  #pragma unroll
  for (int i = 0; i < 4; i++) {
    int ra = wr * 64 + i * 16 + l16;
    aoff[i] = (ra * 32 + lg * 8) ^ ((ra & 7) * 8);
    int rb = wc * 64 + i * 16 + l16;
    boff[i] = (rb * 32 + lg * 8) ^ ((rb & 7) * 8);
  }

  for (int k0 = 0; k0 < K; k0 += 32) {
    gld16(ga0 + k0, lA0);
    gld16(ga1 + k0, lA1);
    gld16(gb0 + k0, lB0);
    gld16(gb1 + k0, lB1);
    __syncthreads();
    bf16x8 af[4], bfr[4];
    #pragma unroll
    for (int i = 0; i < 4; i++) af[i] = *(const bf16x8*)(As + aoff[i]);
    #pragma unroll
    for (int i = 0; i < 4; i++) bfr[i] = *(const bf16x8*)(Bs + boff[i]);
    #pragma unroll
    for (int m = 0; m < 4; m++)
      #pragma unroll
      for (int n = 0; n < 4; n++)
        acc[m][n] = mfma16(af[m], bfr[n], acc[m][n]);
    __syncthreads();
  }

  #pragma unroll
  for (int m = 0; m < 4; m++) {
    int row = m0 + wr * 64 + m * 16 + lg * 4;
    #pragma unroll
    for (int n = 0; n < 4; n++) {
      int col = n0 + wc * 64 + n * 16 + l16;
      #pragma unroll
      for (int r = 0; r < 4; r++) {
        size_t idx = (size_t)(row + r) * N + col;
        float v = acc[m][n][r];
        if (EPI == 0) {
          Cb[idx] = f2bf(v);
        } else if (EPI == 1) {
          Cf[idx] = X[idx] + v;
        } else if (EPI == 2) {
          float gt = bf2f(Cb[idx]);
          float sg = gt / (1.0f + __expf(-gt));
          Cb[idx] = f2bf(sg * v);
        } else {
          Cf[idx] += v;
        }
      }
    }
  }
}

// ------------------- flash attention, sliding window + sink -----------------
// qb [4096][NH*128] (pre-scaled+roped), kb [4096][NKV*128] (roped),
// vbt [(b*NKV+hk)*128 + d][2048]. ao [4096][NH*128].
__global__ __launch_bounds__(256)
void attn_k(const u16* __restrict__ qb, const u16* __restrict__ kb,
            const u16* __restrict__ vbt, u16* __restrict__ ao)
{
  int q0 = blockIdx.x * 128;
  int h = blockIdx.y;
  int b = blockIdx.z;
  int hk = h >> 2;
  int tid = threadIdx.x;
  int w = tid >> 6, l = tid & 63;
  int l16 = l & 15, lg = l >> 4;

  __shared__ u16 Ks[32 * 128];
  __shared__ u16 Vt[128 * 32];
  __shared__ u16 Ps[4][32 * 40];
  u16* Pw = Ps[w];

  // Q fragments (held in registers for whole block)
  bf16x8 qf[2][4];
  #pragma unroll
  for (int m = 0; m < 2; m++)
    #pragma unroll
    for (int kd = 0; kd < 4; kd++) {
      int row = q0 + w * 32 + m * 16 + l16;
      qf[m][kd] = *(const bf16x8*)(qb + (size_t)(b * SEQ + row) * (NH * HDIM)
                                   + h * HDIM + kd * 32 + lg * 8);
    }

  f32x4 oacc[2][8];
  float mrun[2][4], lrun[2][4];
  f32x4 zero = {0.f, 0.f, 0.f, 0.f};
  #pragma unroll
  for (int m = 0; m < 2; m++) {
    #pragma unroll
    for (int nd = 0; nd < 8; nd++) oacc[m][nd] = zero;
    #pragma unroll
    for (int r = 0; r < 4; r++) { mrun[m][r] = -1e9f; lrun[m][r] = 0.f; }
  }

  // staging index precompute
  int kr0 = tid >> 4,        kc0 = (tid & 15) ^ (kr0 & 7);
  int kr1 = (tid + 256) >> 4, kc1 = (tid & 15) ^ (kr1 & 7);
  int vd0, vk0, vd1, vk1;
  swz_rc(tid, vd0, vk0);
  swz_rc(tid + 256, vd1, vk1);
  const u16* kbase = kb + (size_t)(b * SEQ) * (NKV * HDIM) + hk * HDIM;
  const u16* vbase = vbt + (size_t)(b * NKV + hk) * HDIM * SEQ;

  // swizzled read offsets
  int koff[2][4];
  #pragma unroll
  for (int n = 0; n < 2; n++)
    #pragma unroll
    for (int kd = 0; kd < 4; kd++) {
      int key = n * 16 + l16;
      koff[n][kd] = ((key * 128) + kd * 32 + lg * 8) ^ ((key & 7) * 8);
    }
  int voff[8];
  #pragma unroll
  for (int nd = 0; nd < 8; nd++) {
    int d = nd * 16 + l16;
    voff[nd] = (d * 32 + lg * 8) ^ ((d & 7) * 8);
  }

  int lo = (q0 >= WIN) ? ((q0 - (WIN - 1)) >> 5) : 0;
  int hi = (q0 + 127) >> 5;

  for (int it = (lo > 0 ? lo - 1 : 0); it <= hi; ++it) {
    int kt = (it < lo) ? 0 : it;   // sink tile first when window excludes it
    gld16(kbase + (size_t)(kt * 32 + kr0) * (NKV * HDIM) + kc0 * 8, Ks + tid * 8);
    gld16(kbase + (size_t)(kt * 32 + kr1) * (NKV * HDIM) + kc1 * 8, Ks + (tid + 256) * 8);
    gld16(vbase + (size_t)vd0 * SEQ + kt * 32 + vk0 * 8, Vt + tid * 8);
    gld16(vbase + (size_t)vd1 * SEQ + kt * 32 + vk1 * 8, Vt + (tid + 256) * 8);
    __syncthreads();

    // S = Q @ K^T
    f32x4 sacc[2][2];
    sacc[0][0] = zero; sacc[0][1] = zero; sacc[1][0] = zero; sacc[1][1] = zero;
    #pragma unroll
    for (int kd = 0; kd < 4; kd++) {
      bf16x8 kf0 = *(const bf16x8*)(Ks + koff[0][kd]);
      bf16x8 kf1 = *(const bf16x8*)(Ks + koff[1][kd]);
      #pragma unroll
      for (int m = 0; m < 2; m++) {
        sacc[m][0] = mfma16(qf[m][kd], kf0, sacc[m][0]);
        sacc[m][1] = mfma16(qf[m][kd], kf1, sacc[m][1]);
      }
    }

    // mask + online softmax
    #pragma unroll
    for (int m = 0; m < 2; m++) {
      float sc[4];
      #pragma unroll
      for (int r = 0; r < 4; r++) {
        int i = q0 + w * 32 + m * 16 + lg * 4 + r;
        int j0 = kt * 32 + l16;
        int j1 = j0 + 16;
        float s0 = sacc[m][0][r];
        float s1 = sacc[m][1][r];
        bool ok0 = (j0 <= i) && ((i - j0 < WIN) || (j0 < SINKN));
        bool ok1 = (j1 <= i) && ((i - j1 < WIN) || (j1 < SINKN));
        s0 = ok0 ? s0 : -1e9f;
        s1 = ok1 ? s1 : -1e9f;
        float mx = fmaxf(s0, s1);
        mx = fmaxf(mx, __shfl_xor(mx, 1));
        mx = fmaxf(mx, __shfl_xor(mx, 2));
        mx = fmaxf(mx, __shfl_xor(mx, 4));
        mx = fmaxf(mx, __shfl_xor(mx, 8));
        float mold = mrun[m][r];
        float mnew = fmaxf(mold, mx);
        float scl = __expf(mold - mnew);
        mrun[m][r] = mnew;
        float p0 = __expf(s0 - mnew);
        float p1 = __expf(s1 - mnew);
        int prow = m * 16 + lg * 4 + r;
        Pw[prow * 40 + l16] = f2bf(p0);
        Pw[prow * 40 + 16 + l16] = f2bf(p1);
        float ps = p0 + p1;
        ps += __shfl_xor(ps, 1);
        ps += __shfl_xor(ps, 2);
        ps += __shfl_xor(ps, 4);
        ps += __shfl_xor(ps, 8);
        lrun[m][r] = lrun[m][r] * scl + ps;
        sc[r] = scl;
      }
      #pragma unroll
      for (int nd = 0; nd < 8; nd++) {
        oacc[m][nd][0] *= sc[0];
        oacc[m][nd][1] *= sc[1];
        oacc[m][nd][2] *= sc[2];
        oacc[m][nd][3] *= sc[3];
      }
    }

    // O += P @ V
    bf16x8 pa0 = *(const bf16x8*)(Pw + l16 * 40 + lg * 8);
    bf16x8 pa1 = *(const bf16x8*)(Pw + (16 + l16) * 40 + lg * 8);
    #pragma unroll
    for (int nd = 0; nd < 8; nd++) {
      bf16x8 vf = *(const bf16x8*)(Vt + voff[nd]);
      oacc[0][nd] = mfma16(pa0, vf, oacc[0][nd]);
      oacc[1][nd] = mfma16(pa1, vf, oacc[1][nd]);
    }
    __syncthreads();
  }

  #pragma unroll
  for (int m = 0; m < 2; m++)
    #pragma unroll
    for (int r = 0; r < 4; r++) {
      float invl = 1.0f / lrun[m][r];
      int row = q0 + w * 32 + m * 16 + lg * 4 + r;
      #pragma unroll
      for (int nd = 0; nd < 8; nd++) {
        int col = nd * 16 + l16;
        ao[(size_t)(b * SEQ + row) * (NH * HDIM) + h * HDIM + col] =
            f2bf(oacc[m][nd][r] * invl);
      }
    }
}

// ------------------------------- launcher -----------------------------------
extern "C" void kernel_launch(void* const* d_in, const int* in_sizes, int n_in,
                              void* d_out, int out_size, void* d_ws, size_t ws_size,
                              hipStream_t stream)
{
  (void)in_sizes; (void)n_in; (void)out_size;
  const float* x  = (const float*)d_in[0];
  const float* g1 = (const float*)d_in[1];
  const float* g2 = (const float*)d_in[2];
  const float* wq = (const float*)d_in[3];
  const float* wk = (const float*)d_in[4];
  const float* wv = (const float*)d_in[5];
  const float* wo = (const float*)d_in[6];
  const float* wg = (const float*)d_in[7];
  const float* wu = (const float*)d_in[8];
  const float* wd = (const float*)d_in[9];
  float* out = (float*)d_out;

  char* ws = (char*)d_ws;
  size_t off = 0;
  auto alloc = [&](size_t bytes) {
    char* p = ws + off;
    off += (bytes + 255) & ~(size_t)255;
    return p;
  };
  u16* wq_t = (u16*)alloc((size_t)DM * DM * 2);
  u16* wk_t = (u16*)alloc((size_t)(NKV * HDIM) * DM * 2);
  u16* wv_t = (u16*)alloc((size_t)(NKV * HDIM) * DM * 2);
  u16* wo_t = (u16*)alloc((size_t)DM * DM * 2);
  u16* wg_t = (u16*)alloc((size_t)HID * DM * 2);
  u16* wu_t = (u16*)alloc((size_t)HID * DM * 2);
  u16* wd_t = (u16*)alloc((size_t)DM * HID * 2);
  u16* hb   = (u16*)alloc((size_t)TOK * DM * 2);       // h, reused for h2
  u16* qb   = (u16*)alloc((size_t)TOK * NH * HDIM * 2);
  u16* kb   = (u16*)alloc((size_t)TOK * NKV * HDIM * 2);
  u16* vb   = (u16*)alloc((size_t)TOK * NKV * HDIM * 2);
  u16* vbt  = (u16*)alloc((size_t)TOK * NKV * HDIM * 2);
  u16* aob  = (u16*)alloc((size_t)TOK * NH * HDIM * 2);
  u16* gu   = (u16*)alloc((size_t)TOK * HID * 2);
  float* ct = (float*)alloc((size_t)SEQ * 64 * 4);
  float* st = (float*)alloc((size_t)SEQ * 64 * 4);
  if (off > ws_size) return;  // insufficient workspace -> loud failure

  dim3 blk(256);

  // weight transposes (fp32 -> bf16, [K][N] -> [N][K])
  wtrans<<<dim3(DM / 32, DM / 32), blk, 0, stream>>>(wq, wq_t, DM, DM);
  wtrans<<<dim3((NKV * HDIM) / 32, DM / 32), blk, 0, stream>>>(wk, wk_t, DM, NKV * HDIM);
  wtrans<<<dim3((NKV * HDIM) / 32, DM / 32), blk, 0, stream>>>(wv, wv_t, DM, NKV * HDIM);
  wtrans<<<dim3(DM / 32, DM / 32), blk, 0, stream>>>(wo, wo_t, DM, DM);
  wtrans<<<dim3(HID / 32, DM / 32), blk, 0, stream>>>(wg, wg_t, DM, HID);
  wtrans<<<dim3(HID / 32, DM / 32), blk, 0, stream>>>(wu, wu_t, DM, HID);
  wtrans<<<dim3(DM / 32, HID / 32), blk, 0, stream>>>(wd, wd_t, HID, DM);

  rope_table_k<<<SEQ * 64 / 256, blk, 0, stream>>>(ct, st);
  rmsnorm_k<<<TOK, blk, 0, stream>>>(x, g1, hb);

  gemm128<0><<<dim3(DM / 128, TOK / 128), blk, 0, stream>>>(hb, wq_t, qb, nullptr, nullptr, TOK, DM, DM);
  gemm128<0><<<dim3((NKV * HDIM) / 128, TOK / 128), blk, 0, stream>>>(hb, wk_t, kb, nullptr, nullptr, TOK, NKV * HDIM, DM);
  gemm128<0><<<dim3((NKV * HDIM) / 128, TOK / 128), blk, 0, stream>>>(hb, wv_t, vb, nullptr, nullptr, TOK, NKV * HDIM, DM);

  rope_apply_k<<<TOK, dim3(NH * 64), 0, stream>>>(qb, ct, st, 0.08838834764831845f);
  rope_apply_k<<<TOK, dim3(NKV * 64), 0, stream>>>(kb, ct, st, 1.0f);
  vtrans<<<dim3((NKV * HDIM) / 32, TOK / 32), blk, 0, stream>>>(vb, vbt);

  attn_k<<<dim3(SEQ / 128, NH, 2), blk, 0, stream>>>(qb, kb, vbt, aob);

  gemm128<1><<<dim3(DM / 128, TOK / 128), blk, 0, stream>>>(aob, wo_t, nullptr, out, x, TOK, DM, DM);
  rmsnorm_k<<<TOK, blk, 0, stream>>>(out, g2, hb);
  gemm128<0><<<dim3(HID / 128, TOK / 128), blk, 0, stream>>>(hb, wg_t, gu, nullptr, nullptr, TOK, HID, DM);
  gemm128<2><<<dim3(HID / 128, TOK / 128), blk, 0, stream>>>(hb, wu_t, gu, nullptr, nullptr, TOK, HID, DM);
  gemm128<3><<<dim3(DM / 128, TOK / 128), blk, 0, stream>>>(gu, wd_t, nullptr, out, nullptr, TOK, DM, HID);
}

// Round 2
// 990.125 us; speedup vs baseline: 1.1696x; 1.1696x over previous
//
#include <hip/hip_runtime.h>
#include <hip/hip_bf16.h>
#include <stdint.h>

#define TOK 4096
#define SEQ 2048
#define DM 2048
#define NH 16
#define NKV 4
#define HDIM 128
#define HID 8192
#define WIN 1024
#define SINKN 4

typedef float f32x4 __attribute__((ext_vector_type(4)));
typedef __bf16 bf16x8 __attribute__((ext_vector_type(8)));
typedef unsigned short u16;
typedef unsigned int u32;

__device__ __forceinline__ u16 f2bf(float f) {
  union { float f; u32 u; } v; v.f = f;
  return (u16)((v.u + 0x7fffu + ((v.u >> 16) & 1u)) >> 16);
}
__device__ __forceinline__ float bf2f(u16 h) {
  union { u32 u; float f; } v; v.u = ((u32)h) << 16;
  return v.f;
}
__device__ __forceinline__ f32x4 mfma16(bf16x8 a, bf16x8 b, f32x4 c) {
  return __builtin_amdgcn_mfma_f32_16x16x32_bf16(a, b, c, 0, 0, 0);
}
__device__ __forceinline__ void gld16(const u16* g, u16* l) {
  __builtin_amdgcn_global_load_lds(
      (const __attribute__((address_space(1))) u32*)g,
      (__attribute__((address_space(3))) u32*)l, 16, 0, 0);
}
__device__ __forceinline__ void barrier_raw() {
  asm volatile("" ::: "memory");
  __builtin_amdgcn_s_barrier();
  asm volatile("" ::: "memory");
}
// Inverse swizzle for 64B-row tiles ([rows][32] u16), read addr ^= ((row&7)<<4)B.
// chunk c (16B units) -> (row, k8chunk) global source (rule #21).
__device__ __forceinline__ void swz_rc(int c, int& row, int& k8) {
  row = 2 * (c >> 3) + (((c >> 2) & 1) ^ ((c >> 4) & 1));
  k8 = (c & 3) ^ (row & 3);
}

// ---------------- weight transpose fp32[K][N] -> bf16[N][K] ----------------
__global__ __launch_bounds__(256)
void wtrans(const float* __restrict__ in, u16* __restrict__ out, int K, int N)
{
  __shared__ float t[32][33];
  int tx = threadIdx.x & 31, ty = threadIdx.x >> 5;
  int bx = blockIdx.x, by = blockIdx.y;
  #pragma unroll
  for (int i = 0; i < 4; i++) {
    int r = ty + i * 8;
    t[r][tx] = in[(size_t)(by * 32 + r) * N + bx * 32 + tx];
  }
  __syncthreads();
  #pragma unroll
  for (int i = 0; i < 4; i++) {
    int r = ty + i * 8;
    out[(size_t)(bx * 32 + r) * K + by * 32 + tx] = f2bf(t[tx][r]);
  }
}

// ------------- V transpose: bf16 [4096][512] -> [(b*4+hk)*128+d][2048] ------
__global__ __launch_bounds__(256)
void vtrans(const u16* __restrict__ in, u16* __restrict__ out)
{
  __shared__ u16 t[32][33];
  int tx = threadIdx.x & 31, ty = threadIdx.x >> 5;
  int bx = blockIdx.x;
  int by = blockIdx.y;
  #pragma unroll
  for (int i = 0; i < 4; i++) {
    int r = ty + i * 8;
    t[r][tx] = in[(size_t)(by * 32 + r) * (NKV * HDIM) + bx * 32 + tx];
  }
  __syncthreads();
  int b = (by * 32) >> 11;
  int s0 = (by * 32) & (SEQ - 1);
  #pragma unroll
  for (int i = 0; i < 4; i++) {
    int c = bx * 32 + ty + i * 8;
    out[(size_t)(b * (NKV * HDIM) + c) * SEQ + s0 + tx] = t[tx][ty + i * 8];
  }
}

// ---------------------------- RoPE table -----------------------------------
__global__ __launch_bounds__(256)
void rope_table_k(float* __restrict__ ct, float* __restrict__ st)
{
  int idx = blockIdx.x * 256 + threadIdx.x;
  int pos = idx >> 6, d = idx & 63;
  float inv = powf(10000.0f, -(float)d / 64.0f);
  float a = (float)pos * inv;
  ct[idx] = cosf(a);
  st[idx] = sinf(a);
}

// ----------------------- RoPE apply (in place, bf16) ------------------------
__global__ void rope_apply_k(u16* __restrict__ q, const float* __restrict__ ct,
                             const float* __restrict__ st, float scale)
{
  int t = blockIdx.x;
  int hh = threadIdx.x >> 6;
  int d = threadIdx.x & 63;
  int pos = t & (SEQ - 1);
  int nh = blockDim.x >> 6;
  size_t base = (size_t)t * (nh * HDIM) + hh * HDIM + d;
  float x1 = bf2f(q[base]), x2 = bf2f(q[base + 64]);
  float c = ct[pos * 64 + d], s = st[pos * 64 + d];
  q[base]      = f2bf((x1 * c - x2 * s) * scale);
  q[base + 64] = f2bf((x2 * c + x1 * s) * scale);
}

// ------------------------------ RMSNorm ------------------------------------
__global__ __launch_bounds__(256)
void rmsnorm_k(const float* __restrict__ x, const float* __restrict__ g,
               u16* __restrict__ o)
{
  int row = blockIdx.x;
  int tid = threadIdx.x;
  const float* xr = x + (size_t)row * DM;
  float4 v0 = *(const float4*)(xr + tid * 8);
  float4 v1 = *(const float4*)(xr + tid * 8 + 4);
  float ss = v0.x*v0.x + v0.y*v0.y + v0.z*v0.z + v0.w*v0.w
           + v1.x*v1.x + v1.y*v1.y + v1.z*v1.z + v1.w*v1.w;
  #pragma unroll
  for (int d = 1; d < 64; d <<= 1) ss += __shfl_xor(ss, d);
  __shared__ float red[4];
  if ((tid & 63) == 0) red[tid >> 6] = ss;
  __syncthreads();
  float inv = rsqrtf((red[0] + red[1] + red[2] + red[3]) * (1.0f / DM) + 1e-6f);
  float4 g0 = *(const float4*)(g + tid * 8);
  float4 g1 = *(const float4*)(g + tid * 8 + 4);
  ushort4 o0, o1;
  o0.x = f2bf(v0.x * inv * g0.x); o0.y = f2bf(v0.y * inv * g0.y);
  o0.z = f2bf(v0.z * inv * g0.z); o0.w = f2bf(v0.w * inv * g0.w);
  o1.x = f2bf(v1.x * inv * g1.x); o1.y = f2bf(v1.y * inv * g1.y);
  o1.z = f2bf(v1.z * inv * g1.z); o1.w = f2bf(v1.w * inv * g1.w);
  *(ushort4*)(o + (size_t)row * DM + tid * 8) = o0;
  *(ushort4*)(o + (size_t)row * DM + tid * 8 + 4) = o1;
}

// --------------------- 128x128 bf16 GEMM (small-N fallback) -----------------
template<int EPI>
__global__ __launch_bounds__(256)
void gemm128(const u16* __restrict__ A, const u16* __restrict__ Bt,
             u16* __restrict__ Cb, float* __restrict__ Cf,
             const float* __restrict__ X, int M, int N, int K)
{
  __shared__ u16 As[128 * 32];
  __shared__ u16 Bs[128 * 32];
  int nbx = gridDim.x;
  int wg = blockIdx.y * nbx + blockIdx.x;
  int nwg = nbx * gridDim.y;
  int cpx = nwg >> 3;
  int swz = (wg & 7) * cpx + (wg >> 3);
  int bx = swz % nbx, by = swz / nbx;
  int m0 = by * 128, n0 = bx * 128;
  int tid = threadIdx.x;
  int l = tid & 63, w = tid >> 6;
  int l16 = l & 15, lg = l >> 4;
  int wr = w >> 1, wc = w & 1;

  int r0, c0, r1, c1;
  swz_rc(tid, r0, c0);
  swz_rc(tid + 256, r1, c1);
  const u16* ga0 = A + (size_t)(m0 + r0) * K + c0 * 8;
  const u16* ga1 = A + (size_t)(m0 + r1) * K + c1 * 8;
  const u16* gb0 = Bt + (size_t)(n0 + r0) * K + c0 * 8;
  const u16* gb1 = Bt + (size_t)(n0 + r1) * K + c1 * 8;
  u16* lA0 = As + tid * 8;
  u16* lA1 = As + (tid + 256) * 8;
  u16* lB0 = Bs + tid * 8;
  u16* lB1 = Bs + (tid + 256) * 8;

  f32x4 acc[4][4];
  f32x4 zero = {0.f, 0.f, 0.f, 0.f};
  #pragma unroll
  for (int m = 0; m < 4; m++)
    #pragma unroll
    for (int n = 0; n < 4; n++) acc[m][n] = zero;

  int aoff[4], boff[4];
  #pragma unroll
  for (int i = 0; i < 4; i++) {
    int ra = wr * 64 + i * 16 + l16;
    aoff[i] = (ra * 32 + lg * 8) ^ ((ra & 7) * 8);
    int rb = wc * 64 + i * 16 + l16;
    boff[i] = (rb * 32 + lg * 8) ^ ((rb & 7) * 8);
  }

  for (int k0 = 0; k0 < K; k0 += 32) {
    gld16(ga0 + k0, lA0);
    gld16(ga1 + k0, lA1);
    gld16(gb0 + k0, lB0);
    gld16(gb1 + k0, lB1);
    __syncthreads();
    bf16x8 af[4], bfr[4];
    #pragma unroll
    for (int i = 0; i < 4; i++) af[i] = *(const bf16x8*)(As + aoff[i]);
    #pragma unroll
    for (int i = 0; i < 4; i++) bfr[i] = *(const bf16x8*)(Bs + boff[i]);
    #pragma unroll
    for (int m = 0; m < 4; m++)
      #pragma unroll
      for (int n = 0; n < 4; n++)
        acc[m][n] = mfma16(af[m], bfr[n], acc[m][n]);
    __syncthreads();
  }

  #pragma unroll
  for (int m = 0; m < 4; m++) {
    int row = m0 + wr * 64 + m * 16 + lg * 4;
    #pragma unroll
    for (int n = 0; n < 4; n++) {
      int col = n0 + wc * 64 + n * 16 + l16;
      #pragma unroll
      for (int r = 0; r < 4; r++) {
        size_t idx = (size_t)(row + r) * N + col;
        float v = acc[m][n][r];
        if (EPI == 0) {
          Cb[idx] = f2bf(v);
        } else if (EPI == 1) {
          Cf[idx] = X[idx] + v;
        } else if (EPI == 2) {
          float gt = bf2f(Cb[idx]);
          float sg = gt / (1.0f + __expf(-gt));
          Cb[idx] = f2bf(sg * v);
        } else {
          Cf[idx] += v;
        }
      }
    }
  }
}

// ------------- deep-pipelined GEMM: BM x 256 tile, BK=32, 4 LDS slots -------
// 8 waves (2 x 4). T2 swizzle + T3/T4 counted vmcnt + T5 setprio.
// Stage tile j+3 while computing tile j; never drain vmcnt to 0 mid-loop.
template<int BM, int EPI>
__global__ __launch_bounds__(512)
void gemm_dp(const u16* __restrict__ A, const u16* __restrict__ Bt,
             u16* __restrict__ Cb, float* __restrict__ Cf,
             const float* __restrict__ X, int M, int N, int K)
{
  constexpr int BN = 256;
  constexpr int MREP = BM / 32;      // 8 (BM=256) or 4 (BM=128)
  constexpr int P = MREP / 4;        // phases per K-tile: 2 or 1
  constexpr int A_SZ = BM * 32;      // u16 per A slot
  constexpr int B_SZ = BN * 32;
  constexpr int LA = BM / 128;       // gld16/thread per A tile: 2 or 1
  __shared__ u16 lds[4 * (A_SZ + B_SZ)];

  int nbx = gridDim.x;
  int wg = blockIdx.y * nbx + blockIdx.x;
  int nwg = nbx * gridDim.y;
  int cpx = nwg >> 3;
  int swz = (wg & 7) * cpx + (wg >> 3);   // grids are multiples of 8
  int bx = swz % nbx, by = swz / nbx;
  int m0 = by * BM, n0 = bx * BN;

  int tid = threadIdx.x;
  int l = tid & 63, w = tid >> 6;
  int l16 = l & 15, lg = l >> 4;
  int wr = w >> 2, wc = w & 3;            // 2M x 4N waves

  int aoff[MREP], boff[4];
  #pragma unroll
  for (int m = 0; m < MREP; m++) {
    int ar = wr * (BM / 2) + m * 16 + l16;
    aoff[m] = (ar * 32 + lg * 8) ^ ((ar & 7) * 8);
  }
  #pragma unroll
  for (int n = 0; n < 4; n++) {
    int bc = wc * 64 + n * 16 + l16;
    boff[n] = (bc * 32 + lg * 8) ^ ((bc & 7) * 8);
  }

  const u16* gA0; const u16* gA1; const u16* gB0; const u16* gB1;
  {
    int r, kc;
    swz_rc(tid, r, kc);
    gA0 = A + (size_t)(m0 + r) * K + kc * 8;
    gB0 = Bt + (size_t)(n0 + r) * K + kc * 8;
    swz_rc(tid + 512, r, kc);
    gB1 = Bt + (size_t)(n0 + r) * K + kc * 8;
    if (LA == 2) gA1 = A + (size_t)(m0 + r) * K + kc * 8;
    else gA1 = gA0;
  }

  const int NT = K >> 5;

  // prologue: stage tiles 0,1,2 into slots 0,1,2
  #pragma unroll
  for (int t = 0; t < 3; t++) {
    u16* s = lds + t * (A_SZ + B_SZ);
    gld16(gA0 + t * 32, s + tid * 8);
    if (LA == 2) gld16(gA1 + t * 32, s + (tid + 512) * 8);
    gld16(gB0 + t * 32, s + A_SZ + tid * 8);
    gld16(gB1 + t * 32, s + A_SZ + (tid + 512) * 8);
  }
  gA0 += 96; gA1 += 96; gB0 += 96; gB1 += 96;
  if (LA == 2) asm volatile("s_waitcnt vmcnt(8)" ::: "memory");
  else         asm volatile("s_waitcnt vmcnt(6)" ::: "memory");
  barrier_raw();

  f32x4 acc[MREP][4];
  f32x4 zero = {0.f, 0.f, 0.f, 0.f};
  #pragma unroll
  for (int m = 0; m < MREP; m++)
    #pragma unroll
    for (int n = 0; n < 4; n++) acc[m][n] = zero;

  for (int j = 0; j < NT; ++j) {
    u16* As = lds + (j & 3) * (A_SZ + B_SZ);
    u16* Bs = As + A_SZ;
    u16* Ss = lds + ((j + 3) & 3) * (A_SZ + B_SZ);
    const bool st = (j + 3 < NT);

    // ---- phase 0: read B + A-half0, stage A(j+3) [+B if P==1] ----
    bf16x8 bfrag[4], afrag[4];
    #pragma unroll
    for (int n = 0; n < 4; n++) bfrag[n] = *(const bf16x8*)(Bs + boff[n]);
    #pragma unroll
    for (int m = 0; m < 4; m++) afrag[m] = *(const bf16x8*)(As + aoff[m]);
    if (st) {
      gld16(gA0, Ss + tid * 8);
      if (LA == 2) gld16(gA1, Ss + (tid + 512) * 8);
      if (P == 1) {
        gld16(gB0, Ss + A_SZ + tid * 8);
        gld16(gB1, Ss + A_SZ + (tid + 512) * 8);
      }
    }
    barrier_raw();
    asm volatile("s_waitcnt lgkmcnt(0)" ::: "memory");
    __builtin_amdgcn_sched_barrier(0);
    __builtin_amdgcn_s_setprio(1);
    #pragma unroll
    for (int m = 0; m < 4; m++)
      #pragma unroll
      for (int n = 0; n < 4; n++)
        acc[m][n] = mfma16(afrag[m], bfrag[n], acc[m][n]);
    __builtin_amdgcn_s_setprio(0);
    if (P == 1) {
      if (j + 3 < NT)      asm volatile("s_waitcnt vmcnt(6)" ::: "memory");
      else if (j + 2 < NT) asm volatile("s_waitcnt vmcnt(3)" ::: "memory");
      else if (j + 1 < NT) asm volatile("s_waitcnt vmcnt(0)" ::: "memory");
    }
    barrier_raw();

    if (P == 2) {
      // ---- phase 1: read A-half1, stage B(j+3) ----
      #pragma unroll
      for (int m = 0; m < 4; m++) afrag[m] = *(const bf16x8*)(As + aoff[4 + m]);
      if (st) {
        gld16(gB0, Ss + A_SZ + tid * 8);
        gld16(gB1, Ss + A_SZ + (tid + 512) * 8);
      }
      barrier_raw();
      asm volatile("s_waitcnt lgkmcnt(0)" ::: "memory");
      __builtin_amdgcn_sched_barrier(0);
      __builtin_amdgcn_s_setprio(1);
      #pragma unroll
      for (int m = 0; m < 4; m++)
        #pragma unroll
        for (int n = 0; n < 4; n++)
          acc[4 + m][n] = mfma16(afrag[m], bfrag[n], acc[4 + m][n]);
      __builtin_amdgcn_s_setprio(0);
      if (j + 3 < NT)      asm volatile("s_waitcnt vmcnt(8)" ::: "memory");
      else if (j + 2 < NT) asm volatile("s_waitcnt vmcnt(4)" ::: "memory");
      else if (j + 1 < NT) asm volatile("s_waitcnt vmcnt(0)" ::: "memory");
      barrier_raw();
    }
    gA0 += 32; gA1 += 32; gB0 += 32; gB1 += 32;
  }

  #pragma unroll
  for (int m = 0; m < MREP; m++) {
    int row = m0 + wr * (BM / 2) + m * 16 + lg * 4;
    #pragma unroll
    for (int n = 0; n < 4; n++) {
      int col = n0 + wc * 64 + n * 16 + l16;
      #pragma unroll
      for (int r = 0; r < 4; r++) {
        size_t idx = (size_t)(row + r) * N + col;
        float v = acc[m][n][r];
        if (EPI == 0) {
          Cb[idx] = f2bf(v);
        } else if (EPI == 1) {
          Cf[idx] = X[idx] + v;
        } else if (EPI == 2) {
          float gt = bf2f(Cb[idx]);
          float sg = gt / (1.0f + __expf(-gt));
          Cb[idx] = f2bf(sg * v);
        } else {
          Cf[idx] += v;
        }
      }
    }
  }
}

// ------------------- flash attention, sliding window + sink -----------------
__global__ __launch_bounds__(256)
void attn_k(const u16* __restrict__ qb, const u16* __restrict__ kb,
            const u16* __restrict__ vbt, u16* __restrict__ ao)
{
  int q0 = blockIdx.x * 128;
  int h = blockIdx.y;
  int b = blockIdx.z;
  int hk = h >> 2;
  int tid = threadIdx.x;
  int w = tid >> 6, l = tid & 63;
  int l16 = l & 15, lg = l >> 4;

  __shared__ u16 Ks[32 * 128];
  __shared__ u16 Vt[128 * 32];
  __shared__ u16 Ps[4][32 * 40];
  u16* Pw = Ps[w];

  bf16x8 qf[2][4];
  #pragma unroll
  for (int m = 0; m < 2; m++)
    #pragma unroll
    for (int kd = 0; kd < 4; kd++) {
      int row = q0 + w * 32 + m * 16 + l16;
      qf[m][kd] = *(const bf16x8*)(qb + (size_t)(b * SEQ + row) * (NH * HDIM)
                                   + h * HDIM + kd * 32 + lg * 8);
    }

  f32x4 oacc[2][8];
  float mrun[2][4], lrun[2][4];
  f32x4 zero = {0.f, 0.f, 0.f, 0.f};
  #pragma unroll
  for (int m = 0; m < 2; m++) {
    #pragma unroll
    for (int nd = 0; nd < 8; nd++) oacc[m][nd] = zero;
    #pragma unroll
    for (int r = 0; r < 4; r++) { mrun[m][r] = -1e9f; lrun[m][r] = 0.f; }
  }

  int kr0 = tid >> 4,        kc0 = (tid & 15) ^ (kr0 & 7);
  int kr1 = (tid + 256) >> 4, kc1 = (tid & 15) ^ (kr1 & 7);
  int vd0, vk0, vd1, vk1;
  swz_rc(tid, vd0, vk0);
  swz_rc(tid + 256, vd1, vk1);
  const u16* kbase = kb + (size_t)(b * SEQ) * (NKV * HDIM) + hk * HDIM;
  const u16* vbase = vbt + (size_t)(b * NKV + hk) * HDIM * SEQ;

  int koff[2][4];
  #pragma unroll
  for (int n = 0; n < 2; n++)
    #pragma unroll
    for (int kd = 0; kd < 4; kd++) {
      int key = n * 16 + l16;
      koff[n][kd] = ((key * 128) + kd * 32 + lg * 8) ^ ((key & 7) * 8);
    }
  int voff[8];
  #pragma unroll
  for (int nd = 0; nd < 8; nd++) {
    int d = nd * 16 + l16;
    voff[nd] = (d * 32 + lg * 8) ^ ((d & 7) * 8);
  }

  int lo = (q0 >= WIN) ? ((q0 - (WIN - 1)) >> 5) : 0;
  int hi = (q0 + 127) >> 5;

  for (int it = (lo > 0 ? lo - 1 : 0); it <= hi; ++it) {
    int kt = (it < lo) ? 0 : it;
    gld16(kbase + (size_t)(kt * 32 + kr0) * (NKV * HDIM) + kc0 * 8, Ks + tid * 8);
    gld16(kbase + (size_t)(kt * 32 + kr1) * (NKV * HDIM) + kc1 * 8, Ks + (tid + 256) * 8);
    gld16(vbase + (size_t)vd0 * SEQ + kt * 32 + vk0 * 8, Vt + tid * 8);
    gld16(vbase + (size_t)vd1 * SEQ + kt * 32 + vk1 * 8, Vt + (tid + 256) * 8);
    __syncthreads();

    f32x4 sacc[2][2];
    sacc[0][0] = zero; sacc[0][1] = zero; sacc[1][0] = zero; sacc[1][1] = zero;
    #pragma unroll
    for (int kd = 0; kd < 4; kd++) {
      bf16x8 kf0 = *(const bf16x8*)(Ks + koff[0][kd]);
      bf16x8 kf1 = *(const bf16x8*)(Ks + koff[1][kd]);
      #pragma unroll
      for (int m = 0; m < 2; m++) {
        sacc[m][0] = mfma16(qf[m][kd], kf0, sacc[m][0]);
        sacc[m][1] = mfma16(qf[m][kd], kf1, sacc[m][1]);
      }
    }

    #pragma unroll
    for (int m = 0; m < 2; m++) {
      float sc[4];
      #pragma unroll
      for (int r = 0; r < 4; r++) {
        int i = q0 + w * 32 + m * 16 + lg * 4 + r;
        int j0 = kt * 32 + l16;
        int j1 = j0 + 16;
        float s0 = sacc[m][0][r];
        float s1 = sacc[m][1][r];
        bool ok0 = (j0 <= i) && ((i - j0 < WIN) || (j0 < SINKN));
        bool ok1 = (j1 <= i) && ((i - j1 < WIN) || (j1 < SINKN));
        s0 = ok0 ? s0 : -1e9f;
        s1 = ok1 ? s1 : -1e9f;
        float mx = fmaxf(s0, s1);
        mx = fmaxf(mx, __shfl_xor(mx, 1));
        mx = fmaxf(mx, __shfl_xor(mx, 2));
        mx = fmaxf(mx, __shfl_xor(mx, 4));
        mx = fmaxf(mx, __shfl_xor(mx, 8));
        float mold = mrun[m][r];
        float mnew = fmaxf(mold, mx);
        float scl = __expf(mold - mnew);
        mrun[m][r] = mnew;
        float p0 = __expf(s0 - mnew);
        float p1 = __expf(s1 - mnew);
        int prow = m * 16 + lg * 4 + r;
        Pw[prow * 40 + l16] = f2bf(p0);
        Pw[prow * 40 + 16 + l16] = f2bf(p1);
        float ps = p0 + p1;
        ps += __shfl_xor(ps, 1);
        ps += __shfl_xor(ps, 2);
        ps += __shfl_xor(ps, 4);
        ps += __shfl_xor(ps, 8);
        lrun[m][r] = lrun[m][r] * scl + ps;
        sc[r] = scl;
      }
      #pragma unroll
      for (int nd = 0; nd < 8; nd++) {
        oacc[m][nd][0] *= sc[0];
        oacc[m][nd][1] *= sc[1];
        oacc[m][nd][2] *= sc[2];
        oacc[m][nd][3] *= sc[3];
      }
    }

    bf16x8 pa0 = *(const bf16x8*)(Pw + l16 * 40 + lg * 8);
    bf16x8 pa1 = *(const bf16x8*)(Pw + (16 + l16) * 40 + lg * 8);
    #pragma unroll
    for (int nd = 0; nd < 8; nd++) {
      bf16x8 vf = *(const bf16x8*)(Vt + voff[nd]);
      oacc[0][nd] = mfma16(pa0, vf, oacc[0][nd]);
      oacc[1][nd] = mfma16(pa1, vf, oacc[1][nd]);
    }
    __syncthreads();
  }

  #pragma unroll
  for (int m = 0; m < 2; m++)
    #pragma unroll
    for (int r = 0; r < 4; r++) {
      float invl = 1.0f / lrun[m][r];
      int row = q0 + w * 32 + m * 16 + lg * 4 + r;
      #pragma unroll
      for (int nd = 0; nd < 8; nd++) {
        int col = nd * 16 + l16;
        ao[(size_t)(b * SEQ + row) * (NH * HDIM) + h * HDIM + col] =
            f2bf(oacc[m][nd][r] * invl);
      }
    }
}

// ------------------------------- launcher -----------------------------------
extern "C" void kernel_launch(void* const* d_in, const int* in_sizes, int n_in,
                              void* d_out, int out_size, void* d_ws, size_t ws_size,
                              hipStream_t stream)
{
  (void)in_sizes; (void)n_in; (void)out_size;
  const float* x  = (const float*)d_in[0];
  const float* g1 = (const float*)d_in[1];
  const float* g2 = (const float*)d_in[2];
  const float* wq = (const float*)d_in[3];
  const float* wk = (const float*)d_in[4];
  const float* wv = (const float*)d_in[5];
  const float* wo = (const float*)d_in[6];
  const float* wg = (const float*)d_in[7];
  const float* wu = (const float*)d_in[8];
  const float* wd = (const float*)d_in[9];
  float* out = (float*)d_out;

  char* ws = (char*)d_ws;
  size_t off = 0;
  auto alloc = [&](size_t bytes) {
    char* p = ws + off;
    off += (bytes + 255) & ~(size_t)255;
    return p;
  };
  u16* wq_t = (u16*)alloc((size_t)DM * DM * 2);
  u16* wk_t = (u16*)alloc((size_t)(NKV * HDIM) * DM * 2);
  u16* wv_t = (u16*)alloc((size_t)(NKV * HDIM) * DM * 2);
  u16* wo_t = (u16*)alloc((size_t)DM * DM * 2);
  u16* wg_t = (u16*)alloc((size_t)HID * DM * 2);
  u16* wu_t = (u16*)alloc((size_t)HID * DM * 2);
  u16* wd_t = (u16*)alloc((size_t)DM * HID * 2);
  u16* hb   = (u16*)alloc((size_t)TOK * DM * 2);
  u16* qb   = (u16*)alloc((size_t)TOK * NH * HDIM * 2);
  u16* kb   = (u16*)alloc((size_t)TOK * NKV * HDIM * 2);
  u16* vb   = (u16*)alloc((size_t)TOK * NKV * HDIM * 2);
  u16* vbt  = (u16*)alloc((size_t)TOK * NKV * HDIM * 2);
  u16* aob  = (u16*)alloc((size_t)TOK * NH * HDIM * 2);
  u16* gu   = (u16*)alloc((size_t)TOK * HID * 2);
  float* ct = (float*)alloc((size_t)SEQ * 64 * 4);
  float* st = (float*)alloc((size_t)SEQ * 64 * 4);
  if (off > ws_size) return;

  dim3 blk(256);
  dim3 blk512(512);

  wtrans<<<dim3(DM / 32, DM / 32), blk, 0, stream>>>(wq, wq_t, DM, DM);
  wtrans<<<dim3((NKV * HDIM) / 32, DM / 32), blk, 0, stream>>>(wk, wk_t, DM, NKV * HDIM);
  wtrans<<<dim3((NKV * HDIM) / 32, DM / 32), blk, 0, stream>>>(wv, wv_t, DM, NKV * HDIM);
  wtrans<<<dim3(DM / 32, DM / 32), blk, 0, stream>>>(wo, wo_t, DM, DM);
  wtrans<<<dim3(HID / 32, DM / 32), blk, 0, stream>>>(wg, wg_t, DM, HID);
  wtrans<<<dim3(HID / 32, DM / 32), blk, 0, stream>>>(wu, wu_t, DM, HID);
  wtrans<<<dim3(DM / 32, HID / 32), blk, 0, stream>>>(wd, wd_t, HID, DM);

  rope_table_k<<<SEQ * 64 / 256, blk, 0, stream>>>(ct, st);
  rmsnorm_k<<<TOK, blk, 0, stream>>>(x, g1, hb);

  gemm_dp<128, 0><<<dim3(DM / 256, TOK / 128), blk512, 0, stream>>>(hb, wq_t, qb, nullptr, nullptr, TOK, DM, DM);
  gemm128<0><<<dim3((NKV * HDIM) / 128, TOK / 128), blk, 0, stream>>>(hb, wk_t, kb, nullptr, nullptr, TOK, NKV * HDIM, DM);
  gemm128<0><<<dim3((NKV * HDIM) / 128, TOK / 128), blk, 0, stream>>>(hb, wv_t, vb, nullptr, nullptr, TOK, NKV * HDIM, DM);

  rope_apply_k<<<TOK, dim3(NH * 64), 0, stream>>>(qb, ct, st, 0.08838834764831845f);
  rope_apply_k<<<TOK, dim3(NKV * 64), 0, stream>>>(kb, ct, st, 1.0f);
  vtrans<<<dim3((NKV * HDIM) / 32, TOK / 32), blk, 0, stream>>>(vb, vbt);

  attn_k<<<dim3(SEQ / 128, NH, 2), blk, 0, stream>>>(qb, kb, vbt, aob);

  gemm_dp<128, 1><<<dim3(DM / 256, TOK / 128), blk512, 0, stream>>>(aob, wo_t, nullptr, out, x, TOK, DM, DM);
  rmsnorm_k<<<TOK, blk, 0, stream>>>(out, g2, hb);
  gemm_dp<256, 0><<<dim3(HID / 256, TOK / 256), blk512, 0, stream>>>(hb, wg_t, gu, nullptr, nullptr, TOK, HID, DM);
  gemm_dp<256, 2><<<dim3(HID / 256, TOK / 256), blk512, 0, stream>>>(hb, wu_t, gu, nullptr, nullptr, TOK, HID, DM);
  gemm_dp<128, 3><<<dim3(DM / 256, TOK / 128), blk512, 0, stream>>>(gu, wd_t, nullptr, out, nullptr, TOK, DM, HID);
}

// Round 3
// 969.743 us; speedup vs baseline: 1.1942x; 1.0210x over previous
//
#include <hip/hip_runtime.h>
#include <hip/hip_bf16.h>
#include <stdint.h>

#define TOK 4096
#define SEQ 2048
#define DM 2048
#define NH 16
#define NKV 4
#define HDIM 128
#define HID 8192
#define WIN 1024
#define SINKN 4

typedef float f32x4 __attribute__((ext_vector_type(4)));
typedef __bf16 bf16x8 __attribute__((ext_vector_type(8)));
typedef unsigned short u16;
typedef unsigned int u32;

__device__ __forceinline__ u16 f2bf(float f) {
  union { float f; u32 u; } v; v.f = f;
  return (u16)((v.u + 0x7fffu + ((v.u >> 16) & 1u)) >> 16);
}
__device__ __forceinline__ float bf2f(u16 h) {
  union { u32 u; float f; } v; v.u = ((u32)h) << 16;
  return v.f;
}
__device__ __forceinline__ f32x4 mfma16(bf16x8 a, bf16x8 b, f32x4 c) {
  return __builtin_amdgcn_mfma_f32_16x16x32_bf16(a, b, c, 0, 0, 0);
}
__device__ __forceinline__ void gld16(const u16* g, u16* l) {
  __builtin_amdgcn_global_load_lds(
      (const __attribute__((address_space(1))) u32*)g,
      (__attribute__((address_space(3))) u32*)l, 16, 0, 0);
}
// Inverse swizzle for 64B-row tiles ([rows][32] u16), read addr ^= ((row&7)*8) u16.
// chunk c (16B units) -> (row, k8chunk) global source (rule #21).
__device__ __forceinline__ void swz_rc(int c, int& row, int& k8) {
  row = 2 * (c >> 3) + (((c >> 2) & 1) ^ ((c >> 4) & 1));
  k8 = (c & 3) ^ (row & 3);
}

// ---------------- weight transpose fp32[K][N] -> bf16[N][K] ----------------
__global__ __launch_bounds__(256)
void wtrans(const float* __restrict__ in, u16* __restrict__ out, int K, int N)
{
  __shared__ float t[32][33];
  int tx = threadIdx.x & 31, ty = threadIdx.x >> 5;
  int bx = blockIdx.x, by = blockIdx.y;
  #pragma unroll
  for (int i = 0; i < 4; i++) {
    int r = ty + i * 8;
    t[r][tx] = in[(size_t)(by * 32 + r) * N + bx * 32 + tx];
  }
  __syncthreads();
  #pragma unroll
  for (int i = 0; i < 4; i++) {
    int r = ty + i * 8;
    out[(size_t)(bx * 32 + r) * K + by * 32 + tx] = f2bf(t[tx][r]);
  }
}

// ------------- V transpose: bf16 [4096][512] -> [(b*4+hk)*128+d][2048] ------
__global__ __launch_bounds__(256)
void vtrans(const u16* __restrict__ in, u16* __restrict__ out)
{
  __shared__ u16 t[32][33];
  int tx = threadIdx.x & 31, ty = threadIdx.x >> 5;
  int bx = blockIdx.x;
  int by = blockIdx.y;
  #pragma unroll
  for (int i = 0; i < 4; i++) {
    int r = ty + i * 8;
    t[r][tx] = in[(size_t)(by * 32 + r) * (NKV * HDIM) + bx * 32 + tx];
  }
  __syncthreads();
  int b = (by * 32) >> 11;
  int s0 = (by * 32) & (SEQ - 1);
  #pragma unroll
  for (int i = 0; i < 4; i++) {
    int c = bx * 32 + ty + i * 8;
    out[(size_t)(b * (NKV * HDIM) + c) * SEQ + s0 + tx] = t[tx][ty + i * 8];
  }
}

// ---------------------------- RoPE table -----------------------------------
__global__ __launch_bounds__(256)
void rope_table_k(float* __restrict__ ct, float* __restrict__ st)
{
  int idx = blockIdx.x * 256 + threadIdx.x;
  int pos = idx >> 6, d = idx & 63;
  float inv = powf(10000.0f, -(float)d / 64.0f);
  float a = (float)pos * inv;
  ct[idx] = cosf(a);
  st[idx] = sinf(a);
}

// ----------------------- RoPE apply (in place, bf16) ------------------------
__global__ void rope_apply_k(u16* __restrict__ q, const float* __restrict__ ct,
                             const float* __restrict__ st, float scale)
{
  int t = blockIdx.x;
  int hh = threadIdx.x >> 6;
  int d = threadIdx.x & 63;
  int pos = t & (SEQ - 1);
  int nh = blockDim.x >> 6;
  size_t base = (size_t)t * (nh * HDIM) + hh * HDIM + d;
  float x1 = bf2f(q[base]), x2 = bf2f(q[base + 64]);
  float c = ct[pos * 64 + d], s = st[pos * 64 + d];
  q[base]      = f2bf((x1 * c - x2 * s) * scale);
  q[base + 64] = f2bf((x2 * c + x1 * s) * scale);
}

// ------------------------------ RMSNorm ------------------------------------
__global__ __launch_bounds__(256)
void rmsnorm_k(const float* __restrict__ x, const float* __restrict__ g,
               u16* __restrict__ o)
{
  int row = blockIdx.x;
  int tid = threadIdx.x;
  const float* xr = x + (size_t)row * DM;
  float4 v0 = *(const float4*)(xr + tid * 8);
  float4 v1 = *(const float4*)(xr + tid * 8 + 4);
  float ss = v0.x*v0.x + v0.y*v0.y + v0.z*v0.z + v0.w*v0.w
           + v1.x*v1.x + v1.y*v1.y + v1.z*v1.z + v1.w*v1.w;
  #pragma unroll
  for (int d = 1; d < 64; d <<= 1) ss += __shfl_xor(ss, d);
  __shared__ float red[4];
  if ((tid & 63) == 0) red[tid >> 6] = ss;
  __syncthreads();
  float inv = rsqrtf((red[0] + red[1] + red[2] + red[3]) * (1.0f / DM) + 1e-6f);
  float4 g0 = *(const float4*)(g + tid * 8);
  float4 g1 = *(const float4*)(g + tid * 8 + 4);
  ushort4 o0, o1;
  o0.x = f2bf(v0.x * inv * g0.x); o0.y = f2bf(v0.y * inv * g0.y);
  o0.z = f2bf(v0.z * inv * g0.z); o0.w = f2bf(v0.w * inv * g0.w);
  o1.x = f2bf(v1.x * inv * g1.x); o1.y = f2bf(v1.y * inv * g1.y);
  o1.z = f2bf(v1.z * inv * g1.z); o1.w = f2bf(v1.w * inv * g1.w);
  *(ushort4*)(o + (size_t)row * DM + tid * 8) = o0;
  *(ushort4*)(o + (size_t)row * DM + tid * 8 + 4) = o1;
}

// --------------------- 128x128 bf16 GEMM (small-N fallback) -----------------
template<int EPI>
__global__ __launch_bounds__(256)
void gemm128(const u16* __restrict__ A, const u16* __restrict__ Bt,
             u16* __restrict__ Cb, float* __restrict__ Cf,
             const float* __restrict__ X, int M, int N, int K)
{
  __shared__ u16 As[128 * 32];
  __shared__ u16 Bs[128 * 32];
  int nbx = gridDim.x;
  int wg = blockIdx.y * nbx + blockIdx.x;
  int nwg = nbx * gridDim.y;
  int cpx = nwg >> 3;
  int swz = (wg & 7) * cpx + (wg >> 3);
  int bx = swz % nbx, by = swz / nbx;
  int m0 = by * 128, n0 = bx * 128;
  int tid = threadIdx.x;
  int l = tid & 63, w = tid >> 6;
  int l16 = l & 15, lg = l >> 4;
  int wr = w >> 1, wc = w & 1;

  int r0, c0, r1, c1;
  swz_rc(tid, r0, c0);
  swz_rc(tid + 256, r1, c1);
  const u16* ga0 = A + (size_t)(m0 + r0) * K + c0 * 8;
  const u16* ga1 = A + (size_t)(m0 + r1) * K + c1 * 8;
  const u16* gb0 = Bt + (size_t)(n0 + r0) * K + c0 * 8;
  const u16* gb1 = Bt + (size_t)(n0 + r1) * K + c1 * 8;
  u16* lA0 = As + tid * 8;
  u16* lA1 = As + (tid + 256) * 8;
  u16* lB0 = Bs + tid * 8;
  u16* lB1 = Bs + (tid + 256) * 8;

  f32x4 acc[4][4];
  f32x4 zero = {0.f, 0.f, 0.f, 0.f};
  #pragma unroll
  for (int m = 0; m < 4; m++)
    #pragma unroll
    for (int n = 0; n < 4; n++) acc[m][n] = zero;

  int aoff[4], boff[4];
  #pragma unroll
  for (int i = 0; i < 4; i++) {
    int ra = wr * 64 + i * 16 + l16;
    aoff[i] = (ra * 32 + lg * 8) ^ ((ra & 7) * 8);
    int rb = wc * 64 + i * 16 + l16;
    boff[i] = (rb * 32 + lg * 8) ^ ((rb & 7) * 8);
  }

  for (int k0 = 0; k0 < K; k0 += 32) {
    gld16(ga0 + k0, lA0);
    gld16(ga1 + k0, lA1);
    gld16(gb0 + k0, lB0);
    gld16(gb1 + k0, lB1);
    __syncthreads();
    bf16x8 af[4], bfr[4];
    #pragma unroll
    for (int i = 0; i < 4; i++) af[i] = *(const bf16x8*)(As + aoff[i]);
    #pragma unroll
    for (int i = 0; i < 4; i++) bfr[i] = *(const bf16x8*)(Bs + boff[i]);
    #pragma unroll
    for (int m = 0; m < 4; m++)
      #pragma unroll
      for (int n = 0; n < 4; n++)
        acc[m][n] = mfma16(af[m], bfr[n], acc[m][n]);
    __syncthreads();
  }

  #pragma unroll
  for (int m = 0; m < 4; m++) {
    int row = m0 + wr * 64 + m * 16 + lg * 4;
    #pragma unroll
    for (int n = 0; n < 4; n++) {
      int col = n0 + wc * 64 + n * 16 + l16;
      #pragma unroll
      for (int r = 0; r < 4; r++) {
        size_t idx = (size_t)(row + r) * N + col;
        float v = acc[m][n][r];
        if (EPI == 0) {
          Cb[idx] = f2bf(v);
        } else if (EPI == 1) {
          Cf[idx] = X[idx] + v;
        } else if (EPI == 2) {
          float gt = bf2f(Cb[idx]);
          float sg = gt / (1.0f + __expf(-gt));
          Cb[idx] = f2bf(sg * v);
        } else {
          Cf[idx] += v;
        }
      }
    }
  }
}

// ------ single-barrier pipelined GEMM: BM x 256, BK=32, 4-slot ring ---------
// Stage distance 2; ONE s_barrier + counted vmcnt per K-tile; no explicit
// lgkmcnt (compiler emits counted waits for ds_read->MFMA). T2 swizzle + T5.
// Race-freedom: writer slot (j+2)&3 vs concurrent reader slots j&3/(j-1)&3
// under <1-iteration wave drift -> always distinct.
template<int BM, int EPI>
__global__ __launch_bounds__(512, 2)
void gemm_dp2(const u16* __restrict__ A, const u16* __restrict__ Bt,
              u16* __restrict__ Cb, float* __restrict__ Cf,
              const float* __restrict__ X, int M, int N, int K)
{
  constexpr int BN = 256;
  constexpr int MREP = BM / 32;      // 8 (BM=256) or 4 (BM=128)
  constexpr int A_SZ = BM * 32;      // u16 per A slot
  constexpr int B_SZ = BN * 32;
  constexpr int SLOT = A_SZ + B_SZ;
  constexpr int LA = BM / 128;       // A gld16 per thread per tile: 2 or 1
  __shared__ u16 lds[4 * SLOT];

  int nbx = gridDim.x;
  int wg = blockIdx.y * nbx + blockIdx.x;
  int nwg = nbx * gridDim.y;
  int cpx = nwg >> 3;
  int swz = (wg & 7) * cpx + (wg >> 3);   // grids are multiples of 8
  int bx = swz % nbx, by = swz / nbx;
  int m0 = by * BM, n0 = bx * BN;

  int tid = threadIdx.x;
  int l = tid & 63, w = tid >> 6;
  int l16 = l & 15, lg = l >> 4;
  int wr = w >> 2, wc = w & 3;            // 2M x 4N waves

  int aoff[MREP], boff[4];
  #pragma unroll
  for (int m = 0; m < MREP; m++) {
    int ar = wr * (BM / 2) + m * 16 + l16;
    aoff[m] = (ar * 32 + lg * 8) ^ ((ar & 7) * 8);
  }
  #pragma unroll
  for (int n = 0; n < 4; n++) {
    int bc = wc * 64 + n * 16 + l16;
    boff[n] = (bc * 32 + lg * 8) ^ ((bc & 7) * 8);
  }

  const u16* gA0; const u16* gA1; const u16* gB0; const u16* gB1;
  {
    int r, kc;
    swz_rc(tid, r, kc);
    gA0 = A + (size_t)(m0 + r) * K + kc * 8;
    gB0 = Bt + (size_t)(n0 + r) * K + kc * 8;
    swz_rc(tid + 512, r, kc);
    gB1 = Bt + (size_t)(n0 + r) * K + kc * 8;
    if (LA == 2) gA1 = A + (size_t)(m0 + r) * K + kc * 8;
    else gA1 = gA0;
  }

  const int NT = K >> 5;

  auto stage = [&](int t, int s4) {
    u16* s = lds + s4 * SLOT;
    gld16(gA0 + t * 32, s + tid * 8);
    if (LA == 2) gld16(gA1 + t * 32, s + (tid + 512) * 8);
    gld16(gB0 + t * 32, s + A_SZ + tid * 8);
    gld16(gB1 + t * 32, s + A_SZ + (tid + 512) * 8);
  };

  // prologue: stage tiles 0,1 into slots 0,1
  stage(0, 0);
  stage(1, 1);

  f32x4 acc[MREP][4];
  f32x4 zero = {0.f, 0.f, 0.f, 0.f};
  #pragma unroll
  for (int m = 0; m < MREP; m++)
    #pragma unroll
    for (int n = 0; n < 4; n++) acc[m][n] = zero;

  int slot = 0;
  for (int j = 0; j < NT; ++j) {
    // stage tile j+2 (distance 2), then counted vmcnt so tile j is landed
    if (j + 2 < NT) {
      stage(j + 2, (j + 2) & 3);
      if (LA == 2) asm volatile("s_waitcnt vmcnt(8)" ::: "memory");
      else         asm volatile("s_waitcnt vmcnt(6)" ::: "memory");
    } else if (j + 1 < NT) {
      if (LA == 2) asm volatile("s_waitcnt vmcnt(4)" ::: "memory");
      else         asm volatile("s_waitcnt vmcnt(3)" ::: "memory");
    } else {
      asm volatile("s_waitcnt vmcnt(0)" ::: "memory");
    }
    __builtin_amdgcn_s_barrier();
    asm volatile("" ::: "memory");   // keep frag reads below the barrier

    u16* As = lds + slot * SLOT;
    u16* Bs = As + A_SZ;
    bf16x8 bfr[4];
    #pragma unroll
    for (int n = 0; n < 4; n++) bfr[n] = *(const bf16x8*)(Bs + boff[n]);
    #pragma unroll
    for (int h = 0; h < MREP / 4; h++) {
      bf16x8 afr[4];
      #pragma unroll
      for (int m = 0; m < 4; m++) afr[m] = *(const bf16x8*)(As + aoff[h * 4 + m]);
      __builtin_amdgcn_s_setprio(1);
      #pragma unroll
      for (int m = 0; m < 4; m++)
        #pragma unroll
        for (int n = 0; n < 4; n++)
          acc[h * 4 + m][n] = mfma16(afr[m], bfr[n], acc[h * 4 + m][n]);
      __builtin_amdgcn_s_setprio(0);
    }
    slot = (slot + 1) & 3;
  }

  #pragma unroll
  for (int m = 0; m < MREP; m++) {
    int row = m0 + wr * (BM / 2) + m * 16 + lg * 4;
    #pragma unroll
    for (int n = 0; n < 4; n++) {
      int col = n0 + wc * 64 + n * 16 + l16;
      #pragma unroll
      for (int r = 0; r < 4; r++) {
        size_t idx = (size_t)(row + r) * N + col;
        float v = acc[m][n][r];
        if (EPI == 0) {
          Cb[idx] = f2bf(v);
        } else if (EPI == 1) {
          Cf[idx] = X[idx] + v;
        } else if (EPI == 2) {
          float gt = bf2f(Cb[idx]);
          float sg = gt / (1.0f + __expf(-gt));
          Cb[idx] = f2bf(sg * v);
        } else {
          Cf[idx] += v;
        }
      }
    }
  }
}

// ------------------- flash attention, sliding window + sink -----------------
__global__ __launch_bounds__(256)
void attn_k(const u16* __restrict__ qb, const u16* __restrict__ kb,
            const u16* __restrict__ vbt, u16* __restrict__ ao)
{
  int q0 = blockIdx.x * 128;
  int h = blockIdx.y;
  int b = blockIdx.z;
  int hk = h >> 2;
  int tid = threadIdx.x;
  int w = tid >> 6, l = tid & 63;
  int l16 = l & 15, lg = l >> 4;

  __shared__ u16 Ks[32 * 128];
  __shared__ u16 Vt[128 * 32];
  __shared__ u16 Ps[4][32 * 40];
  u16* Pw = Ps[w];

  bf16x8 qf[2][4];
  #pragma unroll
  for (int m = 0; m < 2; m++)
    #pragma unroll
    for (int kd = 0; kd < 4; kd++) {
      int row = q0 + w * 32 + m * 16 + l16;
      qf[m][kd] = *(const bf16x8*)(qb + (size_t)(b * SEQ + row) * (NH * HDIM)
                                   + h * HDIM + kd * 32 + lg * 8);
    }

  f32x4 oacc[2][8];
  float mrun[2][4], lrun[2][4];
  f32x4 zero = {0.f, 0.f, 0.f, 0.f};
  #pragma unroll
  for (int m = 0; m < 2; m++) {
    #pragma unroll
    for (int nd = 0; nd < 8; nd++) oacc[m][nd] = zero;
    #pragma unroll
    for (int r = 0; r < 4; r++) { mrun[m][r] = -1e9f; lrun[m][r] = 0.f; }
  }

  int kr0 = tid >> 4,        kc0 = (tid & 15) ^ (kr0 & 7);
  int kr1 = (tid + 256) >> 4, kc1 = (tid & 15) ^ (kr1 & 7);
  int vd0, vk0, vd1, vk1;
  swz_rc(tid, vd0, vk0);
  swz_rc(tid + 256, vd1, vk1);
  const u16* kbase = kb + (size_t)(b * SEQ) * (NKV * HDIM) + hk * HDIM;
  const u16* vbase = vbt + (size_t)(b * NKV + hk) * HDIM * SEQ;

  int koff[2][4];
  #pragma unroll
  for (int n = 0; n < 2; n++)
    #pragma unroll
    for (int kd = 0; kd < 4; kd++) {
      int key = n * 16 + l16;
      koff[n][kd] = ((key * 128) + kd * 32 + lg * 8) ^ ((key & 7) * 8);
    }
  int voff[8];
  #pragma unroll
  for (int nd = 0; nd < 8; nd++) {
    int d = nd * 16 + l16;
    voff[nd] = (d * 32 + lg * 8) ^ ((d & 7) * 8);
  }

  int lo = (q0 >= WIN) ? ((q0 - (WIN - 1)) >> 5) : 0;
  int hi = (q0 + 127) >> 5;

  for (int it = (lo > 0 ? lo - 1 : 0); it <= hi; ++it) {
    int kt = (it < lo) ? 0 : it;
    gld16(kbase + (size_t)(kt * 32 + kr0) * (NKV * HDIM) + kc0 * 8, Ks + tid * 8);
    gld16(kbase + (size_t)(kt * 32 + kr1) * (NKV * HDIM) + kc1 * 8, Ks + (tid + 256) * 8);
    gld16(vbase + (size_t)vd0 * SEQ + kt * 32 + vk0 * 8, Vt + tid * 8);
    gld16(vbase + (size_t)vd1 * SEQ + kt * 32 + vk1 * 8, Vt + (tid + 256) * 8);
    __syncthreads();

    f32x4 sacc[2][2];
    sacc[0][0] = zero; sacc[0][1] = zero; sacc[1][0] = zero; sacc[1][1] = zero;
    #pragma unroll
    for (int kd = 0; kd < 4; kd++) {
      bf16x8 kf0 = *(const bf16x8*)(Ks + koff[0][kd]);
      bf16x8 kf1 = *(const bf16x8*)(Ks + koff[1][kd]);
      #pragma unroll
      for (int m = 0; m < 2; m++) {
        sacc[m][0] = mfma16(qf[m][kd], kf0, sacc[m][0]);
        sacc[m][1] = mfma16(qf[m][kd], kf1, sacc[m][1]);
      }
    }

    #pragma unroll
    for (int m = 0; m < 2; m++) {
      float sc[4];
      #pragma unroll
      for (int r = 0; r < 4; r++) {
        int i = q0 + w * 32 + m * 16 + lg * 4 + r;
        int j0 = kt * 32 + l16;
        int j1 = j0 + 16;
        float s0 = sacc[m][0][r];
        float s1 = sacc[m][1][r];
        bool ok0 = (j0 <= i) && ((i - j0 < WIN) || (j0 < SINKN));
        bool ok1 = (j1 <= i) && ((i - j1 < WIN) || (j1 < SINKN));
        s0 = ok0 ? s0 : -1e9f;
        s1 = ok1 ? s1 : -1e9f;
        float mx = fmaxf(s0, s1);
        mx = fmaxf(mx, __shfl_xor(mx, 1));
        mx = fmaxf(mx, __shfl_xor(mx, 2));
        mx = fmaxf(mx, __shfl_xor(mx, 4));
        mx = fmaxf(mx, __shfl_xor(mx, 8));
        float mold = mrun[m][r];
        float mnew = fmaxf(mold, mx);
        float scl = __expf(mold - mnew);
        mrun[m][r] = mnew;
        float p0 = __expf(s0 - mnew);
        float p1 = __expf(s1 - mnew);
        int prow = m * 16 + lg * 4 + r;
        Pw[prow * 40 + l16] = f2bf(p0);
        Pw[prow * 40 + 16 + l16] = f2bf(p1);
        float ps = p0 + p1;
        ps += __shfl_xor(ps, 1);
        ps += __shfl_xor(ps, 2);
        ps += __shfl_xor(ps, 4);
        ps += __shfl_xor(ps, 8);
        lrun[m][r] = lrun[m][r] * scl + ps;
        sc[r] = scl;
      }
      #pragma unroll
      for (int nd = 0; nd < 8; nd++) {
        oacc[m][nd][0] *= sc[0];
        oacc[m][nd][1] *= sc[1];
        oacc[m][nd][2] *= sc[2];
        oacc[m][nd][3] *= sc[3];
      }
    }

    bf16x8 pa0 = *(const bf16x8*)(Pw + l16 * 40 + lg * 8);
    bf16x8 pa1 = *(const bf16x8*)(Pw + (16 + l16) * 40 + lg * 8);
    #pragma unroll
    for (int nd = 0; nd < 8; nd++) {
      bf16x8 vf = *(const bf16x8*)(Vt + voff[nd]);
      oacc[0][nd] = mfma16(pa0, vf, oacc[0][nd]);
      oacc[1][nd] = mfma16(pa1, vf, oacc[1][nd]);
    }
    __syncthreads();
  }

  #pragma unroll
  for (int m = 0; m < 2; m++)
    #pragma unroll
    for (int r = 0; r < 4; r++) {
      float invl = 1.0f / lrun[m][r];
      int row = q0 + w * 32 + m * 16 + lg * 4 + r;
      #pragma unroll
      for (int nd = 0; nd < 8; nd++) {
        int col = nd * 16 + l16;
        ao[(size_t)(b * SEQ + row) * (NH * HDIM) + h * HDIM + col] =
            f2bf(oacc[m][nd][r] * invl);
      }
    }
}

// ------------------------------- launcher -----------------------------------
extern "C" void kernel_launch(void* const* d_in, const int* in_sizes, int n_in,
                              void* d_out, int out_size, void* d_ws, size_t ws_size,
                              hipStream_t stream)
{
  (void)in_sizes; (void)n_in; (void)out_size;
  const float* x  = (const float*)d_in[0];
  const float* g1 = (const float*)d_in[1];
  const float* g2 = (const float*)d_in[2];
  const float* wq = (const float*)d_in[3];
  const float* wk = (const float*)d_in[4];
  const float* wv = (const float*)d_in[5];
  const float* wo = (const float*)d_in[6];
  const float* wg = (const float*)d_in[7];
  const float* wu = (const float*)d_in[8];
  const float* wd = (const float*)d_in[9];
  float* out = (float*)d_out;

  char* ws = (char*)d_ws;
  size_t off = 0;
  auto alloc = [&](size_t bytes) {
    char* p = ws + off;
    off += (bytes + 255) & ~(size_t)255;
    return p;
  };
  u16* wq_t = (u16*)alloc((size_t)DM * DM * 2);
  u16* wk_t = (u16*)alloc((size_t)(NKV * HDIM) * DM * 2);
  u16* wv_t = (u16*)alloc((size_t)(NKV * HDIM) * DM * 2);
  u16* wo_t = (u16*)alloc((size_t)DM * DM * 2);
  u16* wg_t = (u16*)alloc((size_t)HID * DM * 2);
  u16* wu_t = (u16*)alloc((size_t)HID * DM * 2);
  u16* wd_t = (u16*)alloc((size_t)DM * HID * 2);
  u16* hb   = (u16*)alloc((size_t)TOK * DM * 2);
  u16* qb   = (u16*)alloc((size_t)TOK * NH * HDIM * 2);
  u16* kb   = (u16*)alloc((size_t)TOK * NKV * HDIM * 2);
  u16* vb   = (u16*)alloc((size_t)TOK * NKV * HDIM * 2);
  u16* vbt  = (u16*)alloc((size_t)TOK * NKV * HDIM * 2);
  u16* aob  = (u16*)alloc((size_t)TOK * NH * HDIM * 2);
  u16* gu   = (u16*)alloc((size_t)TOK * HID * 2);
  float* ct = (float*)alloc((size_t)SEQ * 64 * 4);
  float* st = (float*)alloc((size_t)SEQ * 64 * 4);
  if (off > ws_size) return;

  dim3 blk(256);
  dim3 blk512(512);

  wtrans<<<dim3(DM / 32, DM / 32), blk, 0, stream>>>(wq, wq_t, DM, DM);
  wtrans<<<dim3((NKV * HDIM) / 32, DM / 32), blk, 0, stream>>>(wk, wk_t, DM, NKV * HDIM);
  wtrans<<<dim3((NKV * HDIM) / 32, DM / 32), blk, 0, stream>>>(wv, wv_t, DM, NKV * HDIM);
  wtrans<<<dim3(DM / 32, DM / 32), blk, 0, stream>>>(wo, wo_t, DM, DM);
  wtrans<<<dim3(HID / 32, DM / 32), blk, 0, stream>>>(wg, wg_t, DM, HID);
  wtrans<<<dim3(HID / 32, DM / 32), blk, 0, stream>>>(wu, wu_t, DM, HID);
  wtrans<<<dim3(DM / 32, HID / 32), blk, 0, stream>>>(wd, wd_t, HID, DM);

  rope_table_k<<<SEQ * 64 / 256, blk, 0, stream>>>(ct, st);
  rmsnorm_k<<<TOK, blk, 0, stream>>>(x, g1, hb);

  gemm_dp2<128, 0><<<dim3(DM / 256, TOK / 128), blk512, 0, stream>>>(hb, wq_t, qb, nullptr, nullptr, TOK, DM, DM);
  gemm128<0><<<dim3((NKV * HDIM) / 128, TOK / 128), blk, 0, stream>>>(hb, wk_t, kb, nullptr, nullptr, TOK, NKV * HDIM, DM);
  gemm128<0><<<dim3((NKV * HDIM) / 128, TOK / 128), blk, 0, stream>>>(hb, wv_t, vb, nullptr, nullptr, TOK, NKV * HDIM, DM);

  rope_apply_k<<<TOK, dim3(NH * 64), 0, stream>>>(qb, ct, st, 0.08838834764831845f);
  rope_apply_k<<<TOK, dim3(NKV * 64), 0, stream>>>(kb, ct, st, 1.0f);
  vtrans<<<dim3((NKV * HDIM) / 32, TOK / 32), blk, 0, stream>>>(vb, vbt);

  attn_k<<<dim3(SEQ / 128, NH, 2), blk, 0, stream>>>(qb, kb, vbt, aob);

  gemm_dp2<128, 1><<<dim3(DM / 256, TOK / 128), blk512, 0, stream>>>(aob, wo_t, nullptr, out, x, TOK, DM, DM);
  rmsnorm_k<<<TOK, blk, 0, stream>>>(out, g2, hb);
  gemm_dp2<256, 0><<<dim3(HID / 256, TOK / 256), blk512, 0, stream>>>(hb, wg_t, gu, nullptr, nullptr, TOK, HID, DM);
  gemm_dp2<256, 2><<<dim3(HID / 256, TOK / 256), blk512, 0, stream>>>(hb, wu_t, gu, nullptr, nullptr, TOK, HID, DM);
  gemm_dp2<128, 3><<<dim3(DM / 256, TOK / 128), blk512, 0, stream>>>(gu, wd_t, nullptr, out, nullptr, TOK, DM, HID);
}

// Round 4
// 957.217 us; speedup vs baseline: 1.2098x; 1.0131x over previous
//
#include <hip/hip_runtime.h>
#include <hip/hip_bf16.h>
#include <stdint.h>

#define TOK 4096
#define SEQ 2048
#define DM 2048
#define NH 16
#define NKV 4
#define HDIM 128
#define HID 8192
#define WIN 1024
#define SINKN 4

typedef float f32x4 __attribute__((ext_vector_type(4)));
typedef __bf16 bf16x8 __attribute__((ext_vector_type(8)));
typedef unsigned short u16;
typedef unsigned int u32;

#define VM(n) asm volatile("s_waitcnt vmcnt(" #n ")" ::: "memory")

__device__ __forceinline__ u16 f2bf(float f) {
  union { float f; u32 u; } v; v.f = f;
  return (u16)((v.u + 0x7fffu + ((v.u >> 16) & 1u)) >> 16);
}
__device__ __forceinline__ float bf2f(u16 h) {
  union { u32 u; float f; } v; v.u = ((u32)h) << 16;
  return v.f;
}
__device__ __forceinline__ f32x4 mfma16(bf16x8 a, bf16x8 b, f32x4 c) {
  return __builtin_amdgcn_mfma_f32_16x16x32_bf16(a, b, c, 0, 0, 0);
}
__device__ __forceinline__ void gld16(const u16* g, u16* l) {
  __builtin_amdgcn_global_load_lds(
      (const __attribute__((address_space(1))) u32*)g,
      (__attribute__((address_space(3))) u32*)l, 16, 0, 0);
}
__device__ __forceinline__ void bar() {
  asm volatile("s_barrier" ::: "memory");
}
// Inverse swizzle for 64B-row tiles ([rows][32] u16), read addr ^= ((row&7)*8) u16.
// chunk c (16B units) -> (row, k8chunk) global source (rule #21).
__device__ __forceinline__ void swz_rc(int c, int& row, int& k8) {
  row = 2 * (c >> 3) + (((c >> 2) & 1) ^ ((c >> 4) & 1));
  k8 = (c & 3) ^ (row & 3);
}

// ---------------- weight transpose fp32[K][N] -> bf16[N][K] ----------------
__global__ __launch_bounds__(256)
void wtrans(const float* __restrict__ in, u16* __restrict__ out, int K, int N)
{
  __shared__ float t[32][33];
  int tx = threadIdx.x & 31, ty = threadIdx.x >> 5;
  int bx = blockIdx.x, by = blockIdx.y;
  #pragma unroll
  for (int i = 0; i < 4; i++) {
    int r = ty + i * 8;
    t[r][tx] = in[(size_t)(by * 32 + r) * N + bx * 32 + tx];
  }
  __syncthreads();
  #pragma unroll
  for (int i = 0; i < 4; i++) {
    int r = ty + i * 8;
    out[(size_t)(bx * 32 + r) * K + by * 32 + tx] = f2bf(t[tx][r]);
  }
}

// ---- V transpose: bf16 [4096][ld] cols -> [(b*4+hk)*128+d][2048] -----------
__global__ __launch_bounds__(256)
void vtrans(const u16* __restrict__ in, int ld, u16* __restrict__ out)
{
  __shared__ u16 t[32][33];
  int tx = threadIdx.x & 31, ty = threadIdx.x >> 5;
  int bx = blockIdx.x;
  int by = blockIdx.y;
  #pragma unroll
  for (int i = 0; i < 4; i++) {
    int r = ty + i * 8;
    t[r][tx] = in[(size_t)(by * 32 + r) * ld + bx * 32 + tx];
  }
  __syncthreads();
  int b = (by * 32) >> 11;
  int s0 = (by * 32) & (SEQ - 1);
  #pragma unroll
  for (int i = 0; i < 4; i++) {
    int c = bx * 32 + ty + i * 8;
    out[(size_t)(b * (NKV * HDIM) + c) * SEQ + s0 + tx] = t[tx][ty + i * 8];
  }
}

// ---------------------------- RoPE table -----------------------------------
__global__ __launch_bounds__(256)
void rope_table_k(float* __restrict__ ct, float* __restrict__ st)
{
  int idx = blockIdx.x * 256 + threadIdx.x;
  int pos = idx >> 6, d = idx & 63;
  float inv = powf(10000.0f, -(float)d / 64.0f);
  float a = (float)pos * inv;
  ct[idx] = cosf(a);
  st[idx] = sinf(a);
}

// ----------------------- RoPE apply (in place, bf16) ------------------------
__global__ void rope_apply_k(u16* __restrict__ q, int ld,
                             const float* __restrict__ ct,
                             const float* __restrict__ st, float scale)
{
  int t = blockIdx.x;
  int hh = threadIdx.x >> 6;
  int d = threadIdx.x & 63;
  int pos = t & (SEQ - 1);
  size_t base = (size_t)t * ld + hh * HDIM + d;
  float x1 = bf2f(q[base]), x2 = bf2f(q[base + 64]);
  float c = ct[pos * 64 + d], s = st[pos * 64 + d];
  q[base]      = f2bf((x1 * c - x2 * s) * scale);
  q[base + 64] = f2bf((x2 * c + x1 * s) * scale);
}

// ------------------------------ RMSNorm ------------------------------------
__global__ __launch_bounds__(256)
void rmsnorm_k(const float* __restrict__ x, const float* __restrict__ g,
               u16* __restrict__ o)
{
  int row = blockIdx.x;
  int tid = threadIdx.x;
  const float* xr = x + (size_t)row * DM;
  float4 v0 = *(const float4*)(xr + tid * 8);
  float4 v1 = *(const float4*)(xr + tid * 8 + 4);
  float ss = v0.x*v0.x + v0.y*v0.y + v0.z*v0.z + v0.w*v0.w
           + v1.x*v1.x + v1.y*v1.y + v1.z*v1.z + v1.w*v1.w;
  #pragma unroll
  for (int d = 1; d < 64; d <<= 1) ss += __shfl_xor(ss, d);
  __shared__ float red[4];
  if ((tid & 63) == 0) red[tid >> 6] = ss;
  __syncthreads();
  float inv = rsqrtf((red[0] + red[1] + red[2] + red[3]) * (1.0f / DM) + 1e-6f);
  float4 g0 = *(const float4*)(g + tid * 8);
  float4 g1 = *(const float4*)(g + tid * 8 + 4);
  ushort4 o0, o1;
  o0.x = f2bf(v0.x * inv * g0.x); o0.y = f2bf(v0.y * inv * g0.y);
  o0.z = f2bf(v0.z * inv * g0.z); o0.w = f2bf(v0.w * inv * g0.w);
  o1.x = f2bf(v1.x * inv * g1.x); o1.y = f2bf(v1.y * inv * g1.y);
  o1.z = f2bf(v1.z * inv * g1.z); o1.w = f2bf(v1.w * inv * g1.w);
  *(ushort4*)(o + (size_t)row * DM + tid * 8) = o0;
  *(ushort4*)(o + (size_t)row * DM + tid * 8 + 4) = o1;
}

// --------------------- 128x128 bf16 GEMM (small-N path) ---------------------
template<int EPI>
__global__ __launch_bounds__(256)
void gemm128(const u16* __restrict__ A, const u16* __restrict__ Bt,
             u16* __restrict__ Cb, float* __restrict__ Cf,
             const float* __restrict__ X, int M, int N, int K)
{
  __shared__ u16 As[128 * 32];
  __shared__ u16 Bs[128 * 32];
  int nbx = gridDim.x;
  int wg = blockIdx.y * nbx + blockIdx.x;
  int nwg = nbx * gridDim.y;
  int cpx = nwg >> 3;
  int swz = (wg & 7) * cpx + (wg >> 3);
  int bx = swz % nbx, by = swz / nbx;
  int m0 = by * 128, n0 = bx * 128;
  int tid = threadIdx.x;
  int l = tid & 63, w = tid >> 6;
  int l16 = l & 15, lg = l >> 4;
  int wr = w >> 1, wc = w & 1;

  int r0, c0, r1, c1;
  swz_rc(tid, r0, c0);
  swz_rc(tid + 256, r1, c1);
  const u16* ga0 = A + (size_t)(m0 + r0) * K + c0 * 8;
  const u16* ga1 = A + (size_t)(m0 + r1) * K + c1 * 8;
  const u16* gb0 = Bt + (size_t)(n0 + r0) * K + c0 * 8;
  const u16* gb1 = Bt + (size_t)(n0 + r1) * K + c1 * 8;
  u16* lA0 = As + tid * 8;
  u16* lA1 = As + (tid + 256) * 8;
  u16* lB0 = Bs + tid * 8;
  u16* lB1 = Bs + (tid + 256) * 8;

  f32x4 acc[4][4];
  f32x4 zero = {0.f, 0.f, 0.f, 0.f};
  #pragma unroll
  for (int m = 0; m < 4; m++)
    #pragma unroll
    for (int n = 0; n < 4; n++) acc[m][n] = zero;

  int aoff[4], boff[4];
  #pragma unroll
  for (int i = 0; i < 4; i++) {
    int ra = wr * 64 + i * 16 + l16;
    aoff[i] = (ra * 32 + lg * 8) ^ ((ra & 7) * 8);
    int rb = wc * 64 + i * 16 + l16;
    boff[i] = (rb * 32 + lg * 8) ^ ((rb & 7) * 8);
  }

  for (int k0 = 0; k0 < K; k0 += 32) {
    gld16(ga0 + k0, lA0);
    gld16(ga1 + k0, lA1);
    gld16(gb0 + k0, lB0);
    gld16(gb1 + k0, lB1);
    __syncthreads();
    bf16x8 af[4], bfr[4];
    #pragma unroll
    for (int i = 0; i < 4; i++) af[i] = *(const bf16x8*)(As + aoff[i]);
    #pragma unroll
    for (int i = 0; i < 4; i++) bfr[i] = *(const bf16x8*)(Bs + boff[i]);
    #pragma unroll
    for (int m = 0; m < 4; m++)
      #pragma unroll
      for (int n = 0; n < 4; n++)
        acc[m][n] = mfma16(af[m], bfr[n], acc[m][n]);
    __syncthreads();
  }

  #pragma unroll
  for (int m = 0; m < 4; m++) {
    int row = m0 + wr * 64 + m * 16 + lg * 4;
    #pragma unroll
    for (int n = 0; n < 4; n++) {
      int col = n0 + wc * 64 + n * 16 + l16;
      #pragma unroll
      for (int r = 0; r < 4; r++) {
        size_t idx = (size_t)(row + r) * N + col;
        float v = acc[m][n][r];
        if (EPI == 0) {
          Cb[idx] = f2bf(v);
        } else if (EPI == 1) {
          Cf[idx] = X[idx] + v;
        } else if (EPI == 2) {
          float gt = bf2f(Cb[idx]);
          float sg = gt / (1.0f + __expf(-gt));
          Cb[idx] = f2bf(sg * v);
        } else {
          Cf[idx] += v;
        }
      }
    }
  }
}

// ---------------- 8-phase pipelined GEMM: BM x 256, BK=32 -------------------
// 4-slot LDS ring, stage distance 3, 2 phases per K-tile (nh=0/1).
// Per phase: stage half -> ds_read frags -> s_barrier -> lgkmcnt(0) ->
// sched_barrier -> setprio(1) -> MREP*2 MFMA -> setprio(0) -> s_barrier.
// vmcnt ONCE per K-tile (phase 1): steady 8 (BM=256) / 6 (BM=128), never 0
// mid-loop. Ledger: at ph1(j) after issuing SB(j+3), outstanding allowed =
// tiles j+2,j+3 halves; tile j+1 (read next iter) guaranteed landed.
template<int BM, int EPI>
__global__ __launch_bounds__(512, 2)
void gemm8(const u16* __restrict__ A, const u16* __restrict__ Bt,
           u16* __restrict__ Cb, float* __restrict__ Cf,
           const float* __restrict__ X, int M, int N, int K)
{
  constexpr int BN = 256;
  constexpr int MREP = BM / 32;       // 8 or 4
  constexpr int ASZ = BM * 32;        // u16 per A half-tile
  constexpr int SLOT = ASZ + BN * 32;
  __shared__ u16 lds[4 * SLOT];

  int nbx = gridDim.x;
  int wg = blockIdx.y * nbx + blockIdx.x;
  int nwg = nbx * gridDim.y;
  int cpx = nwg >> 3;
  int swz = (wg & 7) * cpx + (wg >> 3);   // grids are multiples of 8
  int bx = swz % nbx, by = swz / nbx;
  int m0 = by * BM, n0 = bx * BN;

  int tid = threadIdx.x;
  int l = tid & 63, w = tid >> 6;
  int l16 = l & 15, lg = l >> 4;
  int wr = w >> 2, wc = w & 3;            // 2M x 4N waves

  int aoff[MREP], boff[4];
  #pragma unroll
  for (int m = 0; m < MREP; m++) {
    int ar = wr * (BM / 2) + m * 16 + l16;
    aoff[m] = (ar * 32 + lg * 8) ^ ((ar & 7) * 8);
  }
  #pragma unroll
  for (int n = 0; n < 4; n++) {
    int br = wc * 64 + n * 16 + l16;
    boff[n] = ASZ + ((br * 32 + lg * 8) ^ ((br & 7) * 8));
  }

  // staging sources (pre-swizzled global, rule #21)
  const u16 *srcA0, *srcA1, *srcB0, *srcB1;
  {
    int r, kc;
    swz_rc(tid, r, kc);
    srcA0 = A + (size_t)(m0 + r) * K + kc * 8;
    srcB0 = Bt + (size_t)(n0 + r) * K + kc * 8;
    swz_rc(tid + 512, r, kc);
    srcB1 = Bt + (size_t)(n0 + r) * K + kc * 8;
    srcA1 = (BM == 256) ? (A + (size_t)(m0 + r) * K + kc * 8) : srcA0;
  }

  const int NT = K >> 5;

  auto stageA = [&](int t) {
    u16* d = lds + (t & 3) * SLOT;
    gld16(srcA0 + t * 32, d + tid * 8);
    if constexpr (BM == 256) gld16(srcA1 + t * 32, d + (tid + 512) * 8);
  };
  auto stageB = [&](int t) {
    u16* d = lds + (t & 3) * SLOT + ASZ;
    gld16(srcB0 + t * 32, d + tid * 8);
    gld16(srcB1 + t * 32, d + (tid + 512) * 8);
  };

  // prologue: tiles 0,1,2 (oldest-first so vmcnt counts work)
  stageA(0); stageB(0); stageA(1); stageB(1); stageA(2); stageB(2);
  if constexpr (BM == 256) VM(8); else VM(6);   // tile 0 landed
  bar();

  f32x4 acc[MREP][4];
  f32x4 zero = {0.f, 0.f, 0.f, 0.f};
  #pragma unroll
  for (int m = 0; m < MREP; m++)
    #pragma unroll
    for (int n = 0; n < 4; n++) acc[m][n] = zero;

  for (int j = 0; j < NT; ++j) {
    u16* cur = lds + (j & 3) * SLOT;
    const bool st = (j + 3 < NT);

    // ---------------- phase 0 (nh = 0) ----------------
    if (st) stageA(j + 3);
    bf16x8 a[MREP], b0, b1;
    #pragma unroll
    for (int mf = 0; mf < MREP; mf++) a[mf] = *(const bf16x8*)(cur + aoff[mf]);
    b0 = *(const bf16x8*)(cur + boff[0]);
    b1 = *(const bf16x8*)(cur + boff[1]);
    bar();
    asm volatile("s_waitcnt lgkmcnt(0)" ::: "memory");
    __builtin_amdgcn_sched_barrier(0);
    __builtin_amdgcn_s_setprio(1);
    #pragma unroll
    for (int mf = 0; mf < MREP; mf++) {
      acc[mf][0] = mfma16(a[mf], b0, acc[mf][0]);
      acc[mf][1] = mfma16(a[mf], b1, acc[mf][1]);
    }
    __builtin_amdgcn_s_setprio(0);
    __builtin_amdgcn_sched_barrier(0);
    bar();

    // ---------------- phase 1 (nh = 1) ----------------
    if (st) stageB(j + 3);
    b0 = *(const bf16x8*)(cur + boff[2]);
    b1 = *(const bf16x8*)(cur + boff[3]);
    if constexpr (BM == 256) {
      if (st) VM(8); else if (j + 2 < NT) VM(4); else VM(0);
    } else {
      if (st) VM(6); else if (j + 2 < NT) VM(3); else VM(0);
    }
    bar();
    asm volatile("s_waitcnt lgkmcnt(0)" ::: "memory");
    __builtin_amdgcn_sched_barrier(0);
    __builtin_amdgcn_s_setprio(1);
    #pragma unroll
    for (int mf = 0; mf < MREP; mf++) {
      acc[mf][2] = mfma16(a[mf], b0, acc[mf][2]);
      acc[mf][3] = mfma16(a[mf], b1, acc[mf][3]);
    }
    __builtin_amdgcn_s_setprio(0);
    __builtin_amdgcn_sched_barrier(0);
    bar();
  }

  #pragma unroll
  for (int m = 0; m < MREP; m++) {
    int row = m0 + wr * (BM / 2) + m * 16 + lg * 4;
    #pragma unroll
    for (int n = 0; n < 4; n++) {
      int col = n0 + wc * 64 + n * 16 + l16;
      #pragma unroll
      for (int r = 0; r < 4; r++) {
        size_t idx = (size_t)(row + r) * N + col;
        float v = acc[m][n][r];
        if (EPI == 0) {
          Cb[idx] = f2bf(v);
        } else if (EPI == 1) {
          Cf[idx] = X[idx] + v;
        } else if (EPI == 2) {
          float gt = bf2f(Cb[idx]);
          float sg = gt / (1.0f + __expf(-gt));
          Cb[idx] = f2bf(sg * v);
        } else {
          Cf[idx] += v;
        }
      }
    }
  }
}

// ------------------- flash attention, sliding window + sink -----------------
__global__ __launch_bounds__(256)
void attn_k(const u16* __restrict__ qb, const u16* __restrict__ kb, int ldk,
            const u16* __restrict__ vbt, u16* __restrict__ ao)
{
  int q0 = blockIdx.x * 128;
  int h = blockIdx.y;
  int b = blockIdx.z;
  int hk = h >> 2;
  int tid = threadIdx.x;
  int w = tid >> 6, l = tid & 63;
  int l16 = l & 15, lg = l >> 4;

  __shared__ u16 Ks[32 * 128];
  __shared__ u16 Vt[128 * 32];
  __shared__ u16 Ps[4][32 * 40];
  u16* Pw = Ps[w];

  bf16x8 qf[2][4];
  #pragma unroll
  for (int m = 0; m < 2; m++)
    #pragma unroll
    for (int kd = 0; kd < 4; kd++) {
      int row = q0 + w * 32 + m * 16 + l16;
      qf[m][kd] = *(const bf16x8*)(qb + (size_t)(b * SEQ + row) * (NH * HDIM)
                                   + h * HDIM + kd * 32 + lg * 8);
    }

  f32x4 oacc[2][8];
  float mrun[2][4], lrun[2][4];
  f32x4 zero = {0.f, 0.f, 0.f, 0.f};
  #pragma unroll
  for (int m = 0; m < 2; m++) {
    #pragma unroll
    for (int nd = 0; nd < 8; nd++) oacc[m][nd] = zero;
    #pragma unroll
    for (int r = 0; r < 4; r++) { mrun[m][r] = -1e9f; lrun[m][r] = 0.f; }
  }

  int kr0 = tid >> 4,        kc0 = (tid & 15) ^ (kr0 & 7);
  int kr1 = (tid + 256) >> 4, kc1 = (tid & 15) ^ (kr1 & 7);
  int vd0, vk0, vd1, vk1;
  swz_rc(tid, vd0, vk0);
  swz_rc(tid + 256, vd1, vk1);
  const u16* kbase = kb + (size_t)(b * SEQ) * ldk + hk * HDIM;
  const u16* vbase = vbt + (size_t)(b * NKV + hk) * HDIM * SEQ;

  int koff[2][4];
  #pragma unroll
  for (int n = 0; n < 2; n++)
    #pragma unroll
    for (int kd = 0; kd < 4; kd++) {
      int key = n * 16 + l16;
      koff[n][kd] = ((key * 128) + kd * 32 + lg * 8) ^ ((key & 7) * 8);
    }
  int voff[8];
  #pragma unroll
  for (int nd = 0; nd < 8; nd++) {
    int d = nd * 16 + l16;
    voff[nd] = (d * 32 + lg * 8) ^ ((d & 7) * 8);
  }

  int lo = (q0 >= WIN) ? ((q0 - (WIN - 1)) >> 5) : 0;
  int hi = (q0 + 127) >> 5;

  for (int it = (lo > 0 ? lo - 1 : 0); it <= hi; ++it) {
    int kt = (it < lo) ? 0 : it;
    gld16(kbase + (size_t)(kt * 32 + kr0) * ldk + kc0 * 8, Ks + tid * 8);
    gld16(kbase + (size_t)(kt * 32 + kr1) * ldk + kc1 * 8, Ks + (tid + 256) * 8);
    gld16(vbase + (size_t)vd0 * SEQ + kt * 32 + vk0 * 8, Vt + tid * 8);
    gld16(vbase + (size_t)vd1 * SEQ + kt * 32 + vk1 * 8, Vt + (tid + 256) * 8);
    __syncthreads();

    f32x4 sacc[2][2];
    sacc[0][0] = zero; sacc[0][1] = zero; sacc[1][0] = zero; sacc[1][1] = zero;
    #pragma unroll
    for (int kd = 0; kd < 4; kd++) {
      bf16x8 kf0 = *(const bf16x8*)(Ks + koff[0][kd]);
      bf16x8 kf1 = *(const bf16x8*)(Ks + koff[1][kd]);
      #pragma unroll
      for (int m = 0; m < 2; m++) {
        sacc[m][0] = mfma16(qf[m][kd], kf0, sacc[m][0]);
        sacc[m][1] = mfma16(qf[m][kd], kf1, sacc[m][1]);
      }
    }

    #pragma unroll
    for (int m = 0; m < 2; m++) {
      float sc[4];
      #pragma unroll
      for (int r = 0; r < 4; r++) {
        int i = q0 + w * 32 + m * 16 + lg * 4 + r;
        int j0 = kt * 32 + l16;
        int j1 = j0 + 16;
        float s0 = sacc[m][0][r];
        float s1 = sacc[m][1][r];
        bool ok0 = (j0 <= i) && ((i - j0 < WIN) || (j0 < SINKN));
        bool ok1 = (j1 <= i) && ((i - j1 < WIN) || (j1 < SINKN));
        s0 = ok0 ? s0 : -1e9f;
        s1 = ok1 ? s1 : -1e9f;
        float mx = fmaxf(s0, s1);
        mx = fmaxf(mx, __shfl_xor(mx, 1));
        mx = fmaxf(mx, __shfl_xor(mx, 2));
        mx = fmaxf(mx, __shfl_xor(mx, 4));
        mx = fmaxf(mx, __shfl_xor(mx, 8));
        float mold = mrun[m][r];
        float mnew = fmaxf(mold, mx);
        float scl = __expf(mold - mnew);
        mrun[m][r] = mnew;
        float p0 = __expf(s0 - mnew);
        float p1 = __expf(s1 - mnew);
        int prow = m * 16 + lg * 4 + r;
        Pw[prow * 40 + l16] = f2bf(p0);
        Pw[prow * 40 + 16 + l16] = f2bf(p1);
        float ps = p0 + p1;
        ps += __shfl_xor(ps, 1);
        ps += __shfl_xor(ps, 2);
        ps += __shfl_xor(ps, 4);
        ps += __shfl_xor(ps, 8);
        lrun[m][r] = lrun[m][r] * scl + ps;
        sc[r] = scl;
      }
      #pragma unroll
      for (int nd = 0; nd < 8; nd++) {
        oacc[m][nd][0] *= sc[0];
        oacc[m][nd][1] *= sc[1];
        oacc[m][nd][2] *= sc[2];
        oacc[m][nd][3] *= sc[3];
      }
    }

    bf16x8 pa0 = *(const bf16x8*)(Pw + l16 * 40 + lg * 8);
    bf16x8 pa1 = *(const bf16x8*)(Pw + (16 + l16) * 40 + lg * 8);
    #pragma unroll
    for (int nd = 0; nd < 8; nd++) {
      bf16x8 vf = *(const bf16x8*)(Vt + voff[nd]);
      oacc[0][nd] = mfma16(pa0, vf, oacc[0][nd]);
      oacc[1][nd] = mfma16(pa1, vf, oacc[1][nd]);
    }
    __syncthreads();
  }

  #pragma unroll
  for (int m = 0; m < 2; m++)
    #pragma unroll
    for (int r = 0; r < 4; r++) {
      float invl = 1.0f / lrun[m][r];
      int row = q0 + w * 32 + m * 16 + lg * 4 + r;
      #pragma unroll
      for (int nd = 0; nd < 8; nd++) {
        int col = nd * 16 + l16;
        ao[(size_t)(b * SEQ + row) * (NH * HDIM) + h * HDIM + col] =
            f2bf(oacc[m][nd][r] * invl);
      }
    }
}

// ------------------------------- launcher -----------------------------------
extern "C" void kernel_launch(void* const* d_in, const int* in_sizes, int n_in,
                              void* d_out, int out_size, void* d_ws, size_t ws_size,
                              hipStream_t stream)
{
  (void)in_sizes; (void)n_in; (void)out_size;
  const float* x  = (const float*)d_in[0];
  const float* g1 = (const float*)d_in[1];
  const float* g2 = (const float*)d_in[2];
  const float* wq = (const float*)d_in[3];
  const float* wk = (const float*)d_in[4];
  const float* wv = (const float*)d_in[5];
  const float* wo = (const float*)d_in[6];
  const float* wg = (const float*)d_in[7];
  const float* wu = (const float*)d_in[8];
  const float* wd = (const float*)d_in[9];
  float* out = (float*)d_out;

  char* ws = (char*)d_ws;
  size_t off = 0;
  auto alloc = [&](size_t bytes) {
    char* p = ws + off;
    off += (bytes + 255) & ~(size_t)255;
    return p;
  };
  u16* wq_t  = (u16*)alloc((size_t)DM * DM * 2);
  u16* wkv_t = (u16*)alloc((size_t)(2 * NKV * HDIM) * DM * 2);   // K rows 0-511, V rows 512-1023
  u16* wo_t  = (u16*)alloc((size_t)DM * DM * 2);
  u16* wg_t  = (u16*)alloc((size_t)HID * DM * 2);
  u16* wu_t  = (u16*)alloc((size_t)HID * DM * 2);
  u16* wd_t  = (u16*)alloc((size_t)DM * HID * 2);
  u16* hb    = (u16*)alloc((size_t)TOK * DM * 2);
  u16* qb    = (u16*)alloc((size_t)TOK * NH * HDIM * 2);
  u16* kvb   = (u16*)alloc((size_t)TOK * 2 * NKV * HDIM * 2);    // [tok][1024]: k | v
  u16* vbt   = (u16*)alloc((size_t)TOK * NKV * HDIM * 2);
  u16* aob   = (u16*)alloc((size_t)TOK * NH * HDIM * 2);
  u16* gu    = (u16*)alloc((size_t)TOK * HID * 2);
  float* ct  = (float*)alloc((size_t)SEQ * 64 * 4);
  float* st  = (float*)alloc((size_t)SEQ * 64 * 4);
  if (off > ws_size) return;

  dim3 blk(256);
  dim3 blk512(512);
  const int KV = 2 * NKV * HDIM;   // 1024

  wtrans<<<dim3(DM / 32, DM / 32), blk, 0, stream>>>(wq, wq_t, DM, DM);
  wtrans<<<dim3((NKV * HDIM) / 32, DM / 32), blk, 0, stream>>>(wk, wkv_t, DM, NKV * HDIM);
  wtrans<<<dim3((NKV * HDIM) / 32, DM / 32), blk, 0, stream>>>(wv, wkv_t + (size_t)(NKV * HDIM) * DM, DM, NKV * HDIM);
  wtrans<<<dim3(DM / 32, DM / 32), blk, 0, stream>>>(wo, wo_t, DM, DM);
  wtrans<<<dim3(HID / 32, DM / 32), blk, 0, stream>>>(wg, wg_t, DM, HID);
  wtrans<<<dim3(HID / 32, DM / 32), blk, 0, stream>>>(wu, wu_t, DM, HID);
  wtrans<<<dim3(DM / 32, HID / 32), blk, 0, stream>>>(wd, wd_t, HID, DM);

  rope_table_k<<<SEQ * 64 / 256, blk, 0, stream>>>(ct, st);
  rmsnorm_k<<<TOK, blk, 0, stream>>>(x, g1, hb);

  gemm8<128, 0><<<dim3(DM / 256, TOK / 128), blk512, 0, stream>>>(hb, wq_t, qb, nullptr, nullptr, TOK, DM, DM);
  gemm128<0><<<dim3(KV / 128, TOK / 128), blk, 0, stream>>>(hb, wkv_t, kvb, nullptr, nullptr, TOK, KV, DM);

  rope_apply_k<<<TOK, dim3(NH * 64), 0, stream>>>(qb, NH * HDIM, ct, st, 0.08838834764831845f);
  rope_apply_k<<<TOK, dim3(NKV * 64), 0, stream>>>(kvb, KV, ct, st, 1.0f);
  vtrans<<<dim3((NKV * HDIM) / 32, TOK / 32), blk, 0, stream>>>(kvb + NKV * HDIM, KV, vbt);

  attn_k<<<dim3(SEQ / 128, NH, 2), blk, 0, stream>>>(qb, kvb, KV, vbt, aob);

  gemm8<128, 1><<<dim3(DM / 256, TOK / 128), blk512, 0, stream>>>(aob, wo_t, nullptr, out, x, TOK, DM, DM);
  rmsnorm_k<<<TOK, blk, 0, stream>>>(out, g2, hb);
  gemm8<256, 0><<<dim3(HID / 256, TOK / 256), blk512, 0, stream>>>(hb, wg_t, gu, nullptr, nullptr, TOK, HID, DM);
  gemm8<256, 2><<<dim3(HID / 256, TOK / 256), blk512, 0, stream>>>(hb, wu_t, gu, nullptr, nullptr, TOK, HID, DM);
  gemm8<128, 3><<<dim3(DM / 256, TOK / 128), blk512, 0, stream>>>(gu, wd_t, nullptr, out, nullptr, TOK, DM, HID);
}

// Round 5
// 848.087 us; speedup vs baseline: 1.3655x; 1.1287x over previous
//
#include <hip/hip_runtime.h>
#include <hip/hip_bf16.h>
#include <stdint.h>

#define TOK 4096
#define SEQ 2048
#define DM 2048
#define NH 16
#define NKV 4
#define HDIM 128
#define HID 8192
#define WIN 1024
#define SINKN 4

typedef float f32x4 __attribute__((ext_vector_type(4)));
typedef __bf16 bf16x8 __attribute__((ext_vector_type(8)));
typedef unsigned short u16;
typedef unsigned int u32;

#define VM(n) asm volatile("s_waitcnt vmcnt(" #n ")" ::: "memory")

__device__ __forceinline__ u16 f2bf(float f) {
  union { float f; u32 u; } v; v.f = f;
  return (u16)((v.u + 0x7fffu + ((v.u >> 16) & 1u)) >> 16);
}
__device__ __forceinline__ float bf2f(u16 h) {
  union { u32 u; float f; } v; v.u = ((u32)h) << 16;
  return v.f;
}
__device__ __forceinline__ f32x4 mfma16(bf16x8 a, bf16x8 b, f32x4 c) {
  return __builtin_amdgcn_mfma_f32_16x16x32_bf16(a, b, c, 0, 0, 0);
}
__device__ __forceinline__ void gld16(const u16* g, u16* l) {
  __builtin_amdgcn_global_load_lds(
      (const __attribute__((address_space(1))) u32*)g,
      (__attribute__((address_space(3))) u32*)l, 16, 0, 0);
}
__device__ __forceinline__ void bar() {
  asm volatile("s_barrier" ::: "memory");
}
// Inverse swizzle for 64B-row tiles ([rows][32] u16), read addr ^= ((row&7)*8) u16.
// chunk c (16B units) -> (row, k8chunk) global source (rule #21).
__device__ __forceinline__ void swz_rc(int c, int& row, int& k8) {
  row = 2 * (c >> 3) + (((c >> 2) & 1) ^ ((c >> 4) & 1));
  k8 = (c & 3) ^ (row & 3);
}
// XCD-chunked + grouped raster (G=8): per-XCD contiguous serial index s,
// then 8-row super-rows so concurrent blocks form a compact 2D window.
__device__ __forceinline__ void raster8(int wg, int nwg, int nbx, int& bx, int& by) {
  int cpx = nwg >> 3;
  int s = (wg & 7) * cpx + (wg >> 3);
  by = 8 * (s / (8 * nbx)) + (s & 7);
  bx = (s >> 3) % nbx;
}

// ---------------- weight transpose fp32[K][N] -> bf16[N][K] ----------------
__global__ __launch_bounds__(256)
void wtrans(const float* __restrict__ in, u16* __restrict__ out, int K, int N)
{
  __shared__ float t[32][33];
  int tx = threadIdx.x & 31, ty = threadIdx.x >> 5;
  int bx = blockIdx.x, by = blockIdx.y;
  #pragma unroll
  for (int i = 0; i < 4; i++) {
    int r = ty + i * 8;
    t[r][tx] = in[(size_t)(by * 32 + r) * N + bx * 32 + tx];
  }
  __syncthreads();
  #pragma unroll
  for (int i = 0; i < 4; i++) {
    int r = ty + i * 8;
    out[(size_t)(bx * 32 + r) * K + by * 32 + tx] = f2bf(t[tx][r]);
  }
}

// ---- V transpose: bf16 [4096][ld] cols -> [(b*4+hk)*128+d][2048] -----------
__global__ __launch_bounds__(256)
void vtrans(const u16* __restrict__ in, int ld, u16* __restrict__ out)
{
  __shared__ u16 t[32][33];
  int tx = threadIdx.x & 31, ty = threadIdx.x >> 5;
  int bx = blockIdx.x;
  int by = blockIdx.y;
  #pragma unroll
  for (int i = 0; i < 4; i++) {
    int r = ty + i * 8;
    t[r][tx] = in[(size_t)(by * 32 + r) * ld + bx * 32 + tx];
  }
  __syncthreads();
  int b = (by * 32) >> 11;
  int s0 = (by * 32) & (SEQ - 1);
  #pragma unroll
  for (int i = 0; i < 4; i++) {
    int c = bx * 32 + ty + i * 8;
    out[(size_t)(b * (NKV * HDIM) + c) * SEQ + s0 + tx] = t[tx][ty + i * 8];
  }
}

// ---------------------------- RoPE table -----------------------------------
__global__ __launch_bounds__(256)
void rope_table_k(float* __restrict__ ct, float* __restrict__ st)
{
  int idx = blockIdx.x * 256 + threadIdx.x;
  int pos = idx >> 6, d = idx & 63;
  float inv = powf(10000.0f, -(float)d / 64.0f);
  float a = (float)pos * inv;
  ct[idx] = cosf(a);
  st[idx] = sinf(a);
}

// ----------------------- RoPE apply (in place, bf16) ------------------------
__global__ void rope_apply_k(u16* __restrict__ q, int ld,
                             const float* __restrict__ ct,
                             const float* __restrict__ st, float scale)
{
  int t = blockIdx.x;
  int hh = threadIdx.x >> 6;
  int d = threadIdx.x & 63;
  int pos = t & (SEQ - 1);
  size_t base = (size_t)t * ld + hh * HDIM + d;
  float x1 = bf2f(q[base]), x2 = bf2f(q[base + 64]);
  float c = ct[pos * 64 + d], s = st[pos * 64 + d];
  q[base]      = f2bf((x1 * c - x2 * s) * scale);
  q[base + 64] = f2bf((x2 * c + x1 * s) * scale);
}

// ------------------------------ RMSNorm ------------------------------------
__global__ __launch_bounds__(256)
void rmsnorm_k(const float* __restrict__ x, const float* __restrict__ g,
               u16* __restrict__ o)
{
  int row = blockIdx.x;
  int tid = threadIdx.x;
  const float* xr = x + (size_t)row * DM;
  float4 v0 = *(const float4*)(xr + tid * 8);
  float4 v1 = *(const float4*)(xr + tid * 8 + 4);
  float ss = v0.x*v0.x + v0.y*v0.y + v0.z*v0.z + v0.w*v0.w
           + v1.x*v1.x + v1.y*v1.y + v1.z*v1.z + v1.w*v1.w;
  #pragma unroll
  for (int d = 1; d < 64; d <<= 1) ss += __shfl_xor(ss, d);
  __shared__ float red[4];
  if ((tid & 63) == 0) red[tid >> 6] = ss;
  __syncthreads();
  float inv = rsqrtf((red[0] + red[1] + red[2] + red[3]) * (1.0f / DM) + 1e-6f);
  float4 g0 = *(const float4*)(g + tid * 8);
  float4 g1 = *(const float4*)(g + tid * 8 + 4);
  ushort4 o0, o1;
  o0.x = f2bf(v0.x * inv * g0.x); o0.y = f2bf(v0.y * inv * g0.y);
  o0.z = f2bf(v0.z * inv * g0.z); o0.w = f2bf(v0.w * inv * g0.w);
  o1.x = f2bf(v1.x * inv * g1.x); o1.y = f2bf(v1.y * inv * g1.y);
  o1.z = f2bf(v1.z * inv * g1.z); o1.w = f2bf(v1.w * inv * g1.w);
  *(ushort4*)(o + (size_t)row * DM + tid * 8) = o0;
  *(ushort4*)(o + (size_t)row * DM + tid * 8 + 4) = o1;
}

// ---------------- 8-phase pipelined GEMM: BM x 256, BK=32 -------------------
// 4-slot LDS ring, stage distance 3, 2 phases per K-tile. vmcnt once per
// K-tile, never 0 mid-loop. Grouped raster (G=8) for L2 locality.
template<int BM, int EPI>
__global__ __launch_bounds__(512, 2)
void gemm8(const u16* __restrict__ A, const u16* __restrict__ Bt,
           u16* __restrict__ Cb, float* __restrict__ Cf,
           const float* __restrict__ X, int M, int N, int K, int nbx)
{
  constexpr int BN = 256;
  constexpr int MREP = BM / 32;       // 8 or 4
  constexpr int ASZ = BM * 32;        // u16 per A tile
  constexpr int SLOT = ASZ + BN * 32;
  __shared__ u16 lds[4 * SLOT];

  int bx, by;
  raster8(blockIdx.x, gridDim.x, nbx, bx, by);
  int m0 = by * BM, n0 = bx * BN;

  int tid = threadIdx.x;
  int l = tid & 63, w = tid >> 6;
  int l16 = l & 15, lg = l >> 4;
  int wr = w >> 2, wc = w & 3;            // 2M x 4N waves

  int aoff[MREP], boff[4];
  #pragma unroll
  for (int m = 0; m < MREP; m++) {
    int ar = wr * (BM / 2) + m * 16 + l16;
    aoff[m] = (ar * 32 + lg * 8) ^ ((ar & 7) * 8);
  }
  #pragma unroll
  for (int n = 0; n < 4; n++) {
    int br = wc * 64 + n * 16 + l16;
    boff[n] = ASZ + ((br * 32 + lg * 8) ^ ((br & 7) * 8));
  }

  const u16 *srcA0, *srcA1, *srcB0, *srcB1;
  {
    int r, kc;
    swz_rc(tid, r, kc);
    srcA0 = A + (size_t)(m0 + r) * K + kc * 8;
    srcB0 = Bt + (size_t)(n0 + r) * K + kc * 8;
    swz_rc(tid + 512, r, kc);
    srcB1 = Bt + (size_t)(n0 + r) * K + kc * 8;
    srcA1 = (BM == 256) ? (A + (size_t)(m0 + r) * K + kc * 8) : srcA0;
  }

  const int NT = K >> 5;

  auto stageA = [&](int t) {
    u16* d = lds + (t & 3) * SLOT;
    gld16(srcA0 + t * 32, d + tid * 8);
    if constexpr (BM == 256) gld16(srcA1 + t * 32, d + (tid + 512) * 8);
  };
  auto stageB = [&](int t) {
    u16* d = lds + (t & 3) * SLOT + ASZ;
    gld16(srcB0 + t * 32, d + tid * 8);
    gld16(srcB1 + t * 32, d + (tid + 512) * 8);
  };

  stageA(0); stageB(0); stageA(1); stageB(1); stageA(2); stageB(2);
  if constexpr (BM == 256) VM(8); else VM(6);
  bar();

  f32x4 acc[MREP][4];
  f32x4 zero = {0.f, 0.f, 0.f, 0.f};
  #pragma unroll
  for (int m = 0; m < MREP; m++)
    #pragma unroll
    for (int n = 0; n < 4; n++) acc[m][n] = zero;

  for (int j = 0; j < NT; ++j) {
    u16* cur = lds + (j & 3) * SLOT;
    const bool st = (j + 3 < NT);

    if (st) stageA(j + 3);
    bf16x8 a[MREP], b0, b1;
    #pragma unroll
    for (int mf = 0; mf < MREP; mf++) a[mf] = *(const bf16x8*)(cur + aoff[mf]);
    b0 = *(const bf16x8*)(cur + boff[0]);
    b1 = *(const bf16x8*)(cur + boff[1]);
    bar();
    asm volatile("s_waitcnt lgkmcnt(0)" ::: "memory");
    __builtin_amdgcn_sched_barrier(0);
    __builtin_amdgcn_s_setprio(1);
    #pragma unroll
    for (int mf = 0; mf < MREP; mf++) {
      acc[mf][0] = mfma16(a[mf], b0, acc[mf][0]);
      acc[mf][1] = mfma16(a[mf], b1, acc[mf][1]);
    }
    __builtin_amdgcn_s_setprio(0);
    __builtin_amdgcn_sched_barrier(0);
    bar();

    if (st) stageB(j + 3);
    b0 = *(const bf16x8*)(cur + boff[2]);
    b1 = *(const bf16x8*)(cur + boff[3]);
    if constexpr (BM == 256) {
      if (st) VM(8); else if (j + 2 < NT) VM(4); else VM(0);
    } else {
      if (st) VM(6); else if (j + 2 < NT) VM(3); else VM(0);
    }
    bar();
    asm volatile("s_waitcnt lgkmcnt(0)" ::: "memory");
    __builtin_amdgcn_sched_barrier(0);
    __builtin_amdgcn_s_setprio(1);
    #pragma unroll
    for (int mf = 0; mf < MREP; mf++) {
      acc[mf][2] = mfma16(a[mf], b0, acc[mf][2]);
      acc[mf][3] = mfma16(a[mf], b1, acc[mf][3]);
    }
    __builtin_amdgcn_s_setprio(0);
    __builtin_amdgcn_sched_barrier(0);
    bar();
  }

  #pragma unroll
  for (int m = 0; m < MREP; m++) {
    int row = m0 + wr * (BM / 2) + m * 16 + lg * 4;
    #pragma unroll
    for (int n = 0; n < 4; n++) {
      int col = n0 + wc * 64 + n * 16 + l16;
      #pragma unroll
      for (int r = 0; r < 4; r++) {
        size_t idx = (size_t)(row + r) * N + col;
        float v = acc[m][n][r];
        if (EPI == 0) {
          Cb[idx] = f2bf(v);
        } else if (EPI == 1) {
          Cf[idx] = X[idx] + v;
        } else {
          Cf[idx] += v;
        }
      }
    }
  }
}

// ------------- fused gate+up GEMM: 256 x (128 gate | 128 up) ----------------
// Same 8-phase pipeline; B-tile = [128 gate rows | 128 up rows] x 32.
// ph0 = gate MFMAs, ph1 = up MFMAs (A-frags shared). Epilogue: silu(g)*u.
__global__ __launch_bounds__(512, 2)
void gemm8gu(const u16* __restrict__ A, const u16* __restrict__ Bg,
             const u16* __restrict__ Bu, u16* __restrict__ Gu, int K, int nbx)
{
  constexpr int BM = 256;
  constexpr int MREP = 8;
  constexpr int ASZ = BM * 32;
  constexpr int SLOT = ASZ + 256 * 32;
  __shared__ u16 lds[4 * SLOT];

  int bx, by;
  raster8(blockIdx.x, gridDim.x, nbx, bx, by);
  int m0 = by * BM, n0 = bx * 128;

  int tid = threadIdx.x;
  int l = tid & 63, w = tid >> 6;
  int l16 = l & 15, lg = l >> 4;
  int wr = w >> 2, wc = w & 3;

  int aoff[MREP], boff[4];
  #pragma unroll
  for (int m = 0; m < MREP; m++) {
    int ar = wr * 128 + m * 16 + l16;
    aoff[m] = (ar * 32 + lg * 8) ^ ((ar & 7) * 8);
  }
  #pragma unroll
  for (int n = 0; n < 4; n++) {
    // n 0,1: gate rows [0,128); n 2,3: up rows [128,256)
    int br = (n >> 1) * 128 + wc * 32 + (n & 1) * 16 + l16;
    boff[n] = ASZ + ((br * 32 + lg * 8) ^ ((br & 7) * 8));
  }

  const u16 *srcA0, *srcA1, *srcB0, *srcB1;
  {
    int r, kc;
    swz_rc(tid, r, kc);
    srcA0 = A + (size_t)(m0 + r) * K + kc * 8;
    srcB0 = ((r < 128) ? Bg + (size_t)(n0 + r) * K
                       : Bu + (size_t)(n0 + r - 128) * K) + kc * 8;
    swz_rc(tid + 512, r, kc);
    srcA1 = A + (size_t)(m0 + r) * K + kc * 8;
    srcB1 = ((r < 128) ? Bg + (size_t)(n0 + r) * K
                       : Bu + (size_t)(n0 + r - 128) * K) + kc * 8;
  }

  const int NT = K >> 5;

  auto stageA = [&](int t) {
    u16* d = lds + (t & 3) * SLOT;
    gld16(srcA0 + t * 32, d + tid * 8);
    gld16(srcA1 + t * 32, d + (tid + 512) * 8);
  };
  auto stageB = [&](int t) {
    u16* d = lds + (t & 3) * SLOT + ASZ;
    gld16(srcB0 + t * 32, d + tid * 8);
    gld16(srcB1 + t * 32, d + (tid + 512) * 8);
  };

  stageA(0); stageB(0); stageA(1); stageB(1); stageA(2); stageB(2);
  VM(8);
  bar();

  f32x4 acc[MREP][4];
  f32x4 zero = {0.f, 0.f, 0.f, 0.f};
  #pragma unroll
  for (int m = 0; m < MREP; m++)
    #pragma unroll
    for (int n = 0; n < 4; n++) acc[m][n] = zero;

  for (int j = 0; j < NT; ++j) {
    u16* cur = lds + (j & 3) * SLOT;
    const bool st = (j + 3 < NT);

    if (st) stageA(j + 3);
    bf16x8 a[MREP], b0, b1;
    #pragma unroll
    for (int mf = 0; mf < MREP; mf++) a[mf] = *(const bf16x8*)(cur + aoff[mf]);
    b0 = *(const bf16x8*)(cur + boff[0]);
    b1 = *(const bf16x8*)(cur + boff[1]);
    bar();
    asm volatile("s_waitcnt lgkmcnt(0)" ::: "memory");
    __builtin_amdgcn_sched_barrier(0);
    __builtin_amdgcn_s_setprio(1);
    #pragma unroll
    for (int mf = 0; mf < MREP; mf++) {
      acc[mf][0] = mfma16(a[mf], b0, acc[mf][0]);
      acc[mf][1] = mfma16(a[mf], b1, acc[mf][1]);
    }
    __builtin_amdgcn_s_setprio(0);
    __builtin_amdgcn_sched_barrier(0);
    bar();

    if (st) stageB(j + 3);
    b0 = *(const bf16x8*)(cur + boff[2]);
    b1 = *(const bf16x8*)(cur + boff[3]);
    if (st) VM(8); else if (j + 2 < NT) VM(4); else VM(0);
    bar();
    asm volatile("s_waitcnt lgkmcnt(0)" ::: "memory");
    __builtin_amdgcn_sched_barrier(0);
    __builtin_amdgcn_s_setprio(1);
    #pragma unroll
    for (int mf = 0; mf < MREP; mf++) {
      acc[mf][2] = mfma16(a[mf], b0, acc[mf][2]);
      acc[mf][3] = mfma16(a[mf], b1, acc[mf][3]);
    }
    __builtin_amdgcn_s_setprio(0);
    __builtin_amdgcn_sched_barrier(0);
    bar();
  }

  // epilogue: gu = silu(gate) * up, bf16
  #pragma unroll
  for (int m = 0; m < MREP; m++) {
    int row = m0 + wr * 128 + m * 16 + lg * 4;
    #pragma unroll
    for (int n = 0; n < 2; n++) {
      int col = n0 + wc * 32 + n * 16 + l16;
      #pragma unroll
      for (int r = 0; r < 4; r++) {
        float gt = acc[m][n][r];
        float up = acc[m][n + 2][r];
        float sg = gt / (1.0f + __expf(-gt));
        Gu[(size_t)(row + r) * HID + col] = f2bf(sg * up);
      }
    }
  }
}

// ------------------- flash attention, sliding window + sink -----------------
__global__ __launch_bounds__(256)
void attn_k(const u16* __restrict__ qb, int ldq,
            const u16* __restrict__ kb, int ldk,
            const u16* __restrict__ vbt, u16* __restrict__ ao)
{
  int q0 = blockIdx.x * 128;
  int h = blockIdx.y;
  int b = blockIdx.z;
  int hk = h >> 2;
  int tid = threadIdx.x;
  int w = tid >> 6, l = tid & 63;
  int l16 = l & 15, lg = l >> 4;

  __shared__ u16 Ks[32 * 128];
  __shared__ u16 Vt[128 * 32];
  __shared__ u16 Ps[4][32 * 40];
  u16* Pw = Ps[w];

  bf16x8 qf[2][4];
  #pragma unroll
  for (int m = 0; m < 2; m++)
    #pragma unroll
    for (int kd = 0; kd < 4; kd++) {
      int row = q0 + w * 32 + m * 16 + l16;
      qf[m][kd] = *(const bf16x8*)(qb + (size_t)(b * SEQ + row) * ldq
                                   + h * HDIM + kd * 32 + lg * 8);
    }

  f32x4 oacc[2][8];
  float mrun[2][4], lrun[2][4];
  f32x4 zero = {0.f, 0.f, 0.f, 0.f};
  #pragma unroll
  for (int m = 0; m < 2; m++) {
    #pragma unroll
    for (int nd = 0; nd < 8; nd++) oacc[m][nd] = zero;
    #pragma unroll
    for (int r = 0; r < 4; r++) { mrun[m][r] = -1e9f; lrun[m][r] = 0.f; }
  }

  int kr0 = tid >> 4,        kc0 = (tid & 15) ^ (kr0 & 7);
  int kr1 = (tid + 256) >> 4, kc1 = (tid & 15) ^ (kr1 & 7);
  int vd0, vk0, vd1, vk1;
  swz_rc(tid, vd0, vk0);
  swz_rc(tid + 256, vd1, vk1);
  const u16* kbase = kb + (size_t)(b * SEQ) * ldk + hk * HDIM;
  const u16* vbase = vbt + (size_t)(b * NKV + hk) * HDIM * SEQ;

  int koff[2][4];
  #pragma unroll
  for (int n = 0; n < 2; n++)
    #pragma unroll
    for (int kd = 0; kd < 4; kd++) {
      int key = n * 16 + l16;
      koff[n][kd] = ((key * 128) + kd * 32 + lg * 8) ^ ((key & 7) * 8);
    }
  int voff[8];
  #pragma unroll
  for (int nd = 0; nd < 8; nd++) {
    int d = nd * 16 + l16;
    voff[nd] = (d * 32 + lg * 8) ^ ((d & 7) * 8);
  }

  int lo = (q0 >= WIN) ? ((q0 - (WIN - 1)) >> 5) : 0;
  int hi = (q0 + 127) >> 5;

  for (int it = (lo > 0 ? lo - 1 : 0); it <= hi; ++it) {
    int kt = (it < lo) ? 0 : it;
    gld16(kbase + (size_t)(kt * 32 + kr0) * ldk + kc0 * 8, Ks + tid * 8);
    gld16(kbase + (size_t)(kt * 32 + kr1) * ldk + kc1 * 8, Ks + (tid + 256) * 8);
    gld16(vbase + (size_t)vd0 * SEQ + kt * 32 + vk0 * 8, Vt + tid * 8);
    gld16(vbase + (size_t)vd1 * SEQ + kt * 32 + vk1 * 8, Vt + (tid + 256) * 8);
    __syncthreads();

    f32x4 sacc[2][2];
    sacc[0][0] = zero; sacc[0][1] = zero; sacc[1][0] = zero; sacc[1][1] = zero;
    #pragma unroll
    for (int kd = 0; kd < 4; kd++) {
      bf16x8 kf0 = *(const bf16x8*)(Ks + koff[0][kd]);
      bf16x8 kf1 = *(const bf16x8*)(Ks + koff[1][kd]);
      #pragma unroll
      for (int m = 0; m < 2; m++) {
        sacc[m][0] = mfma16(qf[m][kd], kf0, sacc[m][0]);
        sacc[m][1] = mfma16(qf[m][kd], kf1, sacc[m][1]);
      }
    }

    #pragma unroll
    for (int m = 0; m < 2; m++) {
      float sc[4];
      #pragma unroll
      for (int r = 0; r < 4; r++) {
        int i = q0 + w * 32 + m * 16 + lg * 4 + r;
        int j0 = kt * 32 + l16;
        int j1 = j0 + 16;
        float s0 = sacc[m][0][r];
        float s1 = sacc[m][1][r];
        bool ok0 = (j0 <= i) && ((i - j0 < WIN) || (j0 < SINKN));
        bool ok1 = (j1 <= i) && ((i - j1 < WIN) || (j1 < SINKN));
        s0 = ok0 ? s0 : -1e9f;
        s1 = ok1 ? s1 : -1e9f;
        float mx = fmaxf(s0, s1);
        mx = fmaxf(mx, __shfl_xor(mx, 1));
        mx = fmaxf(mx, __shfl_xor(mx, 2));
        mx = fmaxf(mx, __shfl_xor(mx, 4));
        mx = fmaxf(mx, __shfl_xor(mx, 8));
        float mold = mrun[m][r];
        float mnew = fmaxf(mold, mx);
        float scl = __expf(mold - mnew);
        mrun[m][r] = mnew;
        float p0 = __expf(s0 - mnew);
        float p1 = __expf(s1 - mnew);
        int prow = m * 16 + lg * 4 + r;
        Pw[prow * 40 + l16] = f2bf(p0);
        Pw[prow * 40 + 16 + l16] = f2bf(p1);
        float ps = p0 + p1;
        ps += __shfl_xor(ps, 1);
        ps += __shfl_xor(ps, 2);
        ps += __shfl_xor(ps, 4);
        ps += __shfl_xor(ps, 8);
        lrun[m][r] = lrun[m][r] * scl + ps;
        sc[r] = scl;
      }
      #pragma unroll
      for (int nd = 0; nd < 8; nd++) {
        oacc[m][nd][0] *= sc[0];
        oacc[m][nd][1] *= sc[1];
        oacc[m][nd][2] *= sc[2];
        oacc[m][nd][3] *= sc[3];
      }
    }

    bf16x8 pa0 = *(const bf16x8*)(Pw + l16 * 40 + lg * 8);
    bf16x8 pa1 = *(const bf16x8*)(Pw + (16 + l16) * 40 + lg * 8);
    #pragma unroll
    for (int nd = 0; nd < 8; nd++) {
      bf16x8 vf = *(const bf16x8*)(Vt + voff[nd]);
      oacc[0][nd] = mfma16(pa0, vf, oacc[0][nd]);
      oacc[1][nd] = mfma16(pa1, vf, oacc[1][nd]);
    }
    __syncthreads();
  }

  #pragma unroll
  for (int m = 0; m < 2; m++)
    #pragma unroll
    for (int r = 0; r < 4; r++) {
      float invl = 1.0f / lrun[m][r];
      int row = q0 + w * 32 + m * 16 + lg * 4 + r;
      #pragma unroll
      for (int nd = 0; nd < 8; nd++) {
        int col = nd * 16 + l16;
        ao[(size_t)(b * SEQ + row) * (NH * HDIM) + h * HDIM + col] =
            f2bf(oacc[m][nd][r] * invl);
      }
    }
}

// ------------------------------- launcher -----------------------------------
extern "C" void kernel_launch(void* const* d_in, const int* in_sizes, int n_in,
                              void* d_out, int out_size, void* d_ws, size_t ws_size,
                              hipStream_t stream)
{
  (void)in_sizes; (void)n_in; (void)out_size;
  const float* x  = (const float*)d_in[0];
  const float* g1 = (const float*)d_in[1];
  const float* g2 = (const float*)d_in[2];
  const float* wq = (const float*)d_in[3];
  const float* wk = (const float*)d_in[4];
  const float* wv = (const float*)d_in[5];
  const float* wo = (const float*)d_in[6];
  const float* wg = (const float*)d_in[7];
  const float* wu = (const float*)d_in[8];
  const float* wd = (const float*)d_in[9];
  float* out = (float*)d_out;

  char* ws = (char*)d_ws;
  size_t off = 0;
  auto alloc = [&](size_t bytes) {
    char* p = ws + off;
    off += (bytes + 255) & ~(size_t)255;
    return p;
  };
  const int NQKV = 3072;   // q 0..2047 | k 2048..2559 | v 2560..3071
  u16* wqkv_t = (u16*)alloc((size_t)NQKV * DM * 2);
  u16* wo_t   = (u16*)alloc((size_t)DM * DM * 2);
  u16* wg_t   = (u16*)alloc((size_t)HID * DM * 2);
  u16* wu_t   = (u16*)alloc((size_t)HID * DM * 2);
  u16* wd_t   = (u16*)alloc((size_t)DM * HID * 2);
  u16* hb     = (u16*)alloc((size_t)TOK * DM * 2);
  // gu (67.1 MB) aliases qkvb+vbt+aob (dead by the time gateup runs) + tail
  char* span0 = ws + off;
  u16* qkvb   = (u16*)alloc((size_t)TOK * NQKV * 2);
  u16* vbt    = (u16*)alloc((size_t)TOK * NKV * HDIM * 2);
  u16* aob    = (u16*)alloc((size_t)TOK * NH * HDIM * 2);
  size_t span_used = (size_t)(ws + off - span0);
  size_t gu_need = (size_t)TOK * HID * 2;
  if (gu_need > span_used) alloc(gu_need - span_used);
  u16* gu = (u16*)span0;
  float* ct  = (float*)alloc((size_t)SEQ * 64 * 4);
  float* st  = (float*)alloc((size_t)SEQ * 64 * 4);
  if (off > ws_size) return;

  dim3 blk(256);
  dim3 blk512(512);

  // weight transposes (fp32 -> bf16, [K][N] -> [N][K])
  wtrans<<<dim3(DM / 32, DM / 32), blk, 0, stream>>>(wq, wqkv_t, DM, DM);
  wtrans<<<dim3((NKV * HDIM) / 32, DM / 32), blk, 0, stream>>>(wk, wqkv_t + (size_t)DM * DM, DM, NKV * HDIM);
  wtrans<<<dim3((NKV * HDIM) / 32, DM / 32), blk, 0, stream>>>(wv, wqkv_t + (size_t)(DM + NKV * HDIM) * DM, DM, NKV * HDIM);
  wtrans<<<dim3(DM / 32, DM / 32), blk, 0, stream>>>(wo, wo_t, DM, DM);
  wtrans<<<dim3(HID / 32, DM / 32), blk, 0, stream>>>(wg, wg_t, DM, HID);
  wtrans<<<dim3(HID / 32, DM / 32), blk, 0, stream>>>(wu, wu_t, DM, HID);
  wtrans<<<dim3(DM / 32, HID / 32), blk, 0, stream>>>(wd, wd_t, HID, DM);

  rope_table_k<<<SEQ * 64 / 256, blk, 0, stream>>>(ct, st);
  rmsnorm_k<<<TOK, blk, 0, stream>>>(x, g1, hb);

  // fused QKV projection: [4096][3072]
  gemm8<128, 0><<<dim3((NQKV / 256) * (TOK / 128)), blk512, 0, stream>>>(
      hb, wqkv_t, qkvb, nullptr, nullptr, TOK, NQKV, DM, NQKV / 256);

  rope_apply_k<<<TOK, dim3(NH * 64), 0, stream>>>(qkvb, NQKV, ct, st, 0.08838834764831845f);
  rope_apply_k<<<TOK, dim3(NKV * 64), 0, stream>>>(qkvb + DM, NQKV, ct, st, 1.0f);
  vtrans<<<dim3((NKV * HDIM) / 32, TOK / 32), blk, 0, stream>>>(qkvb + DM + NKV * HDIM, NQKV, vbt);

  attn_k<<<dim3(SEQ / 128, NH, 2), blk, 0, stream>>>(qkvb, NQKV, qkvb + DM, NQKV, vbt, aob);

  gemm8<128, 1><<<dim3((DM / 256) * (TOK / 128)), blk512, 0, stream>>>(
      aob, wo_t, nullptr, out, x, TOK, DM, DM, DM / 256);
  rmsnorm_k<<<TOK, blk, 0, stream>>>(out, g2, hb);

  // fused gate+up with silu epilogue
  gemm8gu<<<dim3((HID / 128) * (TOK / 256)), blk512, 0, stream>>>(
      hb, wg_t, wu_t, gu, DM, HID / 128);

  gemm8<128, 3><<<dim3((DM / 256) * (TOK / 128)), blk512, 0, stream>>>(
      gu, wd_t, nullptr, out, nullptr, TOK, DM, HID, DM / 256);
}

// Round 7
// 821.938 us; speedup vs baseline: 1.4090x; 1.0318x over previous
//
#include <hip/hip_runtime.h>
#include <hip/hip_bf16.h>
#include <stdint.h>

#define TOK 4096
#define SEQ 2048
#define DM 2048
#define NH 16
#define NKV 4
#define HDIM 128
#define HID 8192
#define WIN 1024
#define SINKN 4

typedef float f32x4 __attribute__((ext_vector_type(4)));
typedef __bf16 bf16x8 __attribute__((ext_vector_type(8)));
typedef unsigned short u16;
typedef unsigned int u32;

#define VM(n) asm volatile("s_waitcnt vmcnt(" #n ")" ::: "memory")
#define LGKM0 asm volatile("s_waitcnt lgkmcnt(0)" ::: "memory")

__device__ __forceinline__ u16 f2bf(float f) {
  union { float f; u32 u; } v; v.f = f;
  return (u16)((v.u + 0x7fffu + ((v.u >> 16) & 1u)) >> 16);
}
__device__ __forceinline__ float bf2f(u16 h) {
  union { u32 u; float f; } v; v.u = ((u32)h) << 16;
  return v.f;
}
__device__ __forceinline__ f32x4 mfma16(bf16x8 a, bf16x8 b, f32x4 c) {
  return __builtin_amdgcn_mfma_f32_16x16x32_bf16(a, b, c, 0, 0, 0);
}
__device__ __forceinline__ void gld16(const u16* g, u16* l) {
  __builtin_amdgcn_global_load_lds(
      (const __attribute__((address_space(1))) u32*)g,
      (__attribute__((address_space(3))) u32*)l, 16, 0, 0);
}
__device__ __forceinline__ void bar() {
  asm volatile("s_barrier" ::: "memory");
}
// Inverse swizzle for 64B-row tiles ([rows][32] u16) used by attn staging.
__device__ __forceinline__ void swz_rc(int c, int& row, int& k8) {
  row = 2 * (c >> 3) + (((c >> 2) & 1) ^ ((c >> 4) & 1));
  k8 = (c & 3) ^ (row & 3);
}
// XCD-chunked + grouped raster (G=8).
__device__ __forceinline__ void raster8(int wg, int nwg, int nbx, int& bx, int& by) {
  int cpx = nwg >> 3;
  int s = (wg & 7) * cpx + (wg >> 3);
  by = 8 * (s / (8 * nbx)) + (s & 7);
  bx = (s >> 3) % nbx;
}

// ---------------- weight transpose fp32[K][N] -> bf16[N][K] ----------------
__global__ __launch_bounds__(256)
void wtrans(const float* __restrict__ in, u16* __restrict__ out, int K, int N)
{
  __shared__ float t[32][33];
  int tx = threadIdx.x & 31, ty = threadIdx.x >> 5;
  int bx = blockIdx.x, by = blockIdx.y;
  #pragma unroll
  for (int i = 0; i < 4; i++) {
    int r = ty + i * 8;
    t[r][tx] = in[(size_t)(by * 32 + r) * N + bx * 32 + tx];
  }
  __syncthreads();
  #pragma unroll
  for (int i = 0; i < 4; i++) {
    int r = ty + i * 8;
    out[(size_t)(bx * 32 + r) * K + by * 32 + tx] = f2bf(t[tx][r]);
  }
}

// ---- V transpose: bf16 [4096][ld] cols -> [(b*4+hk)*128+d][2048] -----------
__global__ __launch_bounds__(256)
void vtrans(const u16* __restrict__ in, int ld, u16* __restrict__ out)
{
  __shared__ u16 t[32][33];
  int tx = threadIdx.x & 31, ty = threadIdx.x >> 5;
  int bx = blockIdx.x;
  int by = blockIdx.y;
  #pragma unroll
  for (int i = 0; i < 4; i++) {
    int r = ty + i * 8;
    t[r][tx] = in[(size_t)(by * 32 + r) * ld + bx * 32 + tx];
  }
  __syncthreads();
  int b = (by * 32) >> 11;
  int s0 = (by * 32) & (SEQ - 1);
  #pragma unroll
  for (int i = 0; i < 4; i++) {
    int c = bx * 32 + ty + i * 8;
    out[(size_t)(b * (NKV * HDIM) + c) * SEQ + s0 + tx] = t[tx][ty + i * 8];
  }
}

// ---------------------------- RoPE table -----------------------------------
__global__ __launch_bounds__(256)
void rope_table_k(float* __restrict__ ct, float* __restrict__ st)
{
  int idx = blockIdx.x * 256 + threadIdx.x;
  int pos = idx >> 6, d = idx & 63;
  float inv = powf(10000.0f, -(float)d / 64.0f);
  float a = (float)pos * inv;
  ct[idx] = cosf(a);
  st[idx] = sinf(a);
}

// ----------------------- RoPE apply (in place, bf16) ------------------------
__global__ void rope_apply_k(u16* __restrict__ q, int ld,
                             const float* __restrict__ ct,
                             const float* __restrict__ st, float scale)
{
  int t = blockIdx.x;
  int hh = threadIdx.x >> 6;
  int d = threadIdx.x & 63;
  int pos = t & (SEQ - 1);
  size_t base = (size_t)t * ld + hh * HDIM + d;
  float x1 = bf2f(q[base]), x2 = bf2f(q[base + 64]);
  float c = ct[pos * 64 + d], s = st[pos * 64 + d];
  q[base]      = f2bf((x1 * c - x2 * s) * scale);
  q[base + 64] = f2bf((x2 * c + x1 * s) * scale);
}

// ------------------------------ RMSNorm ------------------------------------
__global__ __launch_bounds__(256)
void rmsnorm_k(const float* __restrict__ x, const float* __restrict__ g,
               u16* __restrict__ o)
{
  int row = blockIdx.x;
  int tid = threadIdx.x;
  const float* xr = x + (size_t)row * DM;
  float4 v0 = *(const float4*)(xr + tid * 8);
  float4 v1 = *(const float4*)(xr + tid * 8 + 4);
  float ss = v0.x*v0.x + v0.y*v0.y + v0.z*v0.z + v0.w*v0.w
           + v1.x*v1.x + v1.y*v1.y + v1.z*v1.z + v1.w*v1.w;
  #pragma unroll
  for (int d = 1; d < 64; d <<= 1) ss += __shfl_xor(ss, d);
  __shared__ float red[4];
  if ((tid & 63) == 0) red[tid >> 6] = ss;
  __syncthreads();
  float inv = rsqrtf((red[0] + red[1] + red[2] + red[3]) * (1.0f / DM) + 1e-6f);
  float4 g0 = *(const float4*)(g + tid * 8);
  float4 g1 = *(const float4*)(g + tid * 8 + 4);
  ushort4 o0, o1;
  o0.x = f2bf(v0.x * inv * g0.x); o0.y = f2bf(v0.y * inv * g0.y);
  o0.z = f2bf(v0.z * inv * g0.z); o0.w = f2bf(v0.w * inv * g0.w);
  o1.x = f2bf(v1.x * inv * g1.x); o1.y = f2bf(v1.y * inv * g1.y);
  o1.z = f2bf(v1.z * inv * g1.z); o1.w = f2bf(v1.w * inv * g1.w);
  *(ushort4*)(o + (size_t)row * DM + tid * 8) = o0;
  *(ushort4*)(o + (size_t)row * DM + tid * 8 + 4) = o1;
}

// ------------- deep-pipelined GEMM: 128 x 256, BK=64, 3-slot ring -----------
// 8 waves (2M x 4N), 2 phases per K-tile, 16 MFMA/phase.
// Staging in 8KB units (1 gld16/thread): P_a(t) stages B0,B1,B2 of t+2;
// P_b(t) stages B3,A0,A1 of t+2 -> lead 4 phases. One counted VM(6) per
// K-tile at end of P_b confirms tile t+1 fully landed (6 loads/tile/thread);
// tail: VM(0) once when staging stops. Slot (t+2)%3 == (t-1)%3 whose last
// reads completed before P_b(t-1)'s closing barrier -> no WAR race.
// EPI: 0 store bf16; 1 Cf = X + acc; 3 Cf += acc. GU=1: B = gate|up rows,
// epilogue silu(gate)*up -> bf16.
template<int EPI, int GU>
__global__ __launch_bounds__(512, 1)
void gemmp(const u16* __restrict__ A, const u16* __restrict__ Bt,
           const u16* __restrict__ Bu, u16* __restrict__ Cb,
           float* __restrict__ Cf, const float* __restrict__ X,
           int M, int N, int K, int nbx)
{
  constexpr int ASZ = 128 * 64;          // 8192 u16 per A tile (128 rows x 64)
  constexpr int SLOT = ASZ + 256 * 64;   // + 16384 u16 B tile = 24576 u16
  __shared__ u16 lds[3 * SLOT];          // 144 KB

  int bx, by;
  raster8(blockIdx.x, gridDim.x, nbx, bx, by);
  int m0 = by * 128;
  int n0 = bx * (GU ? 128 : 256);

  int tid = threadIdx.x;
  int l = tid & 63, w = tid >> 6;
  int l16 = l & 15, lg = l >> 4;
  int wr = w >> 2, wc = w & 3;           // 2M x 4N waves

  // ds_read offsets (u16, relative to slot base); swizzle ^((row&7)<<4) bytes
  int aoff[4][2], boff[4][2];
  #pragma unroll
  for (int m = 0; m < 4; m++)
    #pragma unroll
    for (int kk = 0; kk < 2; kk++) {
      int row = wr * 64 + m * 16 + l16;
      aoff[m][kk] = ((row * 128 + kk * 64 + lg * 16) ^ ((row & 7) << 4)) >> 1;
    }
  #pragma unroll
  for (int n = 0; n < 4; n++)
    #pragma unroll
    for (int kk = 0; kk < 2; kk++) {
      int br = GU ? ((n >> 1) * 128 + wc * 32 + (n & 1) * 16 + l16)
                  : (wc * 64 + n * 16 + l16);
      boff[n][kk] = ASZ + (((br * 128 + kk * 64 + lg * 16) ^ ((br & 7) << 4)) >> 1);
    }

  // staging sources: unit = 64 rows x 64 cols (8 KB), 1 gld16/thread.
  // dest chunk = tid: row = tid>>3, slot = tid&7; src colchunk = slot ^ (row&7)
  int urow = tid >> 3;
  int cc = (tid & 7) ^ (urow & 7);
  const u16* pA[2];
  const u16* pB[4];
  pA[0] = A + (size_t)(m0 + urow) * K + cc * 8;
  pA[1] = A + (size_t)(m0 + 64 + urow) * K + cc * 8;
  #pragma unroll
  for (int u = 0; u < 4; u++) {
    if (GU) pB[u] = (u < 2 ? Bt + (size_t)(n0 + u * 64 + urow) * K
                           : Bu + (size_t)(n0 + (u - 2) * 64 + urow) * K) + cc * 8;
    else    pB[u] = Bt + (size_t)(n0 + u * 64 + urow) * K + cc * 8;
  }

  const int NT = K >> 6;

  auto stA = [&](int tt, int u) {
    gld16(pA[u] + (size_t)tt * 64, lds + (tt % 3) * SLOT + u * 4096 + tid * 8);
  };
  auto stB = [&](int tt, int u) {
    gld16(pB[u] + (size_t)tt * 64, lds + (tt % 3) * SLOT + ASZ + u * 4096 + tid * 8);
  };

  // prologue: tiles 0,1 (unit order B0..B3,A0,A1 per tile = 6 loads/tile)
  #pragma unroll
  for (int u = 0; u < 4; u++) stB(0, u);
  stA(0, 0); stA(0, 1);
  #pragma unroll
  for (int u = 0; u < 4; u++) stB(1, u);
  stA(1, 0); stA(1, 1);
  VM(6);              // tile 0 landed
  bar();

  f32x4 acc[4][4];
  f32x4 zero = {0.f, 0.f, 0.f, 0.f};
  #pragma unroll
  for (int m = 0; m < 4; m++)
    #pragma unroll
    for (int n = 0; n < 4; n++) acc[m][n] = zero;

  for (int t = 0; t < NT; ++t) {
    u16* cur = lds + (t % 3) * SLOT;
    const bool st = (t + 2 < NT);

    // ---------------- P_a: n-frags 0,1 ----------------
    if (st) { stB(t + 2, 0); stB(t + 2, 1); stB(t + 2, 2); }
    bf16x8 a[4][2], b[2][2];
    #pragma unroll
    for (int m = 0; m < 4; m++) {
      a[m][0] = *(const bf16x8*)(cur + aoff[m][0]);
      a[m][1] = *(const bf16x8*)(cur + aoff[m][1]);
    }
    #pragma unroll
    for (int n = 0; n < 2; n++) {
      b[n][0] = *(const bf16x8*)(cur + boff[n][0]);
      b[n][1] = *(const bf16x8*)(cur + boff[n][1]);
    }
    bar();
    LGKM0;
    __builtin_amdgcn_sched_barrier(0);
    __builtin_amdgcn_s_setprio(1);
    #pragma unroll
    for (int m = 0; m < 4; m++)
      #pragma unroll
      for (int n = 0; n < 2; n++) {
        acc[m][n] = mfma16(a[m][0], b[n][0], acc[m][n]);
        acc[m][n] = mfma16(a[m][1], b[n][1], acc[m][n]);
      }
    __builtin_amdgcn_s_setprio(0);
    __builtin_amdgcn_sched_barrier(0);
    bar();

    // ---------------- P_b: n-frags 2,3 ----------------
    if (st) { stB(t + 2, 3); stA(t + 2, 0); stA(t + 2, 1); }
    bf16x8 c2[2][2];
    #pragma unroll
    for (int n = 0; n < 2; n++) {
      c2[n][0] = *(const bf16x8*)(cur + boff[n + 2][0]);
      c2[n][1] = *(const bf16x8*)(cur + boff[n + 2][1]);
    }
    if (st) { VM(6); }                       // tile t+1 fully landed
    else if (t + 1 < NT) { VM(0); }          // tail: drain last tile
    bar();
    LGKM0;
    __builtin_amdgcn_sched_barrier(0);
    __builtin_amdgcn_s_setprio(1);
    #pragma unroll
    for (int m = 0; m < 4; m++)
      #pragma unroll
      for (int n = 0; n < 2; n++) {
        acc[m][n + 2] = mfma16(a[m][0], c2[n][0], acc[m][n + 2]);
        acc[m][n + 2] = mfma16(a[m][1], c2[n][1], acc[m][n + 2]);
      }
    __builtin_amdgcn_s_setprio(0);
    __builtin_amdgcn_sched_barrier(0);
    bar();
  }

  if (GU) {
    #pragma unroll
    for (int m = 0; m < 4; m++) {
      int row = m0 + wr * 64 + m * 16 + lg * 4;
      #pragma unroll
      for (int n = 0; n < 2; n++) {
        int col = n0 + wc * 32 + n * 16 + l16;
        #pragma unroll
        for (int r = 0; r < 4; r++) {
          float gt = acc[m][n][r];
          float up = acc[m][n + 2][r];
          float sg = gt / (1.0f + __expf(-gt));
          Cb[(size_t)(row + r) * N + col] = f2bf(sg * up);
        }
      }
    }
  } else {
    #pragma unroll
    for (int m = 0; m < 4; m++) {
      int row = m0 + wr * 64 + m * 16 + lg * 4;
      #pragma unroll
      for (int n = 0; n < 4; n++) {
        int col = n0 + wc * 64 + n * 16 + l16;
        #pragma unroll
        for (int r = 0; r < 4; r++) {
          size_t idx = (size_t)(row + r) * N + col;
          float v = acc[m][n][r];
          if (EPI == 0) {
            Cb[idx] = f2bf(v);
          } else if (EPI == 1) {
            Cf[idx] = X[idx] + v;
          } else {
            Cf[idx] += v;
          }
        }
      }
    }
  }
}

// ------------------- flash attention, sliding window + sink -----------------
__global__ __launch_bounds__(256)
void attn_k(const u16* __restrict__ qb, int ldq,
            const u16* __restrict__ kb, int ldk,
            const u16* __restrict__ vbt, u16* __restrict__ ao)
{
  int q0 = blockIdx.x * 128;
  int h = blockIdx.y;
  int b = blockIdx.z;
  int hk = h >> 2;
  int tid = threadIdx.x;
  int w = tid >> 6, l = tid & 63;
  int l16 = l & 15, lg = l >> 4;

  __shared__ u16 Ks[32 * 128];
  __shared__ u16 Vt[128 * 32];
  __shared__ u16 Ps[4][32 * 40];
  u16* Pw = Ps[w];

  bf16x8 qf[2][4];
  #pragma unroll
  for (int m = 0; m < 2; m++)
    #pragma unroll
    for (int kd = 0; kd < 4; kd++) {
      int row = q0 + w * 32 + m * 16 + l16;
      qf[m][kd] = *(const bf16x8*)(qb + (size_t)(b * SEQ + row) * ldq
                                   + h * HDIM + kd * 32 + lg * 8);
    }

  f32x4 oacc[2][8];
  float mrun[2][4], lrun[2][4];
  f32x4 zero = {0.f, 0.f, 0.f, 0.f};
  #pragma unroll
  for (int m = 0; m < 2; m++) {
    #pragma unroll
    for (int nd = 0; nd < 8; nd++) oacc[m][nd] = zero;
    #pragma unroll
    for (int r = 0; r < 4; r++) { mrun[m][r] = -1e9f; lrun[m][r] = 0.f; }
  }

  int kr0 = tid >> 4,        kc0 = (tid & 15) ^ (kr0 & 7);
  int kr1 = (tid + 256) >> 4, kc1 = (tid & 15) ^ (kr1 & 7);
  int vd0, vk0, vd1, vk1;
  swz_rc(tid, vd0, vk0);
  swz_rc(tid + 256, vd1, vk1);
  const u16* kbase = kb + (size_t)(b * SEQ) * ldk + hk * HDIM;
  const u16* vbase = vbt + (size_t)(b * NKV + hk) * HDIM * SEQ;

  int koff[2][4];
  #pragma unroll
  for (int n = 0; n < 2; n++)
    #pragma unroll
    for (int kd = 0; kd < 4; kd++) {
      int key = n * 16 + l16;
      koff[n][kd] = ((key * 128) + kd * 32 + lg * 8) ^ ((key & 7) * 8);
    }
  int voff[8];
  #pragma unroll
  for (int nd = 0; nd < 8; nd++) {
    int d = nd * 16 + l16;
    voff[nd] = (d * 32 + lg * 8) ^ ((d & 7) * 8);
  }

  int lo = (q0 >= WIN) ? ((q0 - (WIN - 1)) >> 5) : 0;
  int hi = (q0 + 127) >> 5;

  for (int it = (lo > 0 ? lo - 1 : 0); it <= hi; ++it) {
    int kt = (it < lo) ? 0 : it;
    gld16(kbase + (size_t)(kt * 32 + kr0) * ldk + kc0 * 8, Ks + tid * 8);
    gld16(kbase + (size_t)(kt * 32 + kr1) * ldk + kc1 * 8, Ks + (tid + 256) * 8);
    gld16(vbase + (size_t)vd0 * SEQ + kt * 32 + vk0 * 8, Vt + tid * 8);
    gld16(vbase + (size_t)vd1 * SEQ + kt * 32 + vk1 * 8, Vt + (tid + 256) * 8);
    __syncthreads();

    f32x4 sacc[2][2];
    sacc[0][0] = zero; sacc[0][1] = zero; sacc[1][0] = zero; sacc[1][1] = zero;
    #pragma unroll
    for (int kd = 0; kd < 4; kd++) {
      bf16x8 kf0 = *(const bf16x8*)(Ks + koff[0][kd]);
      bf16x8 kf1 = *(const bf16x8*)(Ks + koff[1][kd]);
      #pragma unroll
      for (int m = 0; m < 2; m++) {
        sacc[m][0] = mfma16(qf[m][kd], kf0, sacc[m][0]);
        sacc[m][1] = mfma16(qf[m][kd], kf1, sacc[m][1]);
      }
    }

    #pragma unroll
    for (int m = 0; m < 2; m++) {
      float sc[4];
      #pragma unroll
      for (int r = 0; r < 4; r++) {
        int i = q0 + w * 32 + m * 16 + lg * 4 + r;
        int j0 = kt * 32 + l16;
        int j1 = j0 + 16;
        float s0 = sacc[m][0][r];
        float s1 = sacc[m][1][r];
        bool ok0 = (j0 <= i) && ((i - j0 < WIN) || (j0 < SINKN));
        bool ok1 = (j1 <= i) && ((i - j1 < WIN) || (j1 < SINKN));
        s0 = ok0 ? s0 : -1e9f;
        s1 = ok1 ? s1 : -1e9f;
        float mx = fmaxf(s0, s1);
        mx = fmaxf(mx, __shfl_xor(mx, 1));
        mx = fmaxf(mx, __shfl_xor(mx, 2));
        mx = fmaxf(mx, __shfl_xor(mx, 4));
        mx = fmaxf(mx, __shfl_xor(mx, 8));
        float mold = mrun[m][r];
        float mnew = fmaxf(mold, mx);
        float scl = __expf(mold - mnew);
        mrun[m][r] = mnew;
        float p0 = __expf(s0 - mnew);
        float p1 = __expf(s1 - mnew);
        int prow = m * 16 + lg * 4 + r;
        Pw[prow * 40 + l16] = f2bf(p0);
        Pw[prow * 40 + 16 + l16] = f2bf(p1);
        float ps = p0 + p1;
        ps += __shfl_xor(ps, 1);
        ps += __shfl_xor(ps, 2);
        ps += __shfl_xor(ps, 4);
        ps += __shfl_xor(ps, 8);
        lrun[m][r] = lrun[m][r] * scl + ps;
        sc[r] = scl;
      }
      #pragma unroll
      for (int nd = 0; nd < 8; nd++) {
        oacc[m][nd][0] *= sc[0];
        oacc[m][nd][1] *= sc[1];
        oacc[m][nd][2] *= sc[2];
        oacc[m][nd][3] *= sc[3];
      }
    }

    bf16x8 pa0 = *(const bf16x8*)(Pw + l16 * 40 + lg * 8);
    bf16x8 pa1 = *(const bf16x8*)(Pw + (16 + l16) * 40 + lg * 8);
    #pragma unroll
    for (int nd = 0; nd < 8; nd++) {
      bf16x8 vf = *(const bf16x8*)(Vt + voff[nd]);
      oacc[0][nd] = mfma16(pa0, vf, oacc[0][nd]);
      oacc[1][nd] = mfma16(pa1, vf, oacc[1][nd]);
    }
    __syncthreads();
  }

  #pragma unroll
  for (int m = 0; m < 2; m++)
    #pragma unroll
    for (int r = 0; r < 4; r++) {
      float invl = 1.0f / lrun[m][r];
      int row = q0 + w * 32 + m * 16 + lg * 4 + r;
      #pragma unroll
      for (int nd = 0; nd < 8; nd++) {
        int col = nd * 16 + l16;
        ao[(size_t)(b * SEQ + row) * (NH * HDIM) + h * HDIM + col] =
            f2bf(oacc[m][nd][r] * invl);
      }
    }
}

// ------------------------------- launcher -----------------------------------
extern "C" void kernel_launch(void* const* d_in, const int* in_sizes, int n_in,
                              void* d_out, int out_size, void* d_ws, size_t ws_size,
                              hipStream_t stream)
{
  (void)in_sizes; (void)n_in; (void)out_size;
  const float* x  = (const float*)d_in[0];
  const float* g1 = (const float*)d_in[1];
  const float* g2 = (const float*)d_in[2];
  const float* wq = (const float*)d_in[3];
  const float* wk = (const float*)d_in[4];
  const float* wv = (const float*)d_in[5];
  const float* wo = (const float*)d_in[6];
  const float* wg = (const float*)d_in[7];
  const float* wu = (const float*)d_in[8];
  const float* wd = (const float*)d_in[9];
  float* out = (float*)d_out;

  char* ws = (char*)d_ws;
  size_t off = 0;
  auto alloc = [&](size_t bytes) {
    char* p = ws + off;
    off += (bytes + 255) & ~(size_t)255;
    return p;
  };
  const int NQKV = 3072;   // q 0..2047 | k 2048..2559 | v 2560..3071
  u16* wqkv_t = (u16*)alloc((size_t)NQKV * DM * 2);
  u16* wo_t   = (u16*)alloc((size_t)DM * DM * 2);
  u16* wg_t   = (u16*)alloc((size_t)HID * DM * 2);
  u16* wu_t   = (u16*)alloc((size_t)HID * DM * 2);
  u16* wd_t   = (u16*)alloc((size_t)DM * HID * 2);
  u16* hb     = (u16*)alloc((size_t)TOK * DM * 2);
  // gu (67.1 MB) aliases qkvb+vbt+aob (dead by the time gateup runs) + tail
  char* span0 = ws + off;
  u16* qkvb   = (u16*)alloc((size_t)TOK * NQKV * 2);
  u16* vbt    = (u16*)alloc((size_t)TOK * NKV * HDIM * 2);
  u16* aob    = (u16*)alloc((size_t)TOK * NH * HDIM * 2);
  size_t span_used = (size_t)(ws + off - span0);
  size_t gu_need = (size_t)TOK * HID * 2;
  if (gu_need > span_used) alloc(gu_need - span_used);
  u16* gu = (u16*)span0;
  float* ct  = (float*)alloc((size_t)SEQ * 64 * 4);
  float* st  = (float*)alloc((size_t)SEQ * 64 * 4);
  if (off > ws_size) return;

  dim3 blk(256);
  dim3 blk512(512);

  // weight transposes (fp32 -> bf16, [K][N] -> [N][K])
  wtrans<<<dim3(DM / 32, DM / 32), blk, 0, stream>>>(wq, wqkv_t, DM, DM);
  wtrans<<<dim3((NKV * HDIM) / 32, DM / 32), blk, 0, stream>>>(wk, wqkv_t + (size_t)DM * DM, DM, NKV * HDIM);
  wtrans<<<dim3((NKV * HDIM) / 32, DM / 32), blk, 0, stream>>>(wv, wqkv_t + (size_t)(DM + NKV * HDIM) * DM, DM, NKV * HDIM);
  wtrans<<<dim3(DM / 32, DM / 32), blk, 0, stream>>>(wo, wo_t, DM, DM);
  wtrans<<<dim3(HID / 32, DM / 32), blk, 0, stream>>>(wg, wg_t, DM, HID);
  wtrans<<<dim3(HID / 32, DM / 32), blk, 0, stream>>>(wu, wu_t, DM, HID);
  wtrans<<<dim3(DM / 32, HID / 32), blk, 0, stream>>>(wd, wd_t, HID, DM);

  rope_table_k<<<SEQ * 64 / 256, blk, 0, stream>>>(ct, st);
  rmsnorm_k<<<TOK, blk, 0, stream>>>(x, g1, hb);

  // fused QKV projection: [4096][3072]
  gemmp<0, 0><<<dim3((NQKV / 256) * (TOK / 128)), blk512, 0, stream>>>(
      hb, wqkv_t, nullptr, qkvb, nullptr, nullptr, TOK, NQKV, DM, NQKV / 256);

  rope_apply_k<<<TOK, dim3(NH * 64), 0, stream>>>(qkvb, NQKV, ct, st, 0.08838834764831845f);
  rope_apply_k<<<TOK, dim3(NKV * 64), 0, stream>>>(qkvb + DM, NQKV, ct, st, 1.0f);
  vtrans<<<dim3((NKV * HDIM) / 32, TOK / 32), blk, 0, stream>>>(qkvb + DM + NKV * HDIM, NQKV, vbt);

  attn_k<<<dim3(SEQ / 128, NH, 2), blk, 0, stream>>>(qkvb, NQKV, qkvb + DM, NQKV, vbt, aob);

  gemmp<1, 0><<<dim3((DM / 256) * (TOK / 128)), blk512, 0, stream>>>(
      aob, wo_t, nullptr, nullptr, out, x, TOK, DM, DM, DM / 256);
  rmsnorm_k<<<TOK, blk, 0, stream>>>(out, g2, hb);

  // fused gate+up with silu epilogue (N cols = HID, 128 per block)
  gemmp<0, 1><<<dim3((HID / 128) * (TOK / 128)), blk512, 0, stream>>>(
      hb, wg_t, wu_t, gu, nullptr, nullptr, TOK, HID, DM, HID / 128);

  gemmp<3, 0><<<dim3((DM / 256) * (TOK / 128)), blk512, 0, stream>>>(
      gu, wd_t, nullptr, nullptr, out, nullptr, TOK, DM, HID, DM / 256);
}

// Round 8
// 796.371 us; speedup vs baseline: 1.4542x; 1.0321x over previous
//
#include <hip/hip_runtime.h>
#include <hip/hip_bf16.h>
#include <stdint.h>

#define TOK 4096
#define SEQ 2048
#define DM 2048
#define NH 16
#define NKV 4
#define HDIM 128
#define HID 8192
#define WIN 1024
#define SINKN 4

typedef float f32x4 __attribute__((ext_vector_type(4)));
typedef __bf16 bf16x8 __attribute__((ext_vector_type(8)));
typedef unsigned short u16;
typedef unsigned int u32;

#define VM(n) asm volatile("s_waitcnt vmcnt(" #n ")" ::: "memory")
#define LG(n) asm volatile("s_waitcnt lgkmcnt(" #n ")" ::: "memory")
#define SCHED0 __builtin_amdgcn_sched_barrier(0)

__device__ __forceinline__ u16 f2bf(float f) {
  union { float f; u32 u; } v; v.f = f;
  return (u16)((v.u + 0x7fffu + ((v.u >> 16) & 1u)) >> 16);
}
__device__ __forceinline__ float bf2f(u16 h) {
  union { u32 u; float f; } v; v.u = ((u32)h) << 16;
  return v.f;
}
__device__ __forceinline__ f32x4 mfma16(bf16x8 a, bf16x8 b, f32x4 c) {
  return __builtin_amdgcn_mfma_f32_16x16x32_bf16(a, b, c, 0, 0, 0);
}
__device__ __forceinline__ void gld16(const u16* g, u16* l) {
  __builtin_amdgcn_global_load_lds(
      (const __attribute__((address_space(1))) u32*)g,
      (__attribute__((address_space(3))) u32*)l, 16, 0, 0);
}
__device__ __forceinline__ void bar() {
  asm volatile("s_barrier" ::: "memory");
}
// Inverse swizzle for 64B-row tiles ([rows][32] u16) used by attn staging.
__device__ __forceinline__ void swz_rc(int c, int& row, int& k8) {
  row = 2 * (c >> 3) + (((c >> 2) & 1) ^ ((c >> 4) & 1));
  k8 = (c & 3) ^ (row & 3);
}
// XCD-chunked + grouped raster (G=8).
__device__ __forceinline__ void raster8(int wg, int nwg, int nbx, int& bx, int& by) {
  int cpx = nwg >> 3;
  int s = (wg & 7) * cpx + (wg >> 3);
  by = 8 * (s / (8 * nbx)) + (s & 7);
  bx = (s >> 3) % nbx;
}

// ---------------- weight transpose fp32[K][N] -> bf16[N][K] ----------------
__global__ __launch_bounds__(256)
void wtrans(const float* __restrict__ in, u16* __restrict__ out, int K, int N)
{
  __shared__ float t[32][33];
  int tx = threadIdx.x & 31, ty = threadIdx.x >> 5;
  int bx = blockIdx.x, by = blockIdx.y;
  #pragma unroll
  for (int i = 0; i < 4; i++) {
    int r = ty + i * 8;
    t[r][tx] = in[(size_t)(by * 32 + r) * N + bx * 32 + tx];
  }
  __syncthreads();
  #pragma unroll
  for (int i = 0; i < 4; i++) {
    int r = ty + i * 8;
    out[(size_t)(bx * 32 + r) * K + by * 32 + tx] = f2bf(t[tx][r]);
  }
}

// ---- V transpose: bf16 [4096][ld] cols -> [(b*4+hk)*128+d][2048] -----------
__global__ __launch_bounds__(256)
void vtrans(const u16* __restrict__ in, int ld, u16* __restrict__ out)
{
  __shared__ u16 t[32][33];
  int tx = threadIdx.x & 31, ty = threadIdx.x >> 5;
  int bx = blockIdx.x;
  int by = blockIdx.y;
  #pragma unroll
  for (int i = 0; i < 4; i++) {
    int r = ty + i * 8;
    t[r][tx] = in[(size_t)(by * 32 + r) * ld + bx * 32 + tx];
  }
  __syncthreads();
  int b = (by * 32) >> 11;
  int s0 = (by * 32) & (SEQ - 1);
  #pragma unroll
  for (int i = 0; i < 4; i++) {
    int c = bx * 32 + ty + i * 8;
    out[(size_t)(b * (NKV * HDIM) + c) * SEQ + s0 + tx] = t[tx][ty + i * 8];
  }
}

// ---------------------------- RoPE table -----------------------------------
__global__ __launch_bounds__(256)
void rope_table_k(float* __restrict__ ct, float* __restrict__ st)
{
  int idx = blockIdx.x * 256 + threadIdx.x;
  int pos = idx >> 6, d = idx & 63;
  float inv = powf(10000.0f, -(float)d / 64.0f);
  float a = (float)pos * inv;
  ct[idx] = cosf(a);
  st[idx] = sinf(a);
}

// ----------------------- RoPE apply (in place, bf16) ------------------------
__global__ void rope_apply_k(u16* __restrict__ q, int ld,
                             const float* __restrict__ ct,
                             const float* __restrict__ st, float scale)
{
  int t = blockIdx.x;
  int hh = threadIdx.x >> 6;
  int d = threadIdx.x & 63;
  int pos = t & (SEQ - 1);
  size_t base = (size_t)t * ld + hh * HDIM + d;
  float x1 = bf2f(q[base]), x2 = bf2f(q[base + 64]);
  float c = ct[pos * 64 + d], s = st[pos * 64 + d];
  q[base]      = f2bf((x1 * c - x2 * s) * scale);
  q[base + 64] = f2bf((x2 * c + x1 * s) * scale);
}

// ------------------------------ RMSNorm ------------------------------------
__global__ __launch_bounds__(256)
void rmsnorm_k(const float* __restrict__ x, const float* __restrict__ g,
               u16* __restrict__ o)
{
  int row = blockIdx.x;
  int tid = threadIdx.x;
  const float* xr = x + (size_t)row * DM;
  float4 v0 = *(const float4*)(xr + tid * 8);
  float4 v1 = *(const float4*)(xr + tid * 8 + 4);
  float ss = v0.x*v0.x + v0.y*v0.y + v0.z*v0.z + v0.w*v0.w
           + v1.x*v1.x + v1.y*v1.y + v1.z*v1.z + v1.w*v1.w;
  #pragma unroll
  for (int d = 1; d < 64; d <<= 1) ss += __shfl_xor(ss, d);
  __shared__ float red[4];
  if ((tid & 63) == 0) red[tid >> 6] = ss;
  __syncthreads();
  float inv = rsqrtf((red[0] + red[1] + red[2] + red[3]) * (1.0f / DM) + 1e-6f);
  float4 g0 = *(const float4*)(g + tid * 8);
  float4 g1 = *(const float4*)(g + tid * 8 + 4);
  ushort4 o0, o1;
  o0.x = f2bf(v0.x * inv * g0.x); o0.y = f2bf(v0.y * inv * g0.y);
  o0.z = f2bf(v0.z * inv * g0.z); o0.w = f2bf(v0.w * inv * g0.w);
  o1.x = f2bf(v1.x * inv * g1.x); o1.y = f2bf(v1.y * inv * g1.y);
  o1.z = f2bf(v1.z * inv * g1.z); o1.w = f2bf(v1.w * inv * g1.w);
  *(ushort4*)(o + (size_t)row * DM + tid * 8) = o0;
  *(ushort4*)(o + (size_t)row * DM + tid * 8 + 4) = o1;
}

// ------------- deep-pipelined GEMM: 128 x 256, BK=64, 3-slot ring -----------
// r7 structure + read-lookahead retrofit: P_b's B-reads issued at P_a-top
// behind sched_barrier; P_a waits lgkmcnt(4) (counted), P_b lgkmcnt(0).
template<int EPI>
__global__ __launch_bounds__(512, 1)
void gemmp(const u16* __restrict__ A, const u16* __restrict__ Bt,
           u16* __restrict__ Cb, float* __restrict__ Cf,
           const float* __restrict__ X, int M, int N, int K, int nbx)
{
  constexpr int ASZ = 128 * 64;
  constexpr int SLOT = ASZ + 256 * 64;
  __shared__ u16 lds[3 * SLOT];

  int bx, by;
  raster8(blockIdx.x, gridDim.x, nbx, bx, by);
  int m0 = by * 128;
  int n0 = bx * 256;

  int tid = threadIdx.x;
  int l = tid & 63, w = tid >> 6;
  int l16 = l & 15, lg = l >> 4;
  int wr = w >> 2, wc = w & 3;

  int aoff[4][2], boff[4][2];
  #pragma unroll
  for (int m = 0; m < 4; m++)
    #pragma unroll
    for (int kk = 0; kk < 2; kk++) {
      int row = wr * 64 + m * 16 + l16;
      aoff[m][kk] = ((row * 128 + kk * 64 + lg * 16) ^ ((row & 7) << 4)) >> 1;
    }
  #pragma unroll
  for (int n = 0; n < 4; n++)
    #pragma unroll
    for (int kk = 0; kk < 2; kk++) {
      int br = wc * 64 + n * 16 + l16;
      boff[n][kk] = ASZ + (((br * 128 + kk * 64 + lg * 16) ^ ((br & 7) << 4)) >> 1);
    }

  int urow = tid >> 3;
  int cc = (tid & 7) ^ (urow & 7);
  const u16* pA[2];
  const u16* pB[4];
  pA[0] = A + (size_t)(m0 + urow) * K + cc * 8;
  pA[1] = A + (size_t)(m0 + 64 + urow) * K + cc * 8;
  #pragma unroll
  for (int u = 0; u < 4; u++)
    pB[u] = Bt + (size_t)(n0 + u * 64 + urow) * K + cc * 8;

  const int NT = K >> 6;

  auto stA = [&](int tt, int u) {
    gld16(pA[u] + (size_t)tt * 64, lds + (tt % 3) * SLOT + u * 4096 + tid * 8);
  };
  auto stB = [&](int tt, int u) {
    gld16(pB[u] + (size_t)tt * 64, lds + (tt % 3) * SLOT + ASZ + u * 4096 + tid * 8);
  };

  #pragma unroll
  for (int u = 0; u < 4; u++) stB(0, u);
  stA(0, 0); stA(0, 1);
  #pragma unroll
  for (int u = 0; u < 4; u++) stB(1, u);
  stA(1, 0); stA(1, 1);
  VM(6);
  bar();

  f32x4 acc[4][4];
  f32x4 zero = {0.f, 0.f, 0.f, 0.f};
  #pragma unroll
  for (int m = 0; m < 4; m++)
    #pragma unroll
    for (int n = 0; n < 4; n++) acc[m][n] = zero;

  for (int t = 0; t < NT; ++t) {
    u16* cur = lds + (t % 3) * SLOT;
    const bool st = (t + 2 < NT);

    // ---------------- P_a: n-frags 0,1 (reads for P_b prefetched) ----------
    if (st) { stB(t + 2, 0); stB(t + 2, 1); stB(t + 2, 2); }
    bf16x8 a[4][2], b[2][2], c2[2][2];
    #pragma unroll
    for (int m = 0; m < 4; m++) {
      a[m][0] = *(const bf16x8*)(cur + aoff[m][0]);
      a[m][1] = *(const bf16x8*)(cur + aoff[m][1]);
    }
    #pragma unroll
    for (int n = 0; n < 2; n++) {
      b[n][0] = *(const bf16x8*)(cur + boff[n][0]);
      b[n][1] = *(const bf16x8*)(cur + boff[n][1]);
    }
    SCHED0;
    #pragma unroll
    for (int n = 0; n < 2; n++) {
      c2[n][0] = *(const bf16x8*)(cur + boff[n + 2][0]);
      c2[n][1] = *(const bf16x8*)(cur + boff[n + 2][1]);
    }
    bar();
    LG(4);
    SCHED0;
    __builtin_amdgcn_s_setprio(1);
    #pragma unroll
    for (int m = 0; m < 4; m++)
      #pragma unroll
      for (int n = 0; n < 2; n++) {
        acc[m][n] = mfma16(a[m][0], b[n][0], acc[m][n]);
        acc[m][n] = mfma16(a[m][1], b[n][1], acc[m][n]);
      }
    __builtin_amdgcn_s_setprio(0);
    SCHED0;
    bar();

    // ---------------- P_b: n-frags 2,3 ----------------
    if (st) { stB(t + 2, 3); stA(t + 2, 0); stA(t + 2, 1); }
    if (st) { VM(6); }
    else if (t + 1 < NT) { VM(0); }
    bar();
    LG(0);
    SCHED0;
    __builtin_amdgcn_s_setprio(1);
    #pragma unroll
    for (int m = 0; m < 4; m++)
      #pragma unroll
      for (int n = 0; n < 2; n++) {
        acc[m][n + 2] = mfma16(a[m][0], c2[n][0], acc[m][n + 2]);
        acc[m][n + 2] = mfma16(a[m][1], c2[n][1], acc[m][n + 2]);
      }
    __builtin_amdgcn_s_setprio(0);
    SCHED0;
    bar();
  }

  #pragma unroll
  for (int m = 0; m < 4; m++) {
    int row = m0 + wr * 64 + m * 16 + lg * 4;
    #pragma unroll
    for (int n = 0; n < 4; n++) {
      int col = n0 + wc * 64 + n * 16 + l16;
      #pragma unroll
      for (int r = 0; r < 4; r++) {
        size_t idx = (size_t)(row + r) * N + col;
        float v = acc[m][n][r];
        if (EPI == 0) {
          Cb[idx] = f2bf(v);
        } else if (EPI == 1) {
          Cf[idx] = X[idx] + v;
        } else {
          Cf[idx] += v;
        }
      }
    }
  }
}

// ---- fused gate+up GEMM: 256x(128|128), BK=64, 2-slot, 4-phase pipelined ---
// 8 waves 2Mx4N; wave = 128 rows x (32 gate + 32 up). 64 MFMA/tile/wave in 4
// phases of 16. Reads 1 phase ahead, counted lgkmcnt(4/8/4/0), groups pinned
// by sched_barrier. Staging halves: A-h1(t+1)@ph0, {A-h0,B0,B1}(t+2)@ph3.
// VM(6) at ph3 end => tile t+1 fully landed (ledger: newest 6 = ph3's own).
// Slot-liveness: each victim's reads drain >=1 barrier before stage-issue.
__global__ __launch_bounds__(512, 1)
void gemm256gu(const u16* __restrict__ A, const u16* __restrict__ Bg,
               const u16* __restrict__ Bu, u16* __restrict__ Gu,
               int K, int nbx)
{
  constexpr int SLOT = 32768;           // u16: A 16384 + B 16384
  __shared__ u16 lds[2 * SLOT];         // 128 KiB

  int bx, by;
  raster8(blockIdx.x, gridDim.x, nbx, bx, by);
  int m0 = by * 256, n0 = bx * 128;

  int tid = threadIdx.x;
  int l = tid & 63, w = tid >> 6;
  int l16 = l & 15, lg = l >> 4;
  int wr = w >> 2, wc = w & 3;

  // read bases (u16). swz bits only touch bits 4-6 of the 128B row => fold.
  int sw = (l16 & 7) << 4;
  int aoffk[2], boffk[2];
  #pragma unroll
  for (int kk = 0; kk < 2; kk++) {
    aoffk[kk] = ((wr * 128 + l16) * 128 + ((kk * 64 + lg * 16) ^ sw)) >> 1;
    boffk[kk] = 16384 + ((((wc * 32 + l16) * 128) + ((kk * 64 + lg * 16) ^ sw)) >> 1);
  }
  // A frag(m,half): + half*4096 + m*1024 (u16); B frag(n): +(n&1)*1024+(n>>1)*8192

  int rh = tid >> 3;
  int cc = (tid & 7) ^ (rh & 7);
  const u16* pA0[2]; const u16* pA1[2]; const u16* pBg[2]; const u16* pBu[2];
  #pragma unroll
  for (int ll = 0; ll < 2; ll++) {
    pA0[ll] = A + (size_t)(m0 + ll * 64 + rh) * K + cc * 8;
    pA1[ll] = A + (size_t)(m0 + 128 + ll * 64 + rh) * K + cc * 8;
    pBg[ll] = Bg + (size_t)(n0 + ll * 64 + rh) * K + cc * 8;
    pBu[ll] = Bu + (size_t)(n0 + ll * 64 + rh) * K + cc * 8;
  }

  const int NT = K >> 6;

  auto stA0 = [&](int tt) {
    u16* d = lds + (tt & 1) * SLOT;
    gld16(pA0[0] + (size_t)tt * 64, d + tid * 8);
    gld16(pA0[1] + (size_t)tt * 64, d + 4096 + tid * 8);
  };
  auto stA1 = [&](int tt) {
    u16* d = lds + (tt & 1) * SLOT + 8192;
    gld16(pA1[0] + (size_t)tt * 64, d + tid * 8);
    gld16(pA1[1] + (size_t)tt * 64, d + 4096 + tid * 8);
  };
  auto stBg = [&](int tt) {
    u16* d = lds + (tt & 1) * SLOT + 16384;
    gld16(pBg[0] + (size_t)tt * 64, d + tid * 8);
    gld16(pBg[1] + (size_t)tt * 64, d + 4096 + tid * 8);
  };
  auto stBu = [&](int tt) {
    u16* d = lds + (tt & 1) * SLOT + 16384 + 8192;
    gld16(pBu[0] + (size_t)tt * 64, d + tid * 8);
    gld16(pBu[1] + (size_t)tt * 64, d + 4096 + tid * 8);
  };

  // prologue: tile0 full (8), then tile1 {A-h0,B0,B1} (6); tile1 A-h1 @ph0(t=0)
  stA0(0); stA1(0); stBg(0); stBu(0);
  stA0(1); stBg(1); stBu(1);
  VM(6);
  bar();

  f32x4 acc[8][4];
  f32x4 zero = {0.f, 0.f, 0.f, 0.f};
  #pragma unroll
  for (int m = 0; m < 8; m++)
    #pragma unroll
    for (int n = 0; n < 4; n++) acc[m][n] = zero;

  for (int t = 0; t < NT; ++t) {
    u16* cur = lds + (t & 1) * SLOT;

    // -------- ph0: MFMA mh0*kk0; reads needs0+needs1; stage A-h1(t+1) -------
    if (t + 1 < NT) stA1(t + 1);
    bf16x8 a0[4], a1[4], b0[4];
    #pragma unroll
    for (int m = 0; m < 4; m++)
      a0[m] = *(const bf16x8*)(cur + aoffk[0] + m * 1024);
    #pragma unroll
    for (int n = 0; n < 4; n++)
      b0[n] = *(const bf16x8*)(cur + boffk[0] + (n & 1) * 1024 + (n >> 1) * 8192);
    SCHED0;
    #pragma unroll
    for (int m = 0; m < 4; m++)
      a1[m] = *(const bf16x8*)(cur + aoffk[0] + 4096 + m * 1024);
    bar();
    LG(4);
    SCHED0;
    __builtin_amdgcn_s_setprio(1);
    #pragma unroll
    for (int m = 0; m < 4; m++)
      #pragma unroll
      for (int n = 0; n < 4; n++)
        acc[m][n] = mfma16(a0[m], b0[n], acc[m][n]);
    __builtin_amdgcn_s_setprio(0);
    SCHED0;
    bar();

    // -------- ph1: MFMA mh1*kk0; reads needs2 (A mh0 kk1 + B kk1) -----------
    bf16x8 a2[4], b1[4];
    #pragma unroll
    for (int m = 0; m < 4; m++)
      a2[m] = *(const bf16x8*)(cur + aoffk[1] + m * 1024);
    #pragma unroll
    for (int n = 0; n < 4; n++)
      b1[n] = *(const bf16x8*)(cur + boffk[1] + (n & 1) * 1024 + (n >> 1) * 8192);
    bar();
    LG(8);
    SCHED0;
    __builtin_amdgcn_s_setprio(1);
    #pragma unroll
    for (int m = 0; m < 4; m++)
      #pragma unroll
      for (int n = 0; n < 4; n++)
        acc[4 + m][n] = mfma16(a1[m], b0[n], acc[4 + m][n]);
    __builtin_amdgcn_s_setprio(0);
    SCHED0;
    bar();

    // -------- ph2: MFMA mh0*kk1; reads needs3 (A mh1 kk1) -------------------
    bf16x8 a3[4];
    #pragma unroll
    for (int m = 0; m < 4; m++)
      a3[m] = *(const bf16x8*)(cur + aoffk[1] + 4096 + m * 1024);
    bar();
    LG(4);
    SCHED0;
    __builtin_amdgcn_s_setprio(1);
    #pragma unroll
    for (int m = 0; m < 4; m++)
      #pragma unroll
      for (int n = 0; n < 4; n++)
        acc[m][n] = mfma16(a2[m], b1[n], acc[m][n]);
    __builtin_amdgcn_s_setprio(0);
    SCHED0;
    bar();

    // -------- ph3: MFMA mh1*kk1; stage {A-h0,B0,B1}(t+2); VM(6) -------------
    if (t + 2 < NT) { stA0(t + 2); stBg(t + 2); stBu(t + 2); }
    bar();
    LG(0);
    SCHED0;
    __builtin_amdgcn_s_setprio(1);
    #pragma unroll
    for (int m = 0; m < 4; m++)
      #pragma unroll
      for (int n = 0; n < 4; n++)
        acc[4 + m][n] = mfma16(a3[m], b1[n], acc[4 + m][n]);
    __builtin_amdgcn_s_setprio(0);
    SCHED0;
    if (t + 2 < NT) { VM(6); }
    else if (t + 1 < NT) { VM(0); }
    bar();
  }

  // epilogue: gu = silu(gate) * up
  #pragma unroll
  for (int m = 0; m < 8; m++) {
    int row = m0 + wr * 128 + m * 16 + lg * 4;
    #pragma unroll
    for (int n = 0; n < 2; n++) {
      int col = n0 + wc * 32 + n * 16 + l16;
      #pragma unroll
      for (int r = 0; r < 4; r++) {
        float gt = acc[m][n][r];
        float up = acc[m][n + 2][r];
        float sg = gt / (1.0f + __expf(-gt));
        Gu[(size_t)(row + r) * HID + col] = f2bf(sg * up);
      }
    }
  }
}

// ------------------- flash attention, sliding window + sink -----------------
__global__ __launch_bounds__(256)
void attn_k(const u16* __restrict__ qb, int ldq,
            const u16* __restrict__ kb, int ldk,
            const u16* __restrict__ vbt, u16* __restrict__ ao)
{
  int q0 = blockIdx.x * 128;
  int h = blockIdx.y;
  int b = blockIdx.z;
  int hk = h >> 2;
  int tid = threadIdx.x;
  int w = tid >> 6, l = tid & 63;
  int l16 = l & 15, lg = l >> 4;

  __shared__ u16 Ks[32 * 128];
  __shared__ u16 Vt[128 * 32];
  __shared__ u16 Ps[4][32 * 40];
  u16* Pw = Ps[w];

  bf16x8 qf[2][4];
  #pragma unroll
  for (int m = 0; m < 2; m++)
    #pragma unroll
    for (int kd = 0; kd < 4; kd++) {
      int row = q0 + w * 32 + m * 16 + l16;
      qf[m][kd] = *(const bf16x8*)(qb + (size_t)(b * SEQ + row) * ldq
                                   + h * HDIM + kd * 32 + lg * 8);
    }

  f32x4 oacc[2][8];
  float mrun[2][4], lrun[2][4];
  f32x4 zero = {0.f, 0.f, 0.f, 0.f};
  #pragma unroll
  for (int m = 0; m < 2; m++) {
    #pragma unroll
    for (int nd = 0; nd < 8; nd++) oacc[m][nd] = zero;
    #pragma unroll
    for (int r = 0; r < 4; r++) { mrun[m][r] = -1e9f; lrun[m][r] = 0.f; }
  }

  int kr0 = tid >> 4,        kc0 = (tid & 15) ^ (kr0 & 7);
  int kr1 = (tid + 256) >> 4, kc1 = (tid & 15) ^ (kr1 & 7);
  int vd0, vk0, vd1, vk1;
  swz_rc(tid, vd0, vk0);
  swz_rc(tid + 256, vd1, vk1);
  const u16* kbase = kb + (size_t)(b * SEQ) * ldk + hk * HDIM;
  const u16* vbase = vbt + (size_t)(b * NKV + hk) * HDIM * SEQ;

  int koff[2][4];
  #pragma unroll
  for (int n = 0; n < 2; n++)
    #pragma unroll
    for (int kd = 0; kd < 4; kd++) {
      int key = n * 16 + l16;
      koff[n][kd] = ((key * 128) + kd * 32 + lg * 8) ^ ((key & 7) * 8);
    }
  int voff[8];
  #pragma unroll
  for (int nd = 0; nd < 8; nd++) {
    int d = nd * 16 + l16;
    voff[nd] = (d * 32 + lg * 8) ^ ((d & 7) * 8);
  }

  int lo = (q0 >= WIN) ? ((q0 - (WIN - 1)) >> 5) : 0;
  int hi = (q0 + 127) >> 5;

  for (int it = (lo > 0 ? lo - 1 : 0); it <= hi; ++it) {
    int kt = (it < lo) ? 0 : it;
    gld16(kbase + (size_t)(kt * 32 + kr0) * ldk + kc0 * 8, Ks + tid * 8);
    gld16(kbase + (size_t)(kt * 32 + kr1) * ldk + kc1 * 8, Ks + (tid + 256) * 8);
    gld16(vbase + (size_t)vd0 * SEQ + kt * 32 + vk0 * 8, Vt + tid * 8);
    gld16(vbase + (size_t)vd1 * SEQ + kt * 32 + vk1 * 8, Vt + (tid + 256) * 8);
    __syncthreads();

    f32x4 sacc[2][2];
    sacc[0][0] = zero; sacc[0][1] = zero; sacc[1][0] = zero; sacc[1][1] = zero;
    #pragma unroll
    for (int kd = 0; kd < 4; kd++) {
      bf16x8 kf0 = *(const bf16x8*)(Ks + koff[0][kd]);
      bf16x8 kf1 = *(const bf16x8*)(Ks + koff[1][kd]);
      #pragma unroll
      for (int m = 0; m < 2; m++) {
        sacc[m][0] = mfma16(qf[m][kd], kf0, sacc[m][0]);
        sacc[m][1] = mfma16(qf[m][kd], kf1, sacc[m][1]);
      }
    }

    #pragma unroll
    for (int m = 0; m < 2; m++) {
      float sc[4];
      #pragma unroll
      for (int r = 0; r < 4; r++) {
        int i = q0 + w * 32 + m * 16 + lg * 4 + r;
        int j0 = kt * 32 + l16;
        int j1 = j0 + 16;
        float s0 = sacc[m][0][r];
        float s1 = sacc[m][1][r];
        bool ok0 = (j0 <= i) && ((i - j0 < WIN) || (j0 < SINKN));
        bool ok1 = (j1 <= i) && ((i - j1 < WIN) || (j1 < SINKN));
        s0 = ok0 ? s0 : -1e9f;
        s1 = ok1 ? s1 : -1e9f;
        float mx = fmaxf(s0, s1);
        mx = fmaxf(mx, __shfl_xor(mx, 1));
        mx = fmaxf(mx, __shfl_xor(mx, 2));
        mx = fmaxf(mx, __shfl_xor(mx, 4));
        mx = fmaxf(mx, __shfl_xor(mx, 8));
        float mold = mrun[m][r];
        float mnew = fmaxf(mold, mx);
        float scl = __expf(mold - mnew);
        mrun[m][r] = mnew;
        float p0 = __expf(s0 - mnew);
        float p1 = __expf(s1 - mnew);
        int prow = m * 16 + lg * 4 + r;
        Pw[prow * 40 + l16] = f2bf(p0);
        Pw[prow * 40 + 16 + l16] = f2bf(p1);
        float ps = p0 + p1;
        ps += __shfl_xor(ps, 1);
        ps += __shfl_xor(ps, 2);
        ps += __shfl_xor(ps, 4);
        ps += __shfl_xor(ps, 8);
        lrun[m][r] = lrun[m][r] * scl + ps;
        sc[r] = scl;
      }
      #pragma unroll
      for (int nd = 0; nd < 8; nd++) {
        oacc[m][nd][0] *= sc[0];
        oacc[m][nd][1] *= sc[1];
        oacc[m][nd][2] *= sc[2];
        oacc[m][nd][3] *= sc[3];
      }
    }

    bf16x8 pa0 = *(const bf16x8*)(Pw + l16 * 40 + lg * 8);
    bf16x8 pa1 = *(const bf16x8*)(Pw + (16 + l16) * 40 + lg * 8);
    #pragma unroll
    for (int nd = 0; nd < 8; nd++) {
      bf16x8 vf = *(const bf16x8*)(Vt + voff[nd]);
      oacc[0][nd] = mfma16(pa0, vf, oacc[0][nd]);
      oacc[1][nd] = mfma16(pa1, vf, oacc[1][nd]);
    }
    __syncthreads();
  }

  #pragma unroll
  for (int m = 0; m < 2; m++)
    #pragma unroll
    for (int r = 0; r < 4; r++) {
      float invl = 1.0f / lrun[m][r];
      int row = q0 + w * 32 + m * 16 + lg * 4 + r;
      #pragma unroll
      for (int nd = 0; nd < 8; nd++) {
        int col = nd * 16 + l16;
        ao[(size_t)(b * SEQ + row) * (NH * HDIM) + h * HDIM + col] =
            f2bf(oacc[m][nd][r] * invl);
      }
    }
}

// ------------------------------- launcher -----------------------------------
extern "C" void kernel_launch(void* const* d_in, const int* in_sizes, int n_in,
                              void* d_out, int out_size, void* d_ws, size_t ws_size,
                              hipStream_t stream)
{
  (void)in_sizes; (void)n_in; (void)out_size;
  const float* x  = (const float*)d_in[0];
  const float* g1 = (const float*)d_in[1];
  const float* g2 = (const float*)d_in[2];
  const float* wq = (const float*)d_in[3];
  const float* wk = (const float*)d_in[4];
  const float* wv = (const float*)d_in[5];
  const float* wo = (const float*)d_in[6];
  const float* wg = (const float*)d_in[7];
  const float* wu = (const float*)d_in[8];
  const float* wd = (const float*)d_in[9];
  float* out = (float*)d_out;

  char* ws = (char*)d_ws;
  size_t off = 0;
  auto alloc = [&](size_t bytes) {
    char* p = ws + off;
    off += (bytes + 255) & ~(size_t)255;
    return p;
  };
  const int NQKV = 3072;   // q 0..2047 | k 2048..2559 | v 2560..3071
  u16* wqkv_t = (u16*)alloc((size_t)NQKV * DM * 2);
  u16* wo_t   = (u16*)alloc((size_t)DM * DM * 2);
  u16* wg_t   = (u16*)alloc((size_t)HID * DM * 2);
  u16* wu_t   = (u16*)alloc((size_t)HID * DM * 2);
  u16* wd_t   = (u16*)alloc((size_t)DM * HID * 2);
  u16* hb     = (u16*)alloc((size_t)TOK * DM * 2);
  // gu (67.1 MB) aliases qkvb+vbt+aob (dead by the time gateup runs) + tail
  char* span0 = ws + off;
  u16* qkvb   = (u16*)alloc((size_t)TOK * NQKV * 2);
  u16* vbt    = (u16*)alloc((size_t)TOK * NKV * HDIM * 2);
  u16* aob    = (u16*)alloc((size_t)TOK * NH * HDIM * 2);
  size_t span_used = (size_t)(ws + off - span0);
  size_t gu_need = (size_t)TOK * HID * 2;
  if (gu_need > span_used) alloc(gu_need - span_used);
  u16* gu = (u16*)span0;
  float* ct  = (float*)alloc((size_t)SEQ * 64 * 4);
  float* st  = (float*)alloc((size_t)SEQ * 64 * 4);
  if (off > ws_size) return;

  dim3 blk(256);
  dim3 blk512(512);

  // weight transposes (fp32 -> bf16, [K][N] -> [N][K])
  wtrans<<<dim3(DM / 32, DM / 32), blk, 0, stream>>>(wq, wqkv_t, DM, DM);
  wtrans<<<dim3((NKV * HDIM) / 32, DM / 32), blk, 0, stream>>>(wk, wqkv_t + (size_t)DM * DM, DM, NKV * HDIM);
  wtrans<<<dim3((NKV * HDIM) / 32, DM / 32), blk, 0, stream>>>(wv, wqkv_t + (size_t)(DM + NKV * HDIM) * DM, DM, NKV * HDIM);
  wtrans<<<dim3(DM / 32, DM / 32), blk, 0, stream>>>(wo, wo_t, DM, DM);
  wtrans<<<dim3(HID / 32, DM / 32), blk, 0, stream>>>(wg, wg_t, DM, HID);
  wtrans<<<dim3(HID / 32, DM / 32), blk, 0, stream>>>(wu, wu_t, DM, HID);
  wtrans<<<dim3(DM / 32, HID / 32), blk, 0, stream>>>(wd, wd_t, HID, DM);

  rope_table_k<<<SEQ * 64 / 256, blk, 0, stream>>>(ct, st);
  rmsnorm_k<<<TOK, blk, 0, stream>>>(x, g1, hb);

  // fused QKV projection: [4096][3072]
  gemmp<0><<<dim3((NQKV / 256) * (TOK / 128)), blk512, 0, stream>>>(
      hb, wqkv_t, qkvb, nullptr, nullptr, TOK, NQKV, DM, NQKV / 256);

  rope_apply_k<<<TOK, dim3(NH * 64), 0, stream>>>(qkvb, NQKV, ct, st, 0.08838834764831845f);
  rope_apply_k<<<TOK, dim3(NKV * 64), 0, stream>>>(qkvb + DM, NQKV, ct, st, 1.0f);
  vtrans<<<dim3((NKV * HDIM) / 32, TOK / 32), blk, 0, stream>>>(qkvb + DM + NKV * HDIM, NQKV, vbt);

  attn_k<<<dim3(SEQ / 128, NH, 2), blk, 0, stream>>>(qkvb, NQKV, qkvb + DM, NQKV, vbt, aob);

  gemmp<1><<<dim3((DM / 256) * (TOK / 128)), blk512, 0, stream>>>(
      aob, wo_t, nullptr, out, x, TOK, DM, DM, DM / 256);
  rmsnorm_k<<<TOK, blk, 0, stream>>>(out, g2, hb);

  // fused gate+up with silu epilogue: 256x256 4-phase pipelined kernel
  gemm256gu<<<dim3((HID / 128) * (TOK / 256)), blk512, 0, stream>>>(
      hb, wg_t, wu_t, gu, DM, HID / 128);

  gemmp<3><<<dim3((DM / 256) * (TOK / 128)), blk512, 0, stream>>>(
      gu, wd_t, nullptr, out, nullptr, TOK, DM, HID, DM / 256);
}

// Round 9
// 781.848 us; speedup vs baseline: 1.4812x; 1.0186x over previous
//
#include <hip/hip_runtime.h>
#include <hip/hip_bf16.h>
#include <stdint.h>

#define TOK 4096
#define SEQ 2048
#define DM 2048
#define NH 16
#define NKV 4
#define HDIM 128
#define HID 8192
#define WIN 1024
#define SINKN 4

typedef float f32x4 __attribute__((ext_vector_type(4)));
typedef __bf16 bf16x8 __attribute__((ext_vector_type(8)));
typedef unsigned short u16;
typedef unsigned int u32;

#define VM(n) asm volatile("s_waitcnt vmcnt(" #n ")" ::: "memory")
#define LG(n) asm volatile("s_waitcnt lgkmcnt(" #n ")" ::: "memory")
#define SCHED0 __builtin_amdgcn_sched_barrier(0)

__device__ __forceinline__ u16 f2bf(float f) {
  union { float f; u32 u; } v; v.f = f;
  return (u16)((v.u + 0x7fffu + ((v.u >> 16) & 1u)) >> 16);
}
__device__ __forceinline__ float bf2f(u16 h) {
  union { u32 u; float f; } v; v.u = ((u32)h) << 16;
  return v.f;
}
__device__ __forceinline__ f32x4 mfma16(bf16x8 a, bf16x8 b, f32x4 c) {
  return __builtin_amdgcn_mfma_f32_16x16x32_bf16(a, b, c, 0, 0, 0);
}
__device__ __forceinline__ void gld16(const u16* g, u16* l) {
  __builtin_amdgcn_global_load_lds(
      (const __attribute__((address_space(1))) u32*)g,
      (__attribute__((address_space(3))) u32*)l, 16, 0, 0);
}
__device__ __forceinline__ void bar() {
  asm volatile("s_barrier" ::: "memory");
}
// Inverse swizzle for 64B-row tiles ([rows][32] u16) used by attn staging.
__device__ __forceinline__ void swz_rc(int c, int& row, int& k8) {
  row = 2 * (c >> 3) + (((c >> 2) & 1) ^ ((c >> 4) & 1));
  k8 = (c & 3) ^ (row & 3);
}
// XCD-chunked + grouped raster (G=8).
__device__ __forceinline__ void raster8(int wg, int nwg, int nbx, int& bx, int& by) {
  int cpx = nwg >> 3;
  int s = (wg & 7) * cpx + (wg >> 3);
  by = 8 * (s / (8 * nbx)) + (s & 7);
  bx = (s >> 3) % nbx;
}

// ---------------- weight transpose fp32[K][N] -> bf16[N][K] ----------------
__global__ __launch_bounds__(256)
void wtrans(const float* __restrict__ in, u16* __restrict__ out, int K, int N)
{
  __shared__ float t[32][33];
  int tx = threadIdx.x & 31, ty = threadIdx.x >> 5;
  int bx = blockIdx.x, by = blockIdx.y;
  #pragma unroll
  for (int i = 0; i < 4; i++) {
    int r = ty + i * 8;
    t[r][tx] = in[(size_t)(by * 32 + r) * N + bx * 32 + tx];
  }
  __syncthreads();
  #pragma unroll
  for (int i = 0; i < 4; i++) {
    int r = ty + i * 8;
    out[(size_t)(bx * 32 + r) * K + by * 32 + tx] = f2bf(t[tx][r]);
  }
}

// ---- V transpose: bf16 [4096][ld] cols -> [(b*4+hk)*128+d][2048] -----------
__global__ __launch_bounds__(256)
void vtrans(const u16* __restrict__ in, int ld, u16* __restrict__ out)
{
  __shared__ u16 t[32][33];
  int tx = threadIdx.x & 31, ty = threadIdx.x >> 5;
  int bx = blockIdx.x;
  int by = blockIdx.y;
  #pragma unroll
  for (int i = 0; i < 4; i++) {
    int r = ty + i * 8;
    t[r][tx] = in[(size_t)(by * 32 + r) * ld + bx * 32 + tx];
  }
  __syncthreads();
  int b = (by * 32) >> 11;
  int s0 = (by * 32) & (SEQ - 1);
  #pragma unroll
  for (int i = 0; i < 4; i++) {
    int c = bx * 32 + ty + i * 8;
    out[(size_t)(b * (NKV * HDIM) + c) * SEQ + s0 + tx] = t[tx][ty + i * 8];
  }
}

// ---------------------------- RoPE table -----------------------------------
__global__ __launch_bounds__(256)
void rope_table_k(float* __restrict__ ct, float* __restrict__ st)
{
  int idx = blockIdx.x * 256 + threadIdx.x;
  int pos = idx >> 6, d = idx & 63;
  float inv = powf(10000.0f, -(float)d / 64.0f);
  float a = (float)pos * inv;
  ct[idx] = cosf(a);
  st[idx] = sinf(a);
}

// ----------------------- RoPE apply (in place, bf16) ------------------------
__global__ void rope_apply_k(u16* __restrict__ q, int ld,
                             const float* __restrict__ ct,
                             const float* __restrict__ st, float scale)
{
  int t = blockIdx.x;
  int hh = threadIdx.x >> 6;
  int d = threadIdx.x & 63;
  int pos = t & (SEQ - 1);
  size_t base = (size_t)t * ld + hh * HDIM + d;
  float x1 = bf2f(q[base]), x2 = bf2f(q[base + 64]);
  float c = ct[pos * 64 + d], s = st[pos * 64 + d];
  q[base]      = f2bf((x1 * c - x2 * s) * scale);
  q[base + 64] = f2bf((x2 * c + x1 * s) * scale);
}

// ------------------------------ RMSNorm ------------------------------------
__global__ __launch_bounds__(256)
void rmsnorm_k(const float* __restrict__ x, const float* __restrict__ g,
               u16* __restrict__ o)
{
  int row = blockIdx.x;
  int tid = threadIdx.x;
  const float* xr = x + (size_t)row * DM;
  float4 v0 = *(const float4*)(xr + tid * 8);
  float4 v1 = *(const float4*)(xr + tid * 8 + 4);
  float ss = v0.x*v0.x + v0.y*v0.y + v0.z*v0.z + v0.w*v0.w
           + v1.x*v1.x + v1.y*v1.y + v1.z*v1.z + v1.w*v1.w;
  #pragma unroll
  for (int d = 1; d < 64; d <<= 1) ss += __shfl_xor(ss, d);
  __shared__ float red[4];
  if ((tid & 63) == 0) red[tid >> 6] = ss;
  __syncthreads();
  float inv = rsqrtf((red[0] + red[1] + red[2] + red[3]) * (1.0f / DM) + 1e-6f);
  float4 g0 = *(const float4*)(g + tid * 8);
  float4 g1 = *(const float4*)(g + tid * 8 + 4);
  ushort4 o0, o1;
  o0.x = f2bf(v0.x * inv * g0.x); o0.y = f2bf(v0.y * inv * g0.y);
  o0.z = f2bf(v0.z * inv * g0.z); o0.w = f2bf(v0.w * inv * g0.w);
  o1.x = f2bf(v1.x * inv * g1.x); o1.y = f2bf(v1.y * inv * g1.y);
  o1.z = f2bf(v1.z * inv * g1.z); o1.w = f2bf(v1.w * inv * g1.w);
  *(ushort4*)(o + (size_t)row * DM + tid * 8) = o0;
  *(ushort4*)(o + (size_t)row * DM + tid * 8 + 4) = o1;
}

// ------------- deep-pipelined GEMM: 128 x 256, BK=64, 3-slot ring -----------
// (kept for wo; see r7/r8 notes)
template<int EPI>
__global__ __launch_bounds__(512, 1)
void gemmp(const u16* __restrict__ A, const u16* __restrict__ Bt,
           u16* __restrict__ Cb, float* __restrict__ Cf,
           const float* __restrict__ X, int M, int N, int K, int nbx)
{
  constexpr int ASZ = 128 * 64;
  constexpr int SLOT = ASZ + 256 * 64;
  __shared__ u16 lds[3 * SLOT];

  int bx, by;
  raster8(blockIdx.x, gridDim.x, nbx, bx, by);
  int m0 = by * 128;
  int n0 = bx * 256;

  int tid = threadIdx.x;
  int l = tid & 63, w = tid >> 6;
  int l16 = l & 15, lg = l >> 4;
  int wr = w >> 2, wc = w & 3;

  int aoff[4][2], boff[4][2];
  #pragma unroll
  for (int m = 0; m < 4; m++)
    #pragma unroll
    for (int kk = 0; kk < 2; kk++) {
      int row = wr * 64 + m * 16 + l16;
      aoff[m][kk] = ((row * 128 + kk * 64 + lg * 16) ^ ((row & 7) << 4)) >> 1;
    }
  #pragma unroll
  for (int n = 0; n < 4; n++)
    #pragma unroll
    for (int kk = 0; kk < 2; kk++) {
      int br = wc * 64 + n * 16 + l16;
      boff[n][kk] = ASZ + (((br * 128 + kk * 64 + lg * 16) ^ ((br & 7) << 4)) >> 1);
    }

  int urow = tid >> 3;
  int cc = (tid & 7) ^ (urow & 7);
  const u16* pA[2];
  const u16* pB[4];
  pA[0] = A + (size_t)(m0 + urow) * K + cc * 8;
  pA[1] = A + (size_t)(m0 + 64 + urow) * K + cc * 8;
  #pragma unroll
  for (int u = 0; u < 4; u++)
    pB[u] = Bt + (size_t)(n0 + u * 64 + urow) * K + cc * 8;

  const int NT = K >> 6;

  auto stA = [&](int tt, int u) {
    gld16(pA[u] + (size_t)tt * 64, lds + (tt % 3) * SLOT + u * 4096 + tid * 8);
  };
  auto stB = [&](int tt, int u) {
    gld16(pB[u] + (size_t)tt * 64, lds + (tt % 3) * SLOT + ASZ + u * 4096 + tid * 8);
  };

  #pragma unroll
  for (int u = 0; u < 4; u++) stB(0, u);
  stA(0, 0); stA(0, 1);
  #pragma unroll
  for (int u = 0; u < 4; u++) stB(1, u);
  stA(1, 0); stA(1, 1);
  VM(6);
  bar();

  f32x4 acc[4][4];
  f32x4 zero = {0.f, 0.f, 0.f, 0.f};
  #pragma unroll
  for (int m = 0; m < 4; m++)
    #pragma unroll
    for (int n = 0; n < 4; n++) acc[m][n] = zero;

  for (int t = 0; t < NT; ++t) {
    u16* cur = lds + (t % 3) * SLOT;
    const bool st = (t + 2 < NT);

    if (st) { stB(t + 2, 0); stB(t + 2, 1); stB(t + 2, 2); }
    bf16x8 a[4][2], b[2][2], c2[2][2];
    #pragma unroll
    for (int m = 0; m < 4; m++) {
      a[m][0] = *(const bf16x8*)(cur + aoff[m][0]);
      a[m][1] = *(const bf16x8*)(cur + aoff[m][1]);
    }
    #pragma unroll
    for (int n = 0; n < 2; n++) {
      b[n][0] = *(const bf16x8*)(cur + boff[n][0]);
      b[n][1] = *(const bf16x8*)(cur + boff[n][1]);
    }
    SCHED0;
    #pragma unroll
    for (int n = 0; n < 2; n++) {
      c2[n][0] = *(const bf16x8*)(cur + boff[n + 2][0]);
      c2[n][1] = *(const bf16x8*)(cur + boff[n + 2][1]);
    }
    bar();
    LG(4);
    SCHED0;
    __builtin_amdgcn_s_setprio(1);
    #pragma unroll
    for (int m = 0; m < 4; m++)
      #pragma unroll
      for (int n = 0; n < 2; n++) {
        acc[m][n] = mfma16(a[m][0], b[n][0], acc[m][n]);
        acc[m][n] = mfma16(a[m][1], b[n][1], acc[m][n]);
      }
    __builtin_amdgcn_s_setprio(0);
    SCHED0;
    bar();

    if (st) { stB(t + 2, 3); stA(t + 2, 0); stA(t + 2, 1); }
    if (st) { VM(6); }
    else if (t + 1 < NT) { VM(0); }
    bar();
    LG(0);
    SCHED0;
    __builtin_amdgcn_s_setprio(1);
    #pragma unroll
    for (int m = 0; m < 4; m++)
      #pragma unroll
      for (int n = 0; n < 2; n++) {
        acc[m][n + 2] = mfma16(a[m][0], c2[n][0], acc[m][n + 2]);
        acc[m][n + 2] = mfma16(a[m][1], c2[n][1], acc[m][n + 2]);
      }
    __builtin_amdgcn_s_setprio(0);
    SCHED0;
    bar();
  }

  #pragma unroll
  for (int m = 0; m < 4; m++) {
    int row = m0 + wr * 64 + m * 16 + lg * 4;
    #pragma unroll
    for (int n = 0; n < 4; n++) {
      int col = n0 + wc * 64 + n * 16 + l16;
      #pragma unroll
      for (int r = 0; r < 4; r++) {
        size_t idx = (size_t)(row + r) * N + col;
        float v = acc[m][n][r];
        if (EPI == 0) {
          Cb[idx] = f2bf(v);
        } else if (EPI == 1) {
          Cf[idx] = X[idx] + v;
        } else {
          Cf[idx] += v;
        }
      }
    }
  }
}

// ---- 256x256 GEMM, BK=64, 2-slot, 4-phase, read-ahead-one-phase ------------
// 8 waves 2Mx4N, per-wave out 128x64. Read groups: G0=a0+b0(8) G1=a1(4)
// G2=a2+b1(8) G3=a3(4); each issued one phase before use; counted LG waits
// only the group issued a phase earlier -> LDS reads overlap MFMA.
// LG(0)@ph2 + barrier => all cur-slot reads drained cross-wave before ph3's
// same-slot staging (race-free). VM(6)@ph3 BEFORE barrier => tile t+1 loads
// (A1 from ph0, A0/B from ph3(t-1)) retired, then bar, then G0(t+1) reads.
// GU=1: B rows = gate(128)|up(128), silu epilogue. EPI: 0 bf16 store,
// 4 atomicAdd fp32 (split-K). SPLITK: blockIdx splits K into 2 halves.
template<int EPI, int GU, int SPLITK>
__global__ __launch_bounds__(512, 1)
void gemm256(const u16* __restrict__ A, const u16* __restrict__ B1,
             const u16* __restrict__ B2, u16* __restrict__ Cb,
             float* __restrict__ Cf, int Kst, int NT, int N, int nbx)
{
  constexpr int SLOT = 32768;          // u16: A 16384 + B 16384
  __shared__ u16 lds[2 * SLOT];        // 128 KiB

  int wg = blockIdx.x;
  int nwg = gridDim.x;
  int kh = 0;
  if (SPLITK) { int half = nwg >> 1; kh = (wg >= half); wg -= kh * half; nwg = half; }
  int bx, by;
  raster8(wg, nwg, nbx, bx, by);
  int m0 = by * 256;
  int n0 = bx * (GU ? 128 : 256);
  size_t k0 = (size_t)kh * NT * 64;

  int tid = threadIdx.x;
  int l = tid & 63, w = tid >> 6;
  int l16 = l & 15, lg = l >> 4;
  int wr = w >> 2, wc = w & 3;

  int sw = (l16 & 7) << 4;
  int aoffk[2], boffk[2];
  #pragma unroll
  for (int kk = 0; kk < 2; kk++) {
    aoffk[kk] = ((wr * 128 + l16) * 128 + ((kk * 64 + lg * 16) ^ sw)) >> 1;
    int bbase = GU ? (wc * 32 + l16) : (wc * 64 + l16);
    boffk[kk] = 16384 + (((bbase * 128) + ((kk * 64 + lg * 16) ^ sw)) >> 1);
  }

  int rh = tid >> 3;
  int cc = (tid & 7) ^ (rh & 7);
  const u16* pA0[2]; const u16* pA1[2]; const u16* pB[4];
  #pragma unroll
  for (int ll = 0; ll < 2; ll++) {
    pA0[ll] = A + (size_t)(m0 + ll * 64 + rh) * Kst + k0 + cc * 8;
    pA1[ll] = A + (size_t)(m0 + 128 + ll * 64 + rh) * Kst + k0 + cc * 8;
  }
  #pragma unroll
  for (int u = 0; u < 4; u++) {
    if (GU) pB[u] = (u < 2 ? B1 + (size_t)(n0 + u * 64 + rh) * Kst
                           : B2 + (size_t)(n0 + (u - 2) * 64 + rh) * Kst) + k0 + cc * 8;
    else    pB[u] = B1 + (size_t)(n0 + u * 64 + rh) * Kst + k0 + cc * 8;
  }

  auto stA0 = [&](int tt) {
    u16* d = lds + (tt & 1) * SLOT;
    gld16(pA0[0] + (size_t)tt * 64, d + tid * 8);
    gld16(pA0[1] + (size_t)tt * 64, d + 4096 + tid * 8);
  };
  auto stA1 = [&](int tt) {
    u16* d = lds + (tt & 1) * SLOT + 8192;
    gld16(pA1[0] + (size_t)tt * 64, d + tid * 8);
    gld16(pA1[1] + (size_t)tt * 64, d + 4096 + tid * 8);
  };
  auto stB4 = [&](int tt) {
    u16* d = lds + (tt & 1) * SLOT + 16384;
    #pragma unroll
    for (int u = 0; u < 4; u++)
      gld16(pB[u] + (size_t)tt * 64, d + u * 4096 + tid * 8);
  };

  // prologue: tile0 full (8 loads), tile1 {A0,B} (6). A1(1) staged at ph0(0).
  stA0(0); stA1(0); stB4(0);
  stA0(1); stB4(1);
  VM(6);               // tile0 landed, newest 6 = {A0,B}(1) outstanding
  bar();

  f32x4 acc[8][4];
  f32x4 zero = {0.f, 0.f, 0.f, 0.f};
  #pragma unroll
  for (int m = 0; m < 8; m++)
    #pragma unroll
    for (int n = 0; n < 4; n++) acc[m][n] = zero;

  bf16x8 aA[4], aB[4], aC[4], aD[4], bb0[4], bb1[4];
  // G0(0): a0 + b0 from slot 0
  {
    u16* s0 = lds;
    #pragma unroll
    for (int m = 0; m < 4; m++) aA[m] = *(const bf16x8*)(s0 + aoffk[0] + m * 1024);
    #pragma unroll
    for (int n = 0; n < 4; n++)
      bb0[n] = *(const bf16x8*)(s0 + boffk[0] + (GU ? ((n & 1) * 1024 + (n >> 1) * 8192)
                                                    : (n * 1024)));
  }

  for (int t = 0; t < NT; ++t) {
    u16* cur = lds + (t & 1) * SLOT;
    u16* nxt = lds + ((t + 1) & 1) * SLOT;

    // ---- ph0: issue G1 (a1); stage A1(t+1); MFMA Q0 = mh0 x kk0 ----
    #pragma unroll
    for (int m = 0; m < 4; m++) aB[m] = *(const bf16x8*)(cur + aoffk[0] + 4096 + m * 1024);
    if (t + 1 < NT) stA1(t + 1);
    bar();
    LG(4);               // waits G0 (issued one phase earlier)
    SCHED0;
    __builtin_amdgcn_s_setprio(1);
    #pragma unroll
    for (int m = 0; m < 4; m++)
      #pragma unroll
      for (int n = 0; n < 4; n++)
        acc[m][n] = mfma16(aA[m], bb0[n], acc[m][n]);
    __builtin_amdgcn_s_setprio(0);
    SCHED0;
    bar();

    // ---- ph1: issue G2 (a2 + b1); MFMA Q1 = mh1 x kk0 ----
    #pragma unroll
    for (int m = 0; m < 4; m++) aC[m] = *(const bf16x8*)(cur + aoffk[1] + m * 1024);
    #pragma unroll
    for (int n = 0; n < 4; n++)
      bb1[n] = *(const bf16x8*)(cur + boffk[1] + (GU ? ((n & 1) * 1024 + (n >> 1) * 8192)
                                                     : (n * 1024)));
    bar();
    LG(8);               // waits G1
    SCHED0;
    __builtin_amdgcn_s_setprio(1);
    #pragma unroll
    for (int m = 0; m < 4; m++)
      #pragma unroll
      for (int n = 0; n < 4; n++)
        acc[4 + m][n] = mfma16(aB[m], bb0[n], acc[4 + m][n]);
    __builtin_amdgcn_s_setprio(0);
    SCHED0;
    bar();

    // ---- ph2: issue G3 (a3); MFMA Q2 = mh0 x kk1; FULL lgkm drain ----
    #pragma unroll
    for (int m = 0; m < 4; m++) aD[m] = *(const bf16x8*)(cur + aoffk[1] + 4096 + m * 1024);
    bar();
    LG(0);               // drain G2+G3 -> cur reads all retired (race guard)
    SCHED0;
    __builtin_amdgcn_s_setprio(1);
    #pragma unroll
    for (int m = 0; m < 4; m++)
      #pragma unroll
      for (int n = 0; n < 4; n++)
        acc[m][n] = mfma16(aC[m], bb1[n], acc[m][n]);
    __builtin_amdgcn_s_setprio(0);
    SCHED0;
    bar();

    // ---- ph3: stage {A0,B}(t+2) into cur; VM; bar; issue G0(t+1); Q3 ----
    if (t + 2 < NT) {
      stA0(t + 2); stB4(t + 2);
      VM(6);             // drains tile t+1 loads, leaves the 6 just issued
    } else if (t + 1 < NT) {
      VM(0);             // tail: drain remaining tile t+1 loads
    }
    bar();
    if (t + 1 < NT) {
      #pragma unroll
      for (int m = 0; m < 4; m++) aA[m] = *(const bf16x8*)(nxt + aoffk[0] + m * 1024);
      #pragma unroll
      for (int n = 0; n < 4; n++)
        bb0[n] = *(const bf16x8*)(nxt + boffk[0] + (GU ? ((n & 1) * 1024 + (n >> 1) * 8192)
                                                       : (n * 1024)));
    }
    LG(8);               // G3 already drained at ph2; don't wait G0(t+1)
    SCHED0;
    __builtin_amdgcn_s_setprio(1);
    #pragma unroll
    for (int m = 0; m < 4; m++)
      #pragma unroll
      for (int n = 0; n < 4; n++)
        acc[4 + m][n] = mfma16(aD[m], bb1[n], acc[4 + m][n]);
    __builtin_amdgcn_s_setprio(0);
    SCHED0;
    bar();
  }

  if (GU) {
    #pragma unroll
    for (int m = 0; m < 8; m++) {
      int row = m0 + wr * 128 + m * 16 + lg * 4;
      #pragma unroll
      for (int n = 0; n < 2; n++) {
        int col = n0 + wc * 32 + n * 16 + l16;
        #pragma unroll
        for (int r = 0; r < 4; r++) {
          float gt = acc[m][n][r];
          float up = acc[m][n + 2][r];
          float sg = gt / (1.0f + __expf(-gt));
          Cb[(size_t)(row + r) * N + col] = f2bf(sg * up);
        }
      }
    }
  } else {
    #pragma unroll
    for (int m = 0; m < 8; m++) {
      int row = m0 + wr * 128 + m * 16 + lg * 4;
      #pragma unroll
      for (int n = 0; n < 4; n++) {
        int col = n0 + wc * 64 + n * 16 + l16;
        #pragma unroll
        for (int r = 0; r < 4; r++) {
          size_t idx = (size_t)(row + r) * N + col;
          if (EPI == 0) Cb[idx] = f2bf(acc[m][n][r]);
          else          atomicAdd(Cf + idx, acc[m][n][r]);
        }
      }
    }
  }
}

// ------------------- flash attention, sliding window + sink -----------------
__global__ __launch_bounds__(256)
void attn_k(const u16* __restrict__ qb, int ldq,
            const u16* __restrict__ kb, int ldk,
            const u16* __restrict__ vbt, u16* __restrict__ ao)
{
  int q0 = blockIdx.x * 128;
  int h = blockIdx.y;
  int b = blockIdx.z;
  int hk = h >> 2;
  int tid = threadIdx.x;
  int w = tid >> 6, l = tid & 63;
  int l16 = l & 15, lg = l >> 4;

  __shared__ u16 Ks[32 * 128];
  __shared__ u16 Vt[128 * 32];
  __shared__ u16 Ps[4][32 * 40];
  u16* Pw = Ps[w];

  bf16x8 qf[2][4];
  #pragma unroll
  for (int m = 0; m < 2; m++)
    #pragma unroll
    for (int kd = 0; kd < 4; kd++) {
      int row = q0 + w * 32 + m * 16 + l16;
      qf[m][kd] = *(const bf16x8*)(qb + (size_t)(b * SEQ + row) * ldq
                                   + h * HDIM + kd * 32 + lg * 8);
    }

  f32x4 oacc[2][8];
  float mrun[2][4], lrun[2][4];
  f32x4 zero = {0.f, 0.f, 0.f, 0.f};
  #pragma unroll
  for (int m = 0; m < 2; m++) {
    #pragma unroll
    for (int nd = 0; nd < 8; nd++) oacc[m][nd] = zero;
    #pragma unroll
    for (int r = 0; r < 4; r++) { mrun[m][r] = -1e9f; lrun[m][r] = 0.f; }
  }

  int kr0 = tid >> 4,        kc0 = (tid & 15) ^ (kr0 & 7);
  int kr1 = (tid + 256) >> 4, kc1 = (tid & 15) ^ (kr1 & 7);
  int vd0, vk0, vd1, vk1;
  swz_rc(tid, vd0, vk0);
  swz_rc(tid + 256, vd1, vk1);
  const u16* kbase = kb + (size_t)(b * SEQ) * ldk + hk * HDIM;
  const u16* vbase = vbt + (size_t)(b * NKV + hk) * HDIM * SEQ;

  int koff[2][4];
  #pragma unroll
  for (int n = 0; n < 2; n++)
    #pragma unroll
    for (int kd = 0; kd < 4; kd++) {
      int key = n * 16 + l16;
      koff[n][kd] = ((key * 128) + kd * 32 + lg * 8) ^ ((key & 7) * 8);
    }
  int voff[8];
  #pragma unroll
  for (int nd = 0; nd < 8; nd++) {
    int d = nd * 16 + l16;
    voff[nd] = (d * 32 + lg * 8) ^ ((d & 7) * 8);
  }

  int lo = (q0 >= WIN) ? ((q0 - (WIN - 1)) >> 5) : 0;
  int hi = (q0 + 127) >> 5;

  for (int it = (lo > 0 ? lo - 1 : 0); it <= hi; ++it) {
    int kt = (it < lo) ? 0 : it;
    gld16(kbase + (size_t)(kt * 32 + kr0) * ldk + kc0 * 8, Ks + tid * 8);
    gld16(kbase + (size_t)(kt * 32 + kr1) * ldk + kc1 * 8, Ks + (tid + 256) * 8);
    gld16(vbase + (size_t)vd0 * SEQ + kt * 32 + vk0 * 8, Vt + tid * 8);
    gld16(vbase + (size_t)vd1 * SEQ + kt * 32 + vk1 * 8, Vt + (tid + 256) * 8);
    __syncthreads();

    f32x4 sacc[2][2];
    sacc[0][0] = zero; sacc[0][1] = zero; sacc[1][0] = zero; sacc[1][1] = zero;
    #pragma unroll
    for (int kd = 0; kd < 4; kd++) {
      bf16x8 kf0 = *(const bf16x8*)(Ks + koff[0][kd]);
      bf16x8 kf1 = *(const bf16x8*)(Ks + koff[1][kd]);
      #pragma unroll
      for (int m = 0; m < 2; m++) {
        sacc[m][0] = mfma16(qf[m][kd], kf0, sacc[m][0]);
        sacc[m][1] = mfma16(qf[m][kd], kf1, sacc[m][1]);
      }
    }

    #pragma unroll
    for (int m = 0; m < 2; m++) {
      float sc[4];
      #pragma unroll
      for (int r = 0; r < 4; r++) {
        int i = q0 + w * 32 + m * 16 + lg * 4 + r;
        int j0 = kt * 32 + l16;
        int j1 = j0 + 16;
        float s0 = sacc[m][0][r];
        float s1 = sacc[m][1][r];
        bool ok0 = (j0 <= i) && ((i - j0 < WIN) || (j0 < SINKN));
        bool ok1 = (j1 <= i) && ((i - j1 < WIN) || (j1 < SINKN));
        s0 = ok0 ? s0 : -1e9f;
        s1 = ok1 ? s1 : -1e9f;
        float mx = fmaxf(s0, s1);
        mx = fmaxf(mx, __shfl_xor(mx, 1));
        mx = fmaxf(mx, __shfl_xor(mx, 2));
        mx = fmaxf(mx, __shfl_xor(mx, 4));
        mx = fmaxf(mx, __shfl_xor(mx, 8));
        float mold = mrun[m][r];
        float mnew = fmaxf(mold, mx);
        float scl = __expf(mold - mnew);
        mrun[m][r] = mnew;
        float p0 = __expf(s0 - mnew);
        float p1 = __expf(s1 - mnew);
        int prow = m * 16 + lg * 4 + r;
        Pw[prow * 40 + l16] = f2bf(p0);
        Pw[prow * 40 + 16 + l16] = f2bf(p1);
        float ps = p0 + p1;
        ps += __shfl_xor(ps, 1);
        ps += __shfl_xor(ps, 2);
        ps += __shfl_xor(ps, 4);
        ps += __shfl_xor(ps, 8);
        lrun[m][r] = lrun[m][r] * scl + ps;
        sc[r] = scl;
      }
      #pragma unroll
      for (int nd = 0; nd < 8; nd++) {
        oacc[m][nd][0] *= sc[0];
        oacc[m][nd][1] *= sc[1];
        oacc[m][nd][2] *= sc[2];
        oacc[m][nd][3] *= sc[3];
      }
    }

    bf16x8 pa0 = *(const bf16x8*)(Pw + l16 * 40 + lg * 8);
    bf16x8 pa1 = *(const bf16x8*)(Pw + (16 + l16) * 40 + lg * 8);
    #pragma unroll
    for (int nd = 0; nd < 8; nd++) {
      bf16x8 vf = *(const bf16x8*)(Vt + voff[nd]);
      oacc[0][nd] = mfma16(pa0, vf, oacc[0][nd]);
      oacc[1][nd] = mfma16(pa1, vf, oacc[1][nd]);
    }
    __syncthreads();
  }

  #pragma unroll
  for (int m = 0; m < 2; m++)
    #pragma unroll
    for (int r = 0; r < 4; r++) {
      float invl = 1.0f / lrun[m][r];
      int row = q0 + w * 32 + m * 16 + lg * 4 + r;
      #pragma unroll
      for (int nd = 0; nd < 8; nd++) {
        int col = nd * 16 + l16;
        ao[(size_t)(b * SEQ + row) * (NH * HDIM) + h * HDIM + col] =
            f2bf(oacc[m][nd][r] * invl);
      }
    }
}

// ------------------------------- launcher -----------------------------------
extern "C" void kernel_launch(void* const* d_in, const int* in_sizes, int n_in,
                              void* d_out, int out_size, void* d_ws, size_t ws_size,
                              hipStream_t stream)
{
  (void)in_sizes; (void)n_in; (void)out_size;
  const float* x  = (const float*)d_in[0];
  const float* g1 = (const float*)d_in[1];
  const float* g2 = (const float*)d_in[2];
  const float* wq = (const float*)d_in[3];
  const float* wk = (const float*)d_in[4];
  const float* wv = (const float*)d_in[5];
  const float* wo = (const float*)d_in[6];
  const float* wg = (const float*)d_in[7];
  const float* wu = (const float*)d_in[8];
  const float* wd = (const float*)d_in[9];
  float* out = (float*)d_out;

  char* ws = (char*)d_ws;
  size_t off = 0;
  auto alloc = [&](size_t bytes) {
    char* p = ws + off;
    off += (bytes + 255) & ~(size_t)255;
    return p;
  };
  const int NQKV = 3072;   // q 0..2047 | k 2048..2559 | v 2560..3071
  u16* wqkv_t = (u16*)alloc((size_t)NQKV * DM * 2);
  u16* wo_t   = (u16*)alloc((size_t)DM * DM * 2);
  u16* wg_t   = (u16*)alloc((size_t)HID * DM * 2);
  u16* wu_t   = (u16*)alloc((size_t)HID * DM * 2);
  u16* wd_t   = (u16*)alloc((size_t)DM * HID * 2);
  u16* hb     = (u16*)alloc((size_t)TOK * DM * 2);
  // gu (67.1 MB) aliases qkvb+vbt+aob (dead by the time gateup runs) + tail
  char* span0 = ws + off;
  u16* qkvb   = (u16*)alloc((size_t)TOK * NQKV * 2);
  u16* vbt    = (u16*)alloc((size_t)TOK * NKV * HDIM * 2);
  u16* aob    = (u16*)alloc((size_t)TOK * NH * HDIM * 2);
  size_t span_used = (size_t)(ws + off - span0);
  size_t gu_need = (size_t)TOK * HID * 2;
  if (gu_need > span_used) alloc(gu_need - span_used);
  u16* gu = (u16*)span0;
  float* ct  = (float*)alloc((size_t)SEQ * 64 * 4);
  float* st  = (float*)alloc((size_t)SEQ * 64 * 4);
  if (off > ws_size) return;

  dim3 blk(256);
  dim3 blk512(512);

  // weight transposes (fp32 -> bf16, [K][N] -> [N][K])
  wtrans<<<dim3(DM / 32, DM / 32), blk, 0, stream>>>(wq, wqkv_t, DM, DM);
  wtrans<<<dim3((NKV * HDIM) / 32, DM / 32), blk, 0, stream>>>(wk, wqkv_t + (size_t)DM * DM, DM, NKV * HDIM);
  wtrans<<<dim3((NKV * HDIM) / 32, DM / 32), blk, 0, stream>>>(wv, wqkv_t + (size_t)(DM + NKV * HDIM) * DM, DM, NKV * HDIM);
  wtrans<<<dim3(DM / 32, DM / 32), blk, 0, stream>>>(wo, wo_t, DM, DM);
  wtrans<<<dim3(HID / 32, DM / 32), blk, 0, stream>>>(wg, wg_t, DM, HID);
  wtrans<<<dim3(HID / 32, DM / 32), blk, 0, stream>>>(wu, wu_t, DM, HID);
  wtrans<<<dim3(DM / 32, HID / 32), blk, 0, stream>>>(wd, wd_t, HID, DM);

  rope_table_k<<<SEQ * 64 / 256, blk, 0, stream>>>(ct, st);
  rmsnorm_k<<<TOK, blk, 0, stream>>>(x, g1, hb);

  // fused QKV projection: [4096][3072] via 256x256 kernel (192 blocks)
  gemm256<0, 0, 0><<<dim3((NQKV / 256) * (TOK / 256)), blk512, 0, stream>>>(
      hb, wqkv_t, nullptr, qkvb, nullptr, DM, DM / 64, NQKV, NQKV / 256);

  rope_apply_k<<<TOK, dim3(NH * 64), 0, stream>>>(qkvb, NQKV, ct, st, 0.08838834764831845f);
  rope_apply_k<<<TOK, dim3(NKV * 64), 0, stream>>>(qkvb + DM, NQKV, ct, st, 1.0f);
  vtrans<<<dim3((NKV * HDIM) / 32, TOK / 32), blk, 0, stream>>>(qkvb + DM + NKV * HDIM, NQKV, vbt);

  attn_k<<<dim3(SEQ / 128, NH, 2), blk, 0, stream>>>(qkvb, NQKV, qkvb + DM, NQKV, vbt, aob);

  gemmp<1><<<dim3((DM / 256) * (TOK / 128)), blk512, 0, stream>>>(
      aob, wo_t, nullptr, out, x, TOK, DM, DM, DM / 256);
  rmsnorm_k<<<TOK, blk, 0, stream>>>(out, g2, hb);

  // fused gate+up with silu epilogue (1024 blocks)
  gemm256<0, 1, 0><<<dim3((HID / 128) * (TOK / 256)), blk512, 0, stream>>>(
      hb, wg_t, wu_t, gu, nullptr, DM, DM / 64, HID, HID / 128);

  // down-proj: split-K=2, atomicAdd into out (256 blocks)
  gemm256<4, 0, 1><<<dim3(2 * (DM / 256) * (TOK / 256)), blk512, 0, stream>>>(
      gu, wd_t, nullptr, nullptr, out, HID, HID / 128, DM, DM / 256);
}

// Round 10
// 770.874 us; speedup vs baseline: 1.5023x; 1.0142x over previous
//
#include <hip/hip_runtime.h>
#include <hip/hip_bf16.h>
#include <stdint.h>

#define TOK 4096
#define SEQ 2048
#define DM 2048
#define NH 16
#define NKV 4
#define HDIM 128
#define HID 8192
#define WIN 1024
#define SINKN 4

typedef float f32x4 __attribute__((ext_vector_type(4)));
typedef __bf16 bf16x8 __attribute__((ext_vector_type(8)));
typedef unsigned short u16;
typedef unsigned int u32;

#define VM(n) asm volatile("s_waitcnt vmcnt(" #n ")" ::: "memory")
#define LG(n) asm volatile("s_waitcnt lgkmcnt(" #n ")" ::: "memory")
#define SCHED0 __builtin_amdgcn_sched_barrier(0)

__device__ __forceinline__ u16 f2bf(float f) {
  union { float f; u32 u; } v; v.f = f;
  return (u16)((v.u + 0x7fffu + ((v.u >> 16) & 1u)) >> 16);
}
__device__ __forceinline__ float bf2f(u16 h) {
  union { u32 u; float f; } v; v.u = ((u32)h) << 16;
  return v.f;
}
__device__ __forceinline__ f32x4 mfma16(bf16x8 a, bf16x8 b, f32x4 c) {
  return __builtin_amdgcn_mfma_f32_16x16x32_bf16(a, b, c, 0, 0, 0);
}
__device__ __forceinline__ void gld16(const u16* g, u16* l) {
  __builtin_amdgcn_global_load_lds(
      (const __attribute__((address_space(1))) u32*)g,
      (__attribute__((address_space(3))) u32*)l, 16, 0, 0);
}
__device__ __forceinline__ void bar() {
  asm volatile("s_barrier" ::: "memory");
}
// Inverse swizzle for 64B-row tiles ([rows][32] u16) used by attn staging.
__device__ __forceinline__ void swz_rc(int c, int& row, int& k8) {
  row = 2 * (c >> 3) + (((c >> 2) & 1) ^ ((c >> 4) & 1));
  k8 = (c & 3) ^ (row & 3);
}
// XCD-chunked + grouped raster (G=8).
__device__ __forceinline__ void raster8(int wg, int nwg, int nbx, int& bx, int& by) {
  int cpx = nwg >> 3;
  int s = (wg & 7) * cpx + (wg >> 3);
  by = 8 * (s / (8 * nbx)) + (s & 7);
  bx = (s >> 3) % nbx;
}

// ---------------- weight transpose fp32[K][N] -> bf16[N][K] ----------------
__global__ __launch_bounds__(256)
void wtrans(const float* __restrict__ in, u16* __restrict__ out, int K, int N)
{
  __shared__ float t[32][33];
  int tx = threadIdx.x & 31, ty = threadIdx.x >> 5;
  int bx = blockIdx.x, by = blockIdx.y;
  #pragma unroll
  for (int i = 0; i < 4; i++) {
    int r = ty + i * 8;
    t[r][tx] = in[(size_t)(by * 32 + r) * N + bx * 32 + tx];
  }
  __syncthreads();
  #pragma unroll
  for (int i = 0; i < 4; i++) {
    int r = ty + i * 8;
    out[(size_t)(bx * 32 + r) * K + by * 32 + tx] = f2bf(t[tx][r]);
  }
}

// ---- V transpose: bf16 [4096][ld] cols -> [(b*4+hk)*128+d][2048] -----------
__global__ __launch_bounds__(256)
void vtrans(const u16* __restrict__ in, int ld, u16* __restrict__ out)
{
  __shared__ u16 t[32][33];
  int tx = threadIdx.x & 31, ty = threadIdx.x >> 5;
  int bx = blockIdx.x;
  int by = blockIdx.y;
  #pragma unroll
  for (int i = 0; i < 4; i++) {
    int r = ty + i * 8;
    t[r][tx] = in[(size_t)(by * 32 + r) * ld + bx * 32 + tx];
  }
  __syncthreads();
  int b = (by * 32) >> 11;
  int s0 = (by * 32) & (SEQ - 1);
  #pragma unroll
  for (int i = 0; i < 4; i++) {
    int c = bx * 32 + ty + i * 8;
    out[(size_t)(b * (NKV * HDIM) + c) * SEQ + s0 + tx] = t[tx][ty + i * 8];
  }
}

// ---------------------------- RoPE table -----------------------------------
__global__ __launch_bounds__(256)
void rope_table_k(float* __restrict__ ct, float* __restrict__ st)
{
  int idx = blockIdx.x * 256 + threadIdx.x;
  int pos = idx >> 6, d = idx & 63;
  float inv = powf(10000.0f, -(float)d / 64.0f);
  float a = (float)pos * inv;
  ct[idx] = cosf(a);
  st[idx] = sinf(a);
}

// ----------------------- RoPE apply (in place, bf16) ------------------------
__global__ void rope_apply_k(u16* __restrict__ q, int ld,
                             const float* __restrict__ ct,
                             const float* __restrict__ st, float scale)
{
  int t = blockIdx.x;
  int hh = threadIdx.x >> 6;
  int d = threadIdx.x & 63;
  int pos = t & (SEQ - 1);
  size_t base = (size_t)t * ld + hh * HDIM + d;
  float x1 = bf2f(q[base]), x2 = bf2f(q[base + 64]);
  float c = ct[pos * 64 + d], s = st[pos * 64 + d];
  q[base]      = f2bf((x1 * c - x2 * s) * scale);
  q[base + 64] = f2bf((x2 * c + x1 * s) * scale);
}

// ------------------------------ RMSNorm ------------------------------------
__global__ __launch_bounds__(256)
void rmsnorm_k(const float* __restrict__ x, const float* __restrict__ g,
               u16* __restrict__ o)
{
  int row = blockIdx.x;
  int tid = threadIdx.x;
  const float* xr = x + (size_t)row * DM;
  float4 v0 = *(const float4*)(xr + tid * 8);
  float4 v1 = *(const float4*)(xr + tid * 8 + 4);
  float ss = v0.x*v0.x + v0.y*v0.y + v0.z*v0.z + v0.w*v0.w
           + v1.x*v1.x + v1.y*v1.y + v1.z*v1.z + v1.w*v1.w;
  #pragma unroll
  for (int d = 1; d < 64; d <<= 1) ss += __shfl_xor(ss, d);
  __shared__ float red[4];
  if ((tid & 63) == 0) red[tid >> 6] = ss;
  __syncthreads();
  float inv = rsqrtf((red[0] + red[1] + red[2] + red[3]) * (1.0f / DM) + 1e-6f);
  float4 g0 = *(const float4*)(g + tid * 8);
  float4 g1 = *(const float4*)(g + tid * 8 + 4);
  ushort4 o0, o1;
  o0.x = f2bf(v0.x * inv * g0.x); o0.y = f2bf(v0.y * inv * g0.y);
  o0.z = f2bf(v0.z * inv * g0.z); o0.w = f2bf(v0.w * inv * g0.w);
  o1.x = f2bf(v1.x * inv * g1.x); o1.y = f2bf(v1.y * inv * g1.y);
  o1.z = f2bf(v1.z * inv * g1.z); o1.w = f2bf(v1.w * inv * g1.w);
  *(ushort4*)(o + (size_t)row * DM + tid * 8) = o0;
  *(ushort4*)(o + (size_t)row * DM + tid * 8 + 4) = o1;
}

// ------------- deep-pipelined GEMM: 128 x 256, BK=64, 3-slot ring -----------
// (kept for wo; see r7/r8 notes)
template<int EPI>
__global__ __launch_bounds__(512, 1)
void gemmp(const u16* __restrict__ A, const u16* __restrict__ Bt,
           u16* __restrict__ Cb, float* __restrict__ Cf,
           const float* __restrict__ X, int M, int N, int K, int nbx)
{
  constexpr int ASZ = 128 * 64;
  constexpr int SLOT = ASZ + 256 * 64;
  __shared__ u16 lds[3 * SLOT];

  int bx, by;
  raster8(blockIdx.x, gridDim.x, nbx, bx, by);
  int m0 = by * 128;
  int n0 = bx * 256;

  int tid = threadIdx.x;
  int l = tid & 63, w = tid >> 6;
  int l16 = l & 15, lg = l >> 4;
  int wr = w >> 2, wc = w & 3;

  int aoff[4][2], boff[4][2];
  #pragma unroll
  for (int m = 0; m < 4; m++)
    #pragma unroll
    for (int kk = 0; kk < 2; kk++) {
      int row = wr * 64 + m * 16 + l16;
      aoff[m][kk] = ((row * 128 + kk * 64 + lg * 16) ^ ((row & 7) << 4)) >> 1;
    }
  #pragma unroll
  for (int n = 0; n < 4; n++)
    #pragma unroll
    for (int kk = 0; kk < 2; kk++) {
      int br = wc * 64 + n * 16 + l16;
      boff[n][kk] = ASZ + (((br * 128 + kk * 64 + lg * 16) ^ ((br & 7) << 4)) >> 1);
    }

  int urow = tid >> 3;
  int cc = (tid & 7) ^ (urow & 7);
  const u16* pA[2];
  const u16* pB[4];
  pA[0] = A + (size_t)(m0 + urow) * K + cc * 8;
  pA[1] = A + (size_t)(m0 + 64 + urow) * K + cc * 8;
  #pragma unroll
  for (int u = 0; u < 4; u++)
    pB[u] = Bt + (size_t)(n0 + u * 64 + urow) * K + cc * 8;

  const int NT = K >> 6;

  auto stA = [&](int tt, int u) {
    gld16(pA[u] + (size_t)tt * 64, lds + (tt % 3) * SLOT + u * 4096 + tid * 8);
  };
  auto stB = [&](int tt, int u) {
    gld16(pB[u] + (size_t)tt * 64, lds + (tt % 3) * SLOT + ASZ + u * 4096 + tid * 8);
  };

  #pragma unroll
  for (int u = 0; u < 4; u++) stB(0, u);
  stA(0, 0); stA(0, 1);
  #pragma unroll
  for (int u = 0; u < 4; u++) stB(1, u);
  stA(1, 0); stA(1, 1);
  VM(6);
  bar();

  f32x4 acc[4][4];
  f32x4 zero = {0.f, 0.f, 0.f, 0.f};
  #pragma unroll
  for (int m = 0; m < 4; m++)
    #pragma unroll
    for (int n = 0; n < 4; n++) acc[m][n] = zero;

  for (int t = 0; t < NT; ++t) {
    u16* cur = lds + (t % 3) * SLOT;
    const bool st = (t + 2 < NT);

    if (st) { stB(t + 2, 0); stB(t + 2, 1); stB(t + 2, 2); }
    bf16x8 a[4][2], b[2][2], c2[2][2];
    #pragma unroll
    for (int m = 0; m < 4; m++) {
      a[m][0] = *(const bf16x8*)(cur + aoff[m][0]);
      a[m][1] = *(const bf16x8*)(cur + aoff[m][1]);
    }
    #pragma unroll
    for (int n = 0; n < 2; n++) {
      b[n][0] = *(const bf16x8*)(cur + boff[n][0]);
      b[n][1] = *(const bf16x8*)(cur + boff[n][1]);
    }
    SCHED0;
    #pragma unroll
    for (int n = 0; n < 2; n++) {
      c2[n][0] = *(const bf16x8*)(cur + boff[n + 2][0]);
      c2[n][1] = *(const bf16x8*)(cur + boff[n + 2][1]);
    }
    bar();
    LG(4);
    SCHED0;
    __builtin_amdgcn_s_setprio(1);
    #pragma unroll
    for (int m = 0; m < 4; m++)
      #pragma unroll
      for (int n = 0; n < 2; n++) {
        acc[m][n] = mfma16(a[m][0], b[n][0], acc[m][n]);
        acc[m][n] = mfma16(a[m][1], b[n][1], acc[m][n]);
      }
    __builtin_amdgcn_s_setprio(0);
    SCHED0;
    bar();

    if (st) { stB(t + 2, 3); stA(t + 2, 0); stA(t + 2, 1); }
    if (st) { VM(6); }
    else if (t + 1 < NT) { VM(0); }
    bar();
    LG(0);
    SCHED0;
    __builtin_amdgcn_s_setprio(1);
    #pragma unroll
    for (int m = 0; m < 4; m++)
      #pragma unroll
      for (int n = 0; n < 2; n++) {
        acc[m][n + 2] = mfma16(a[m][0], c2[n][0], acc[m][n + 2]);
        acc[m][n + 2] = mfma16(a[m][1], c2[n][1], acc[m][n + 2]);
      }
    __builtin_amdgcn_s_setprio(0);
    SCHED0;
    bar();
  }

  #pragma unroll
  for (int m = 0; m < 4; m++) {
    int row = m0 + wr * 64 + m * 16 + lg * 4;
    #pragma unroll
    for (int n = 0; n < 4; n++) {
      int col = n0 + wc * 64 + n * 16 + l16;
      #pragma unroll
      for (int r = 0; r < 4; r++) {
        size_t idx = (size_t)(row + r) * N + col;
        float v = acc[m][n][r];
        if (EPI == 0) {
          Cb[idx] = f2bf(v);
        } else if (EPI == 1) {
          Cf[idx] = X[idx] + v;
        } else {
          Cf[idx] += v;
        }
      }
    }
  }
}

// ---- 256x256 GEMM, m201-faithful: BK=64, 2-slot, 4 phases/K-tile -----------
// Halves are clean 128-row regions: A-h = rows mh*128+[0,128),
// B-h = rows nh*128+[0,128) (GU: h0=gate from B1, h1=up from B2).
// Frag map: row = m0 + mh*128 + wr*64 + mm*16 + l16;
//           col = n0 + nh*128 + wc*32 + nn*16 + l16 (non-GU).
// Phase p of tile t: in-phase ds_reads for its 16 MFMA + ONE half-tile stage:
//   ph0: read A-mh0(8)+B-nh0(4) [lgkm(8) pre-bar], stage B-h1(t+1)
//   ph1: read B-nh1(4),                          stage A-h0(t+2)
//   ph2: read A-mh1(8),                          stage B-h0(t+2)
//   ph3: (no reads),                             stage A-h1(t+2), VM(6)
// FIFO ledger: at ph3, queue = [B-h1(t+1), A-h0(t+2), B-h0(t+2), A-h1(t+2)]
// (8 gld); VM(6) retires B-h1(t+1) -> tile t+1 fully landed, 3-phase lead,
// never drains fresh loads. WAR: every victim region's reads complete >=1
// barrier before its stage-issue (per-phase read->LG(0)->MFMA->bar).
template<int EPI, int GU, int SPLITK>
__global__ __launch_bounds__(512, 1)
void gemm256(const u16* __restrict__ A, const u16* __restrict__ B1,
             const u16* __restrict__ B2, u16* __restrict__ Cb,
             float* __restrict__ Cf, int Kst, int NT, int N, int nbx)
{
  constexpr int SLOT = 32768;          // u16: A-h0|A-h1|B-h0|B-h1, 8192 each
  __shared__ u16 lds[2 * SLOT];        // 128 KiB

  int wg = blockIdx.x;
  int nwg = gridDim.x;
  int kh = 0;
  if (SPLITK) { int half = nwg >> 1; kh = (wg >= half); wg -= kh * half; nwg = half; }
  int bx, by;
  raster8(wg, nwg, nbx, bx, by);
  int m0 = by * 256;
  int n0 = bx * (GU ? 128 : 256);
  size_t k0 = (size_t)kh * NT * 64;

  int tid = threadIdx.x;
  int l = tid & 63, w = tid >> 6;
  int l16 = l & 15, lg = l >> 4;
  int wr = w >> 2, wc = w & 3;

  // read offsets within a 128x64 half-region (u16 index)
  int aoff[4][2], boff[2][2];
  #pragma unroll
  for (int mm = 0; mm < 4; mm++)
    #pragma unroll
    for (int kk = 0; kk < 2; kk++) {
      int ar = wr * 64 + mm * 16 + l16;
      aoff[mm][kk] = ((ar * 128 + ((kk * 64 + lg * 16) ^ ((ar & 7) << 4))) >> 1);
    }
  #pragma unroll
  for (int nn = 0; nn < 2; nn++)
    #pragma unroll
    for (int kk = 0; kk < 2; kk++) {
      int br = wc * 32 + nn * 16 + l16;
      boff[nn][kk] = 16384 + ((br * 128 + ((kk * 64 + lg * 16) ^ ((br & 7) << 4))) >> 1);
    }

  // staging: one 64-row subtile per gld16 (512 thr x 16B = 8KB), inverse-swz src
  int rh = tid >> 3;
  int cc = (tid & 7) ^ (rh & 7);
  const u16* pA[4];                    // rows m0 + u*64 + rh, u = h*2+i
  #pragma unroll
  for (int u = 0; u < 4; u++)
    pA[u] = A + (size_t)(m0 + u * 64 + rh) * Kst + k0 + cc * 8;
  const u16* pB[4];
  #pragma unroll
  for (int u = 0; u < 4; u++) {
    if (GU) pB[u] = (u < 2 ? B1 + (size_t)(n0 + u * 64 + rh) * Kst
                           : B2 + (size_t)(n0 + (u - 2) * 64 + rh) * Kst) + k0 + cc * 8;
    else    pB[u] = B1 + (size_t)(n0 + u * 64 + rh) * Kst + k0 + cc * 8;
  }

  auto stA = [&](int tt, int h) {
    u16* d = lds + (tt & 1) * SLOT + h * 8192;
    gld16(pA[h * 2 + 0] + (size_t)tt * 64, d + tid * 8);
    gld16(pA[h * 2 + 1] + (size_t)tt * 64, d + 4096 + tid * 8);
  };
  auto stB = [&](int tt, int h) {
    u16* d = lds + (tt & 1) * SLOT + 16384 + h * 8192;
    gld16(pB[h * 2 + 0] + (size_t)tt * 64, d + tid * 8);
    gld16(pB[h * 2 + 1] + (size_t)tt * 64, d + 4096 + tid * 8);
  };

  // prologue: tile0 all 4 halves, tile1 first 3 (B-h1(1) staged at t=0 ph0)
  stA(0, 0); stB(0, 0); stA(0, 1); stB(0, 1);
  stA(1, 0); stB(1, 0); stA(1, 1);
  VM(6);               // tile0 (oldest 8) landed; tile1's 3 halves in flight
  bar();

  f32x4 acc[8][4];
  f32x4 zero = {0.f, 0.f, 0.f, 0.f};
  #pragma unroll
  for (int m = 0; m < 8; m++)
    #pragma unroll
    for (int n = 0; n < 4; n++) acc[m][n] = zero;

  for (int t = 0; t < NT; ++t) {
    u16* cur = lds + (t & 1) * SLOT;
    bf16x8 a0[4][2], a1[4][2], b0[2][2], b1[2][2];

    // ---- ph0: read A-mh0 + B-nh0 (12); stage B-h1(t+1); MFMA (mh0,nh0) ----
    #pragma unroll
    for (int mm = 0; mm < 4; mm++)
      #pragma unroll
      for (int kk = 0; kk < 2; kk++)
        a0[mm][kk] = *(const bf16x8*)(cur + aoff[mm][kk]);
    #pragma unroll
    for (int nn = 0; nn < 2; nn++)
      #pragma unroll
      for (int kk = 0; kk < 2; kk++)
        b0[nn][kk] = *(const bf16x8*)(cur + boff[nn][kk]);
    if (t + 1 < NT) stB(t + 1, 1);
    LG(8);
    bar();
    LG(0);
    SCHED0;
    __builtin_amdgcn_s_setprio(1);
    #pragma unroll
    for (int mm = 0; mm < 4; mm++)
      #pragma unroll
      for (int nn = 0; nn < 2; nn++)
        #pragma unroll
        for (int kk = 0; kk < 2; kk++)
          acc[mm][nn] = mfma16(a0[mm][kk], b0[nn][kk], acc[mm][nn]);
    __builtin_amdgcn_s_setprio(0);
    SCHED0;
    bar();

    // ---- ph1: read B-nh1 (4); stage A-h0(t+2); MFMA (mh0,nh1) ----
    #pragma unroll
    for (int nn = 0; nn < 2; nn++)
      #pragma unroll
      for (int kk = 0; kk < 2; kk++)
        b1[nn][kk] = *(const bf16x8*)(cur + boff[nn][kk] + 8192);
    if (t + 2 < NT) stA(t + 2, 0);
    bar();
    LG(0);
    SCHED0;
    __builtin_amdgcn_s_setprio(1);
    #pragma unroll
    for (int mm = 0; mm < 4; mm++)
      #pragma unroll
      for (int nn = 0; nn < 2; nn++)
        #pragma unroll
        for (int kk = 0; kk < 2; kk++)
          acc[mm][2 + nn] = mfma16(a0[mm][kk], b1[nn][kk], acc[mm][2 + nn]);
    __builtin_amdgcn_s_setprio(0);
    SCHED0;
    bar();

    // ---- ph2: read A-mh1 (8); stage B-h0(t+2); MFMA (mh1,nh0) ----
    #pragma unroll
    for (int mm = 0; mm < 4; mm++)
      #pragma unroll
      for (int kk = 0; kk < 2; kk++)
        a1[mm][kk] = *(const bf16x8*)(cur + aoff[mm][kk] + 8192);
    if (t + 2 < NT) stB(t + 2, 0);
    bar();
    LG(0);
    SCHED0;
    __builtin_amdgcn_s_setprio(1);
    #pragma unroll
    for (int mm = 0; mm < 4; mm++)
      #pragma unroll
      for (int nn = 0; nn < 2; nn++)
        #pragma unroll
        for (int kk = 0; kk < 2; kk++)
          acc[4 + mm][nn] = mfma16(a1[mm][kk], b0[nn][kk], acc[4 + mm][nn]);
    __builtin_amdgcn_s_setprio(0);
    SCHED0;
    bar();

    // ---- ph3: stage A-h1(t+2); VM(6); MFMA (mh1,nh1) ----
    if (t + 2 < NT) { stA(t + 2, 1); VM(6); }
    else if (t + 1 < NT) { VM(0); }
    bar();
    SCHED0;
    __builtin_amdgcn_s_setprio(1);
    #pragma unroll
    for (int mm = 0; mm < 4; mm++)
      #pragma unroll
      for (int nn = 0; nn < 2; nn++)
        #pragma unroll
        for (int kk = 0; kk < 2; kk++)
          acc[4 + mm][2 + nn] = mfma16(a1[mm][kk], b1[nn][kk], acc[4 + mm][2 + nn]);
    __builtin_amdgcn_s_setprio(0);
    SCHED0;
    bar();
  }

  if (GU) {
    // nh0 = gate, nh1 = up; col = n0 + wc*32 + nn*16 + l16
    #pragma unroll
    for (int m = 0; m < 8; m++) {
      int row = m0 + (m >> 2) * 128 + wr * 64 + (m & 3) * 16 + lg * 4;
      #pragma unroll
      for (int nn = 0; nn < 2; nn++) {
        int col = n0 + wc * 32 + nn * 16 + l16;
        #pragma unroll
        for (int r = 0; r < 4; r++) {
          float gt = acc[m][nn][r];
          float up = acc[m][2 + nn][r];
          float sg = gt / (1.0f + __expf(-gt));
          Cb[(size_t)(row + r) * N + col] = f2bf(sg * up);
        }
      }
    }
  } else {
    #pragma unroll
    for (int m = 0; m < 8; m++) {
      int row = m0 + (m >> 2) * 128 + wr * 64 + (m & 3) * 16 + lg * 4;
      #pragma unroll
      for (int n = 0; n < 4; n++) {
        int col = n0 + (n >> 1) * 128 + wc * 32 + (n & 1) * 16 + l16;
        #pragma unroll
        for (int r = 0; r < 4; r++) {
          size_t idx = (size_t)(row + r) * N + col;
          if (EPI == 0) Cb[idx] = f2bf(acc[m][n][r]);
          else          atomicAdd(Cf + idx, acc[m][n][r]);
        }
      }
    }
  }
}

// ------------------- flash attention, sliding window + sink -----------------
__global__ __launch_bounds__(256)
void attn_k(const u16* __restrict__ qb, int ldq,
            const u16* __restrict__ kb, int ldk,
            const u16* __restrict__ vbt, u16* __restrict__ ao)
{
  int q0 = blockIdx.x * 128;
  int h = blockIdx.y;
  int b = blockIdx.z;
  int hk = h >> 2;
  int tid = threadIdx.x;
  int w = tid >> 6, l = tid & 63;
  int l16 = l & 15, lg = l >> 4;

  __shared__ u16 Ks[32 * 128];
  __shared__ u16 Vt[128 * 32];
  __shared__ u16 Ps[4][32 * 40];
  u16* Pw = Ps[w];

  bf16x8 qf[2][4];
  #pragma unroll
  for (int m = 0; m < 2; m++)
    #pragma unroll
    for (int kd = 0; kd < 4; kd++) {
      int row = q0 + w * 32 + m * 16 + l16;
      qf[m][kd] = *(const bf16x8*)(qb + (size_t)(b * SEQ + row) * ldq
                                   + h * HDIM + kd * 32 + lg * 8);
    }

  f32x4 oacc[2][8];
  float mrun[2][4], lrun[2][4];
  f32x4 zero = {0.f, 0.f, 0.f, 0.f};
  #pragma unroll
  for (int m = 0; m < 2; m++) {
    #pragma unroll
    for (int nd = 0; nd < 8; nd++) oacc[m][nd] = zero;
    #pragma unroll
    for (int r = 0; r < 4; r++) { mrun[m][r] = -1e9f; lrun[m][r] = 0.f; }
  }

  int kr0 = tid >> 4,        kc0 = (tid & 15) ^ (kr0 & 7);
  int kr1 = (tid + 256) >> 4, kc1 = (tid & 15) ^ (kr1 & 7);
  int vd0, vk0, vd1, vk1;
  swz_rc(tid, vd0, vk0);
  swz_rc(tid + 256, vd1, vk1);
  const u16* kbase = kb + (size_t)(b * SEQ) * ldk + hk * HDIM;
  const u16* vbase = vbt + (size_t)(b * NKV + hk) * HDIM * SEQ;

  int koff[2][4];
  #pragma unroll
  for (int n = 0; n < 2; n++)
    #pragma unroll
    for (int kd = 0; kd < 4; kd++) {
      int key = n * 16 + l16;
      koff[n][kd] = ((key * 128) + kd * 32 + lg * 8) ^ ((key & 7) * 8);
    }
  int voff[8];
  #pragma unroll
  for (int nd = 0; nd < 8; nd++) {
    int d = nd * 16 + l16;
    voff[nd] = (d * 32 + lg * 8) ^ ((d & 7) * 8);
  }

  int lo = (q0 >= WIN) ? ((q0 - (WIN - 1)) >> 5) : 0;
  int hi = (q0 + 127) >> 5;

  for (int it = (lo > 0 ? lo - 1 : 0); it <= hi; ++it) {
    int kt = (it < lo) ? 0 : it;
    gld16(kbase + (size_t)(kt * 32 + kr0) * ldk + kc0 * 8, Ks + tid * 8);
    gld16(kbase + (size_t)(kt * 32 + kr1) * ldk + kc1 * 8, Ks + (tid + 256) * 8);
    gld16(vbase + (size_t)vd0 * SEQ + kt * 32 + vk0 * 8, Vt + tid * 8);
    gld16(vbase + (size_t)vd1 * SEQ + kt * 32 + vk1 * 8, Vt + (tid + 256) * 8);
    __syncthreads();

    f32x4 sacc[2][2];
    sacc[0][0] = zero; sacc[0][1] = zero; sacc[1][0] = zero; sacc[1][1] = zero;
    #pragma unroll
    for (int kd = 0; kd < 4; kd++) {
      bf16x8 kf0 = *(const bf16x8*)(Ks + koff[0][kd]);
      bf16x8 kf1 = *(const bf16x8*)(Ks + koff[1][kd]);
      #pragma unroll
      for (int m = 0; m < 2; m++) {
        sacc[m][0] = mfma16(qf[m][kd], kf0, sacc[m][0]);
        sacc[m][1] = mfma16(qf[m][kd], kf1, sacc[m][1]);
      }
    }

    #pragma unroll
    for (int m = 0; m < 2; m++) {
      float sc[4];
      #pragma unroll
      for (int r = 0; r < 4; r++) {
        int i = q0 + w * 32 + m * 16 + lg * 4 + r;
        int j0 = kt * 32 + l16;
        int j1 = j0 + 16;
        float s0 = sacc[m][0][r];
        float s1 = sacc[m][1][r];
        bool ok0 = (j0 <= i) && ((i - j0 < WIN) || (j0 < SINKN));
        bool ok1 = (j1 <= i) && ((i - j1 < WIN) || (j1 < SINKN));
        s0 = ok0 ? s0 : -1e9f;
        s1 = ok1 ? s1 : -1e9f;
        float mx = fmaxf(s0, s1);
        mx = fmaxf(mx, __shfl_xor(mx, 1));
        mx = fmaxf(mx, __shfl_xor(mx, 2));
        mx = fmaxf(mx, __shfl_xor(mx, 4));
        mx = fmaxf(mx, __shfl_xor(mx, 8));
        float mold = mrun[m][r];
        float mnew = fmaxf(mold, mx);
        float scl = __expf(mold - mnew);
        mrun[m][r] = mnew;
        float p0 = __expf(s0 - mnew);
        float p1 = __expf(s1 - mnew);
        int prow = m * 16 + lg * 4 + r;
        Pw[prow * 40 + l16] = f2bf(p0);
        Pw[prow * 40 + 16 + l16] = f2bf(p1);
        float ps = p0 + p1;
        ps += __shfl_xor(ps, 1);
        ps += __shfl_xor(ps, 2);
        ps += __shfl_xor(ps, 4);
        ps += __shfl_xor(ps, 8);
        lrun[m][r] = lrun[m][r] * scl + ps;
        sc[r] = scl;
      }
      #pragma unroll
      for (int nd = 0; nd < 8; nd++) {
        oacc[m][nd][0] *= sc[0];
        oacc[m][nd][1] *= sc[1];
        oacc[m][nd][2] *= sc[2];
        oacc[m][nd][3] *= sc[3];
      }
    }

    bf16x8 pa0 = *(const bf16x8*)(Pw + l16 * 40 + lg * 8);
    bf16x8 pa1 = *(const bf16x8*)(Pw + (16 + l16) * 40 + lg * 8);
    #pragma unroll
    for (int nd = 0; nd < 8; nd++) {
      bf16x8 vf = *(const bf16x8*)(Vt + voff[nd]);
      oacc[0][nd] = mfma16(pa0, vf, oacc[0][nd]);
      oacc[1][nd] = mfma16(pa1, vf, oacc[1][nd]);
    }
    __syncthreads();
  }

  #pragma unroll
  for (int m = 0; m < 2; m++)
    #pragma unroll
    for (int r = 0; r < 4; r++) {
      float invl = 1.0f / lrun[m][r];
      int row = q0 + w * 32 + m * 16 + lg * 4 + r;
      #pragma unroll
      for (int nd = 0; nd < 8; nd++) {
        int col = nd * 16 + l16;
        ao[(size_t)(b * SEQ + row) * (NH * HDIM) + h * HDIM + col] =
            f2bf(oacc[m][nd][r] * invl);
      }
    }
}

// ------------------------------- launcher -----------------------------------
extern "C" void kernel_launch(void* const* d_in, const int* in_sizes, int n_in,
                              void* d_out, int out_size, void* d_ws, size_t ws_size,
                              hipStream_t stream)
{
  (void)in_sizes; (void)n_in; (void)out_size;
  const float* x  = (const float*)d_in[0];
  const float* g1 = (const float*)d_in[1];
  const float* g2 = (const float*)d_in[2];
  const float* wq = (const float*)d_in[3];
  const float* wk = (const float*)d_in[4];
  const float* wv = (const float*)d_in[5];
  const float* wo = (const float*)d_in[6];
  const float* wg = (const float*)d_in[7];
  const float* wu = (const float*)d_in[8];
  const float* wd = (const float*)d_in[9];
  float* out = (float*)d_out;

  char* ws = (char*)d_ws;
  size_t off = 0;
  auto alloc = [&](size_t bytes) {
    char* p = ws + off;
    off += (bytes + 255) & ~(size_t)255;
    return p;
  };
  const int NQKV = 3072;   // q 0..2047 | k 2048..2559 | v 2560..3071
  u16* wqkv_t = (u16*)alloc((size_t)NQKV * DM * 2);
  u16* wo_t   = (u16*)alloc((size_t)DM * DM * 2);
  u16* wg_t   = (u16*)alloc((size_t)HID * DM * 2);
  u16* wu_t   = (u16*)alloc((size_t)HID * DM * 2);
  u16* wd_t   = (u16*)alloc((size_t)DM * HID * 2);
  u16* hb     = (u16*)alloc((size_t)TOK * DM * 2);
  // gu (67.1 MB) aliases qkvb+vbt+aob (dead by the time gateup runs) + tail
  char* span0 = ws + off;
  u16* qkvb   = (u16*)alloc((size_t)TOK * NQKV * 2);
  u16* vbt    = (u16*)alloc((size_t)TOK * NKV * HDIM * 2);
  u16* aob    = (u16*)alloc((size_t)TOK * NH * HDIM * 2);
  size_t span_used = (size_t)(ws + off - span0);
  size_t gu_need = (size_t)TOK * HID * 2;
  if (gu_need > span_used) alloc(gu_need - span_used);
  u16* gu = (u16*)span0;
  float* ct  = (float*)alloc((size_t)SEQ * 64 * 4);
  float* st  = (float*)alloc((size_t)SEQ * 64 * 4);
  if (off > ws_size) return;

  dim3 blk(256);
  dim3 blk512(512);

  // weight transposes (fp32 -> bf16, [K][N] -> [N][K])
  wtrans<<<dim3(DM / 32, DM / 32), blk, 0, stream>>>(wq, wqkv_t, DM, DM);
  wtrans<<<dim3((NKV * HDIM) / 32, DM / 32), blk, 0, stream>>>(wk, wqkv_t + (size_t)DM * DM, DM, NKV * HDIM);
  wtrans<<<dim3((NKV * HDIM) / 32, DM / 32), blk, 0, stream>>>(wv, wqkv_t + (size_t)(DM + NKV * HDIM) * DM, DM, NKV * HDIM);
  wtrans<<<dim3(DM / 32, DM / 32), blk, 0, stream>>>(wo, wo_t, DM, DM);
  wtrans<<<dim3(HID / 32, DM / 32), blk, 0, stream>>>(wg, wg_t, DM, HID);
  wtrans<<<dim3(HID / 32, DM / 32), blk, 0, stream>>>(wu, wu_t, DM, HID);
  wtrans<<<dim3(DM / 32, HID / 32), blk, 0, stream>>>(wd, wd_t, HID, DM);

  rope_table_k<<<SEQ * 64 / 256, blk, 0, stream>>>(ct, st);
  rmsnorm_k<<<TOK, blk, 0, stream>>>(x, g1, hb);

  // fused QKV projection: [4096][3072] via 256x256 kernel (192 blocks)
  gemm256<0, 0, 0><<<dim3((NQKV / 256) * (TOK / 256)), blk512, 0, stream>>>(
      hb, wqkv_t, nullptr, qkvb, nullptr, DM, DM / 64, NQKV, NQKV / 256);

  rope_apply_k<<<TOK, dim3(NH * 64), 0, stream>>>(qkvb, NQKV, ct, st, 0.08838834764831845f);
  rope_apply_k<<<TOK, dim3(NKV * 64), 0, stream>>>(qkvb + DM, NQKV, ct, st, 1.0f);
  vtrans<<<dim3((NKV * HDIM) / 32, TOK / 32), blk, 0, stream>>>(qkvb + DM + NKV * HDIM, NQKV, vbt);

  attn_k<<<dim3(SEQ / 128, NH, 2), blk, 0, stream>>>(qkvb, NQKV, qkvb + DM, NQKV, vbt, aob);

  gemmp<1><<<dim3((DM / 256) * (TOK / 128)), blk512, 0, stream>>>(
      aob, wo_t, nullptr, out, x, TOK, DM, DM, DM / 256);
  rmsnorm_k<<<TOK, blk, 0, stream>>>(out, g2, hb);

  // fused gate+up with silu epilogue (1024 blocks)
  gemm256<0, 1, 0><<<dim3((HID / 128) * (TOK / 256)), blk512, 0, stream>>>(
      hb, wg_t, wu_t, gu, nullptr, DM, DM / 64, HID, HID / 128);

  // down-proj: split-K=2, atomicAdd into out (256 blocks)
  gemm256<4, 0, 1><<<dim3(2 * (DM / 256) * (TOK / 256)), blk512, 0, stream>>>(
      gu, wd_t, nullptr, nullptr, out, HID, HID / 128, DM, DM / 256);
}